// Round 8
// baseline (392.472 us; speedup 1.0000x reference)
//
#include <hip/hip_runtime.h>

typedef unsigned short u16;
typedef unsigned int u32;
typedef __attribute__((ext_vector_type(8))) short bf16x8;
typedef __attribute__((ext_vector_type(4))) float f32x4;

#define CH 40
#define IW 258                   // ring-padded width (256 + 2)
#define IWCH (IW * CH)           // 10320
#define IMG_CL (IW * IW * CH)    // u16 elements per image, channel-last padded
#define WT_SET (48 * 384)        // u16 per weight set
#define SBUF 15840               // u16 per stage buffer (6*66*40)

#define GLDS16(g, l) __builtin_amdgcn_global_load_lds( \
    (const __attribute__((address_space(1))) void*)(g), \
    (__attribute__((address_space(3))) void*)(l), 16, 0, 0)

__device__ __forceinline__ float b2f(u16 u) {
  union { u32 i; float f; } v; v.i = ((u32)u) << 16; return v.f;
}
__device__ __forceinline__ u16 f2b(float f) {
  union { float f; u32 i; } v; v.f = f;
  u32 r = v.i + 0x7fffu + ((v.i >> 16) & 1u);
  return (u16)(r >> 16);
}
__device__ __forceinline__ u32 addbf2(u32 a, u32 b) {
  union { u32 i; float f; } lo_a, lo_b, hi_a, hi_b;
  lo_a.i = a << 16; lo_b.i = b << 16;
  hi_a.i = a & 0xffff0000u; hi_b.i = b & 0xffff0000u;
  float lo = lo_a.f + lo_b.f, hi = hi_a.f + hi_b.f;
  return (u32)f2b(lo) | ((u32)f2b(hi) << 16);
}
__device__ __forceinline__ float actf(float t, int ACT) {
  if (ACT == 1) return 0.5f * t * (1.f + erff(t * 0.70710678118654752f));
  if (ACT == 2) return fmaxf(t, 0.f);
  return t;
}

// ---- weights -> Wt bf16 [48][384] per set --------------------------------
__global__ __launch_bounds__(256)
void prep_w_k(const float* __restrict__ w0, const float* __restrict__ w1,
              const float* __restrict__ w2, const float* __restrict__ w3,
              const float* __restrict__ w4, u16* __restrict__ wt)
{
  int i = blockIdx.x * 256 + threadIdx.x;      // 5*48*384 = 92160
  if (i >= 5 * WT_SET) return;
  int k = i % 384;
  int oc = (i / 384) % 48;
  int set = i / WT_SET;
  u16 v = 0;
  if (set == 4) {
    if (oc < 40 && k < 40) v = f2b(w4[oc * 40 + k]);
  } else {
    int dy = k >> 7;
    int r = k & 127;
    if (oc < 40 && r < 120) {
      int dx = r / 40;
      int ic = r - dx * 40;
      const float* w = (set == 0) ? w0 : (set == 1) ? w1 : (set == 2) ? w2 : w3;
      v = f2b(w[((oc * 40 + ic) * 3 + dy) * 3 + dx]);
    }
  }
  wt[i] = v;
}

// ---- x fp32 planar -> xcl bf16 channel-last + zero rings of xcl, cla -----
__global__ __launch_bounds__(256)
void prep_x_k(const float* __restrict__ x, u16* __restrict__ xcl,
              u16* __restrict__ cla)
{
  const int n = blockIdx.x / IW;
  const int yr = blockIdx.x % IW;
  const int t = threadIdx.x;
  const size_t base = (size_t)n * IMG_CL + (size_t)yr * IWCH;
  const uint4 z = {0u, 0u, 0u, 0u};

  if (yr == 0 || yr == IW - 1) {
    for (int i = t; i < IWCH / 8; i += 256) {
      ((uint4*)(xcl + base))[i] = z;
      ((uint4*)(cla + base))[i] = z;
    }
    return;
  }
  if (t < 5) {
    ((uint4*)(xcl + base))[t] = z;
    ((uint4*)(cla + base))[t] = z;
  } else if (t < 10) {
    size_t b2 = base + (size_t)(IW - 1) * CH;
    ((uint4*)(xcl + b2))[t - 5] = z;
    ((uint4*)(cla + b2))[t - 5] = z;
  }
  const int y = yr - 1;
  const float* xp = x + (size_t)n * CH * 65536 + (size_t)y * 256 + t;
  __attribute__((aligned(16))) u16 buf[40];
  #pragma unroll
  for (int ic = 0; ic < 40; ++ic) buf[ic] = f2b(xp[(size_t)ic * 65536]);
  u16* dst = xcl + base + (size_t)(t + 1) * CH;
  #pragma unroll
  for (int q = 0; q < 5; ++q) ((uint4*)dst)[q] = ((const uint4*)buf)[q];
}

// ---- 2-phase pipelined MFMA conv 3x3: block = 4-row strip, walks 4 x-tiles
// DUAL: two weight sets / two outputs (conv1+conv5).  CL epilogue: swapped
// operands + LDS restage; PLANAR: unswapped + direct float4 stores.
template<int ACTA, int ACTB, bool DUAL, bool RES, bool PLANAR_OUT>
__global__ __launch_bounds__(256, 2)
void convp_k(const u16* __restrict__ incl, const u16* __restrict__ wtA,
             const u16* __restrict__ wtB, const float* __restrict__ biasA,
             const float* __restrict__ biasB, const u16* __restrict__ rescl,
             void* __restrict__ outA, void* __restrict__ outB)
{
  __shared__ u16 s_buf[2 * SBUF];          // 63360 B double buffer

  const int tid = threadIdx.x;
  const int bid = ((int)blockIdx.x & 7) * 64 + ((int)blockIdx.x >> 3); // 512
  const int n = bid >> 6;
  const int y0 = (bid & 63) << 2;

  const int w = tid >> 6;
  const int l = tid & 63;
  const int g = l >> 4;
  const int m = l & 15;
  const int y = y0 + w;

  auto stage = [&](int sb, int x0) {
    const u16* src = incl + (size_t)n * IMG_CL + ((size_t)y0 * IW + x0) * CH;
    u16* dst = s_buf + sb * SBUF;
    #pragma unroll
    for (int k = 0; k < 8; ++k) {
      int i = tid + (k << 8);
      if (i < 1980) {
        int r = i / 330, o = i - r * 330;
        GLDS16(src + (size_t)r * IWCH + o * 8, dst + i * 8);
      }
    }
  };

  stage(0, 0);
  __syncthreads();                         // drains vmcnt: buf0 ready

  int cur = 0;
  #pragma unroll 1
  for (int t = 0; t < 4; ++t) {
    if (t < 3) stage(cur ^ 1, (t + 1) << 6);   // issue-early, lands by barrier
    const int x0 = t << 6;
    const u16* sin = s_buf + cur * SBUF;

    f32x4 accA[4][3], accB[4][3];
    #pragma unroll
    for (int xt = 0; xt < 4; ++xt)
      #pragma unroll
      for (int tt = 0; tt < 3; ++tt) {
        accA[xt][tt] = (f32x4){0.f, 0.f, 0.f, 0.f};
        if (DUAL) accB[xt][tt] = (f32x4){0.f, 0.f, 0.f, 0.f};
      }

    #pragma unroll
    for (int s = 0; s < 12; ++s) {
      const int dy = s >> 2;
      const int c = ((s & 3) << 2) + g;    // k-chunk id 0..15
      int dx, icb;
      if (c >= 15)      { dx = 0; icb = 0; }   // zero-weight pad chunk
      else if (c >= 10) { dx = 2; icb = (c - 10) * 8; }
      else if (c >= 5)  { dx = 1; icb = (c - 5) * 8; }
      else              { dx = 0; icb = c * 8; }
      const int abase = (w + dy) * (66 * CH) + (m + dx) * CH + icb;
      bf16x8 a0 = *(const bf16x8*)(sin + abase);
      bf16x8 a1 = *(const bf16x8*)(sin + abase + 16 * CH);
      bf16x8 a2 = *(const bf16x8*)(sin + abase + 32 * CH);
      bf16x8 a3 = *(const bf16x8*)(sin + abase + 48 * CH);
      const int wb = s * 32 + g * 8;
      #pragma unroll
      for (int tt = 0; tt < 3; ++tt) {
        bf16x8 bA = *(const bf16x8*)(wtA + (m + 16 * tt) * 384 + wb);
        if (PLANAR_OUT) {
          accA[0][tt] = __builtin_amdgcn_mfma_f32_16x16x32_bf16(a0, bA, accA[0][tt], 0, 0, 0);
          accA[1][tt] = __builtin_amdgcn_mfma_f32_16x16x32_bf16(a1, bA, accA[1][tt], 0, 0, 0);
          accA[2][tt] = __builtin_amdgcn_mfma_f32_16x16x32_bf16(a2, bA, accA[2][tt], 0, 0, 0);
          accA[3][tt] = __builtin_amdgcn_mfma_f32_16x16x32_bf16(a3, bA, accA[3][tt], 0, 0, 0);
        } else {
          accA[0][tt] = __builtin_amdgcn_mfma_f32_16x16x32_bf16(bA, a0, accA[0][tt], 0, 0, 0);
          accA[1][tt] = __builtin_amdgcn_mfma_f32_16x16x32_bf16(bA, a1, accA[1][tt], 0, 0, 0);
          accA[2][tt] = __builtin_amdgcn_mfma_f32_16x16x32_bf16(bA, a2, accA[2][tt], 0, 0, 0);
          accA[3][tt] = __builtin_amdgcn_mfma_f32_16x16x32_bf16(bA, a3, accA[3][tt], 0, 0, 0);
        }
        if (DUAL) {
          bf16x8 bB = *(const bf16x8*)(wtB + (m + 16 * tt) * 384 + wb);
          accB[0][tt] = __builtin_amdgcn_mfma_f32_16x16x32_bf16(bB, a0, accB[0][tt], 0, 0, 0);
          accB[1][tt] = __builtin_amdgcn_mfma_f32_16x16x32_bf16(bB, a1, accB[1][tt], 0, 0, 0);
          accB[2][tt] = __builtin_amdgcn_mfma_f32_16x16x32_bf16(bB, a2, accB[2][tt], 0, 0, 0);
          accB[3][tt] = __builtin_amdgcn_mfma_f32_16x16x32_bf16(bB, a3, accB[3][tt], 0, 0, 0);
        }
      }
    }

    if (PLANAR_OUT) {
      // D: row = px (4g+i), col = oc (m+16t) -> direct float4 stores
      const float bv0 = biasA[m];
      const float bv1 = biasA[m + 16];
      const float bv2 = (m < 8) ? biasA[m + 32] : 0.f;
      #pragma unroll
      for (int tt = 0; tt < 3; ++tt) {
        const int oc = m + 16 * tt;
        if (tt == 2 && m >= 8) continue;
        const float bv = (tt == 0) ? bv0 : (tt == 1) ? bv1 : bv2;
        #pragma unroll
        for (int xt = 0; xt < 4; ++xt) {
          const int xb = x0 + xt * 16 + 4 * g;
          float v[4];
          #pragma unroll
          for (int i = 0; i < 4; ++i) v[i] = actf(accA[xt][tt][i] + bv, ACTA);
          *(float4*)((float*)outA + (((size_t)(n * CH + oc)) << 16) + ((size_t)y << 8) + xb)
              = make_float4(v[0], v[1], v[2], v[3]);
        }
      }
      __syncthreads();                     // stage(t+1) landed; buf flip safe
    } else {
      __syncthreads();                     // all waves done reading buf[cur]
      u16* so = (u16*)s_buf + cur * SBUF + w * 3072;  // per-wave 6144 B
      const size_t rowu = (size_t)n * IMG_CL + ((size_t)(y + 1) * IW + (x0 + 1)) * CH;
      const int NOUT = DUAL ? 2 : 1;
      #pragma unroll
      for (int which = 0; which < NOUT; ++which) {
        const float* bias = which ? biasB : biasA;
        const int ACT = which ? ACTB : ACTA;
        f32x4 (*acc)[3] = which ? accB : accA;
        float4 bv[3];
        bv[0] = *(const float4*)(bias + 4 * g);
        bv[1] = *(const float4*)(bias + 16 + 4 * g);
        bv[2] = (g < 2) ? *(const float4*)(bias + 32 + 4 * g)
                        : make_float4(0.f, 0.f, 0.f, 0.f);
        #pragma unroll
        for (int tt = 0; tt < 3; ++tt) {
          if (tt == 2 && g >= 2) continue;
          #pragma unroll
          for (int xt = 0; xt < 4; ++xt) {
            const int pxl = xt * 16 + m;
            float v[4];
            #pragma unroll
            for (int i = 0; i < 4; ++i)
              v[i] = actf(acc[xt][tt][i] + ((const float*)&bv[tt])[i], ACT);
            uint2 pk;
            pk.x = (u32)f2b(v[0]) | ((u32)f2b(v[1]) << 16);
            pk.y = (u32)f2b(v[2]) | ((u32)f2b(v[3]) << 16);
            int byt = pxl * 80 + (16 * tt + 4 * g) * 2;
            byt ^= ((pxl >> 3) & 7) << 4;
            *(uint2*)((char*)so + byt) = pk;
          }
        }
        u16* dst = (u16*)(which ? outB : outA);
        #pragma unroll
        for (int q = 0; q < 5; ++q) {
          int byt = l * 80 + q * 16;
          byt ^= ((l >> 3) & 7) << 4;
          uint4 d = *(const uint4*)((const char*)so + byt);
          if (RES) {
            uint4 rv = *(const uint4*)(rescl + rowu + (size_t)l * 40 + q * 8);
            d.x = addbf2(d.x, rv.x); d.y = addbf2(d.y, rv.y);
            d.z = addbf2(d.z, rv.z); d.w = addbf2(d.w, rv.w);
          }
          *(uint4*)(dst + rowu + (size_t)l * 40 + q * 8) = d;
        }
      }
      __syncthreads();                     // restage reads done; stage landed
    }
    cur ^= 1;
  }
}

// ---- depthwise conv k3 s8 p2 d2 on cl bf16 -> planar f32 (8,40,32,32) ----
__global__ __launch_bounds__(256)
void dwconv_k(const u16* __restrict__ incl, const float* __restrict__ w,
              const float* __restrict__ b, float* __restrict__ out)
{
  int idx = blockIdx.x * 256 + threadIdx.x;
  if (idx >= 8 * 32 * 32 * CH) return;
  int c = idx % CH;
  int p = idx / CH;
  int ox = p & 31;
  int oy = (p >> 5) & 31;
  int n = p >> 10;
  float acc = b[c];
  const u16* ip = incl + (size_t)n * IMG_CL;
  #pragma unroll
  for (int dy = 0; dy < 3; ++dy) {
    int y = oy * 8 - 2 + dy * 2;
    if ((unsigned)y >= 256u) continue;
    #pragma unroll
    for (int dx = 0; dx < 3; ++dx) {
      int x = ox * 8 - 2 + dx * 2;
      if ((unsigned)x >= 256u) continue;
      acc += w[c * 9 + dy * 3 + dx] * b2f(ip[((size_t)(y + 1) * IW + (x + 1)) * CH + c]);
    }
  }
  out[((size_t)(n * CH + c) << 10) + oy * 32 + ox] = acc;
}

// ---- per-8x8-block iDCT on planar f32 32x32 ------------------------------
__global__ __launch_bounds__(256)
void idct8_k(const float* __restrict__ in, float* __restrict__ out)
{
  __shared__ float ctab[8];
  if (threadIdx.x < 8) {
    const float c_[8] = {1.f, 0.70710678118654752f, 0.f, -0.70710678118654752f,
                         -1.f, -0.70710678118654752f, 0.f, 0.70710678118654752f};
    ctab[threadIdx.x] = c_[threadIdx.x];
  }
  __syncthreads();
  int idx = blockIdx.x * 256 + threadIdx.x;
  if (idx >= 8 * CH * 32 * 32) return;
  int ox = idx & 31, oy = (idx >> 5) & 31, bc = idx >> 10;
  int k = oy & 7, lq = ox & 7;
  const float* ip = in + bc * 1024 + (oy & ~7) * 32 + (ox & ~7);
  float acc = 0.f;
  #pragma unroll
  for (int mm = 0; mm < 8; ++mm) {
    float rk = ctab[(k * mm) & 7];
    float s = 0.f;
    #pragma unroll
    for (int nn = 0; nn < 8; ++nn)
      s += ctab[(lq * nn) & 7] * ip[mm * 32 + nn];
    acc += rk * s;
  }
  out[idx] = acc * 0.125f;
}

// ---- MFMA 1x1 conv + sigmoid + bilinear(32->256) multiply; cl bf16 -------
__global__ __launch_bounds__(256)
void wgtmul_k(const u16* __restrict__ t1cl, const u16* __restrict__ wt3,
              const float* __restrict__ b3, const float* __restrict__ dct,
              u16* __restrict__ outcl)
{
  __shared__ float s_yw[40 * 33];
  __shared__ u16 s_out[4 * 3072];

  const int q8 = (int)gridDim.x >> 3;
  const int bid = ((int)blockIdx.x & 7) * q8 + ((int)blockIdx.x >> 3);
  const int n = bid >> 8;
  const int y = bid & 255;
  const int tid = threadIdx.x;

  float sy = (y + 0.5f) * 0.125f - 0.5f;
  float yq = floorf(sy);
  float fy = sy - yq;
  int y0c = max((int)yq, 0), y1c = min((int)yq + 1, 31);

  for (int i = tid; i < 1280; i += 256) {
    int oc = i >> 5, c = i & 31;
    const float* sp = dct + ((size_t)(n * CH + oc) << 10);
    s_yw[oc * 33 + c] = (1.f - fy) * sp[y0c * 32 + c] + fy * sp[y1c * 32 + c];
  }
  __syncthreads();

  const int w = tid >> 6;
  const int l = tid & 63;
  const int g = l >> 4;
  const int m = l & 15;
  const int xb = w << 6;

  const u16* tp = t1cl + (size_t)n * IMG_CL + ((size_t)(y + 1) * IW + 1) * CH;

  f32x4 acc[4][3];
  #pragma unroll
  for (int xt = 0; xt < 4; ++xt)
    #pragma unroll
    for (int t = 0; t < 3; ++t) acc[xt][t] = (f32x4){0.f, 0.f, 0.f, 0.f};

  #pragma unroll
  for (int xt = 0; xt < 4; ++xt) {
    const u16* ap = tp + (size_t)(xb + xt * 16 + m) * CH;
    bf16x8 a0 = *(const bf16x8*)(ap + 8 * g);
    bf16x8 a1 = *(const bf16x8*)(ap + 32 + 8 * g);
    #pragma unroll
    for (int t = 0; t < 3; ++t) {
      bf16x8 b0 = *(const bf16x8*)(wt3 + (m + 16 * t) * 384 + 8 * g);
      bf16x8 b1 = *(const bf16x8*)(wt3 + (m + 16 * t) * 384 + 32 + 8 * g);
      acc[xt][t] = __builtin_amdgcn_mfma_f32_16x16x32_bf16(b0, a0, acc[xt][t], 0, 0, 0);
      acc[xt][t] = __builtin_amdgcn_mfma_f32_16x16x32_bf16(b1, a1, acc[xt][t], 0, 0, 0);
    }
  }

  u16* so = s_out + w * 3072;
  float4 bv[3];
  bv[0] = *(const float4*)(b3 + 4 * g);
  bv[1] = *(const float4*)(b3 + 16 + 4 * g);
  bv[2] = (g < 2) ? *(const float4*)(b3 + 32 + 4 * g) : make_float4(0.f, 0.f, 0.f, 0.f);
  #pragma unroll
  for (int t = 0; t < 3; ++t) {
    if (t == 2 && g >= 2) continue;
    #pragma unroll
    for (int xt = 0; xt < 4; ++xt) {
      const int pxl = xt * 16 + m;
      const int px = xb + pxl;
      float sx = (px + 0.5f) * 0.125f - 0.5f;
      float xq = floorf(sx);
      float fx = sx - xq;
      int x0c = max((int)xq, 0), x1c = min((int)xq + 1, 31);
      u16 r4[4];
      #pragma unroll
      for (int i = 0; i < 4; ++i) {
        int oc = 16 * t + 4 * g + i;
        float wgt = 1.f / (1.f + expf(-(acc[xt][t][i] + ((const float*)&bv[t])[i])));
        float bil = (1.f - fx) * s_yw[oc * 33 + x0c] + fx * s_yw[oc * 33 + x1c];
        r4[i] = f2b(wgt * bil);
      }
      uint2 pk;
      pk.x = (u32)r4[0] | ((u32)r4[1] << 16);
      pk.y = (u32)r4[2] | ((u32)r4[3] << 16);
      int byt = pxl * 80 + (16 * t + 4 * g) * 2;
      byt ^= ((pxl >> 3) & 7) << 4;
      *(uint2*)((char*)so + byt) = pk;
    }
  }
  const size_t rowu = (size_t)n * IMG_CL + ((size_t)(y + 1) * IW + (xb + 1)) * CH;
  #pragma unroll
  for (int q = 0; q < 5; ++q) {
    int byt = l * 80 + q * 16;
    byt ^= ((l >> 3) & 7) << 4;
    uint4 d = *(const uint4*)((const char*)so + byt);
    *(uint4*)(outcl + rowu + (size_t)l * 40 + q * 8) = d;
  }
}

extern "C" void kernel_launch(void* const* d_in, const int* in_sizes, int n_in,
                              void* d_out, int out_size, void* d_ws, size_t ws_size,
                              hipStream_t stream)
{
  const float* x       = (const float*)d_in[0];
  const float* conv_w  = (const float*)d_in[1];
  const float* conv_b  = (const float*)d_in[2];
  const float* ddct_w  = (const float*)d_in[3];
  const float* ddct_b  = (const float*)d_in[4];
  const float* dctc_w  = (const float*)d_in[5];
  const float* dctc_b  = (const float*)d_in[6];
  const float* w1_w    = (const float*)d_in[7];
  const float* w1_b    = (const float*)d_in[8];
  const float* w3_w    = (const float*)d_in[9];
  const float* w3_b    = (const float*)d_in[10];
  const float* after_w = (const float*)d_in[11];
  const float* after_b = (const float*)d_in[12];

  char* ws = (char*)d_ws;
  const size_t CLB = (size_t)8 * IMG_CL * 2;          // 42,600,960 B
  u16*   xcl    = (u16*)ws;                           // x, later dd
  u16*   cl_a   = (u16*)(ws + CLB);                   // dct_feat, later prod
  u16*   cl_c   = (u16*)(ws + 2 * CLB);               // t1
  float* small0 = (float*)(ws + 3 * CLB);             // 1,310,720 B
  float* small1 = (float*)(ws + 3 * CLB + 1310720);   // 1,310,720 B
  u16*   wt     = (u16*)(ws + 3 * CLB + 2621440);     // 184,320 B (5 sets)

  // 0. weight transform + input cl conversion + ring zeroing (xcl, cl_a)
  prep_w_k<<<360, 256, 0, stream>>>(conv_w, ddct_w, w1_w, after_w, w3_w, wt);
  prep_x_k<<<8 * IW, 256, 0, stream>>>(x, xcl, cl_a);
  // 1+5. dct_feat = gelu(conv(x)) -> cl_a ; t1 = relu(conv(x,w1)) -> cl_c
  convp_k<1, 2, true, false, false><<<512, 256, 0, stream>>>(
      xcl, wt, wt + 2 * WT_SET, conv_b, w1_b, nullptr, cl_a, cl_c);
  // 2. dd = gelu(conv(dct_feat)) + dct_feat        -> xcl (x dead)
  convp_k<1, 0, false, true, false><<<512, 256, 0, stream>>>(
      cl_a, wt + WT_SET, nullptr, ddct_b, nullptr, cl_a, xcl, nullptr);
  // 3. depthwise strided conv                      -> small0
  dwconv_k<<<1280, 256, 0, stream>>>(xcl, dctc_w, dctc_b, small0);
  // 4. per-block 8x8 iDCT                          -> small1
  idct8_k<<<1280, 256, 0, stream>>>(small0, small1);
  // 6. prod = sigmoid(1x1(t1)) * bilinear(idct)    -> cl_a (dct_feat dead)
  wgtmul_k<<<2048, 256, 0, stream>>>(cl_c, wt + 4 * WT_SET, w3_b, small1, cl_a);
  // 7. out = conv(prod, after)                     -> d_out fp32 planar
  convp_k<0, 0, false, false, true><<<512, 256, 0, stream>>>(
      cl_a, wt + 3 * WT_SET, nullptr, after_b, nullptr, nullptr, (void*)d_out, nullptr);
}

// Round 9
// 303.257 us; speedup vs baseline: 1.2942x; 1.2942x over previous
//
#include <hip/hip_runtime.h>

typedef unsigned short u16;
typedef unsigned int u32;
typedef __attribute__((ext_vector_type(8))) short bf16x8;
typedef __attribute__((ext_vector_type(4))) float f32x4;

#define CH 40
#define IW 258                   // ring-padded width (256 + 2)
#define IWCH (IW * CH)           // 10320
#define IMG_CL (IW * IW * CH)    // u16 elements per image, channel-last padded
#define WT_SET (48 * 384)        // u16 per weight set

#define GLDS16(g, l) __builtin_amdgcn_global_load_lds( \
    (const __attribute__((address_space(1))) void*)(g), \
    (__attribute__((address_space(3))) void*)(l), 16, 0, 0)

__device__ __forceinline__ float b2f(u16 u) {
  union { u32 i; float f; } v; v.i = ((u32)u) << 16; return v.f;
}
__device__ __forceinline__ u16 f2b(float f) {
  union { float f; u32 i; } v; v.f = f;
  u32 r = v.i + 0x7fffu + ((v.i >> 16) & 1u);
  return (u16)(r >> 16);
}
__device__ __forceinline__ u32 addbf2(u32 a, u32 b) {
  union { u32 i; float f; } lo_a, lo_b, hi_a, hi_b;
  lo_a.i = a << 16; lo_b.i = b << 16;
  hi_a.i = a & 0xffff0000u; hi_b.i = b & 0xffff0000u;
  float lo = lo_a.f + lo_b.f, hi = hi_a.f + hi_b.f;
  return (u32)f2b(lo) | ((u32)f2b(hi) << 16);
}
__device__ __forceinline__ float actf(float t, int ACT) {
  if (ACT == 1) return 0.5f * t * (1.f + erff(t * 0.70710678118654752f));
  if (ACT == 2) return fmaxf(t, 0.f);
  return t;
}

// ---- weights -> Wt bf16 [48][384] per set --------------------------------
__global__ __launch_bounds__(256)
void prep_w_k(const float* __restrict__ w0, const float* __restrict__ w1,
              const float* __restrict__ w2, const float* __restrict__ w3,
              const float* __restrict__ w4, u16* __restrict__ wt)
{
  int i = blockIdx.x * 256 + threadIdx.x;      // 5*48*384 = 92160
  if (i >= 5 * WT_SET) return;
  int k = i % 384;
  int oc = (i / 384) % 48;
  int set = i / WT_SET;
  u16 v = 0;
  if (set == 4) {
    if (oc < 40 && k < 40) v = f2b(w4[oc * 40 + k]);
  } else {
    int dy = k >> 7;
    int r = k & 127;
    if (oc < 40 && r < 120) {
      int dx = r / 40;
      int ic = r - dx * 40;
      const float* w = (set == 0) ? w0 : (set == 1) ? w1 : (set == 2) ? w2 : w3;
      v = f2b(w[((oc * 40 + ic) * 3 + dy) * 3 + dx]);
    }
  }
  wt[i] = v;
}

// ---- x fp32 planar -> xcl bf16 channel-last + zero rings of xcl, cla -----
__global__ __launch_bounds__(256)
void prep_x_k(const float* __restrict__ x, u16* __restrict__ xcl,
              u16* __restrict__ cla)
{
  const int n = blockIdx.x / IW;
  const int yr = blockIdx.x % IW;
  const int t = threadIdx.x;
  const size_t base = (size_t)n * IMG_CL + (size_t)yr * IWCH;
  const uint4 z = {0u, 0u, 0u, 0u};

  if (yr == 0 || yr == IW - 1) {
    for (int i = t; i < IWCH / 8; i += 256) {
      ((uint4*)(xcl + base))[i] = z;
      ((uint4*)(cla + base))[i] = z;
    }
    return;
  }
  if (t < 5) {
    ((uint4*)(xcl + base))[t] = z;
    ((uint4*)(cla + base))[t] = z;
  } else if (t < 10) {
    size_t b2 = base + (size_t)(IW - 1) * CH;
    ((uint4*)(xcl + b2))[t - 5] = z;
    ((uint4*)(cla + b2))[t - 5] = z;
  }
  const int y = yr - 1;
  const float* xp = x + (size_t)n * CH * 65536 + (size_t)y * 256 + t;
  __attribute__((aligned(16))) u16 buf[40];
  #pragma unroll
  for (int ic = 0; ic < 40; ++ic) buf[ic] = f2b(xp[(size_t)ic * 65536]);
  u16* dst = xcl + base + (size_t)(t + 1) * CH;
  #pragma unroll
  for (int q = 0; q < 5; ++q) ((uint4*)dst)[q] = ((const uint4*)buf)[q];
}

// ---- wave-split fused conv1+conv5: 8 waves, waves 0-3 -> A, 4-7 -> B -----
// One staged tile (4 rows x 64 px), each wave one output row of one tensor.
__global__ __launch_bounds__(512, 2)
void fconv15w_k(const u16* __restrict__ incl, const u16* __restrict__ wtA,
                const u16* __restrict__ wtB, const float* __restrict__ biasA,
                const float* __restrict__ biasB, u16* __restrict__ outA,
                u16* __restrict__ outB)
{
  __shared__ __align__(16) char s_mem[40960];  // staging 31680 B; restage 8x5120
  u16* s_in = (u16*)s_mem;

  const int tid = threadIdx.x;
  const int q8 = (int)gridDim.x >> 3;
  const int bid = ((int)blockIdx.x & 7) * q8 + ((int)blockIdx.x >> 3);
  const int n = bid >> 8;
  const int tb = bid & 255;
  const int y0 = (tb >> 2) << 2;
  const int x0 = (tb & 3) << 6;

  const u16* src = incl + (size_t)n * IMG_CL + ((size_t)y0 * IW + x0) * CH;
  #pragma unroll
  for (int k = 0; k < 4; ++k) {            // 1980 16B chunks, lane-linear LDS
    int i = tid + (k << 9);
    if (i < 1980) {
      int r = i / 330, o = i - r * 330;
      GLDS16(src + (size_t)r * IWCH + o * 8, s_in + i * 8);
    }
  }
  __syncthreads();

  const int w = tid >> 6;
  const bool isA = (w < 4);
  const int ry = w & 3;                    // output row within strip
  const int l = tid & 63;
  const int g = l >> 4;
  const int m = l & 15;

  const u16* wt = isA ? wtA : wtB;
  const float* bias = isA ? biasA : biasB;

  f32x4 acc[4][3];
  #pragma unroll
  for (int xt = 0; xt < 4; ++xt)
    #pragma unroll
    for (int tt = 0; tt < 3; ++tt) acc[xt][tt] = (f32x4){0.f, 0.f, 0.f, 0.f};

  #pragma unroll
  for (int s = 0; s < 12; ++s) {
    const int dy = s >> 2;
    const int c = ((s & 3) << 2) + g;      // k-chunk id 0..15
    int dx, icb;
    if (c >= 15)      { dx = 0; icb = 0; }     // zero-weight pad chunk
    else if (c >= 10) { dx = 2; icb = (c - 10) * 8; }
    else if (c >= 5)  { dx = 1; icb = (c - 5) * 8; }
    else              { dx = 0; icb = c * 8; }
    const int abase = (ry + dy) * (66 * CH) + (m + dx) * CH + icb;
    bf16x8 a0 = *(const bf16x8*)(s_in + abase);
    bf16x8 a1 = *(const bf16x8*)(s_in + abase + 16 * CH);
    bf16x8 a2 = *(const bf16x8*)(s_in + abase + 32 * CH);
    bf16x8 a3 = *(const bf16x8*)(s_in + abase + 48 * CH);
    const int wb = s * 32 + g * 8;
    #pragma unroll
    for (int tt = 0; tt < 3; ++tt) {
      bf16x8 bW = *(const bf16x8*)(wt + (m + 16 * tt) * 384 + wb);
      acc[0][tt] = __builtin_amdgcn_mfma_f32_16x16x32_bf16(bW, a0, acc[0][tt], 0, 0, 0);
      acc[1][tt] = __builtin_amdgcn_mfma_f32_16x16x32_bf16(bW, a1, acc[1][tt], 0, 0, 0);
      acc[2][tt] = __builtin_amdgcn_mfma_f32_16x16x32_bf16(bW, a2, acc[2][tt], 0, 0, 0);
      acc[3][tt] = __builtin_amdgcn_mfma_f32_16x16x32_bf16(bW, a3, acc[3][tt], 0, 0, 0);
    }
  }

  const int y = y0 + ry;
  const int ACT = isA ? 1 : 2;
  __syncthreads();                         // all waves done reading s_in

  // per-wave restage region: exactly 5120 B (XOR swizzle stays inside)
  char* so = s_mem + w * 5120;
  float4 bv[3];
  bv[0] = *(const float4*)(bias + 4 * g);
  bv[1] = *(const float4*)(bias + 16 + 4 * g);
  bv[2] = (g < 2) ? *(const float4*)(bias + 32 + 4 * g)
                  : make_float4(0.f, 0.f, 0.f, 0.f);
  #pragma unroll
  for (int tt = 0; tt < 3; ++tt) {
    if (tt == 2 && g >= 2) continue;       // oc >= 40: padding
    #pragma unroll
    for (int xt = 0; xt < 4; ++xt) {
      const int pxl = xt * 16 + m;
      float v[4];
      #pragma unroll
      for (int i = 0; i < 4; ++i)
        v[i] = actf(acc[xt][tt][i] + ((const float*)&bv[tt])[i], ACT);
      uint2 pk;
      pk.x = (u32)f2b(v[0]) | ((u32)f2b(v[1]) << 16);
      pk.y = (u32)f2b(v[2]) | ((u32)f2b(v[3]) << 16);
      int byt = pxl * 80 + (16 * tt + 4 * g) * 2;
      byt ^= ((pxl >> 3) & 7) << 4;
      *(uint2*)(so + byt) = pk;
    }
  }
  u16* dst = isA ? outA : outB;
  const size_t rowu = (size_t)n * IMG_CL + ((size_t)(y + 1) * IW + (x0 + 1)) * CH;
  #pragma unroll
  for (int q = 0; q < 5; ++q) {
    int byt = l * 80 + q * 16;
    byt ^= ((l >> 3) & 7) << 4;
    uint4 d = *(const uint4*)(so + byt);
    *(uint4*)(dst + rowu + (size_t)l * 40 + q * 8) = d;
  }
}

// ---- MFMA implicit-GEMM conv 3x3 pad 1, 8 rows x 64 px, 8 waves ----------
template<int ACT, bool RES, bool PLANAR_OUT>
__global__ __launch_bounds__(512, 4)
void convm_k(const u16* __restrict__ incl, const u16* __restrict__ wt,
             const float* __restrict__ bias, const u16* __restrict__ rescl,
             void* __restrict__ outp)
{
  __shared__ u16 s_in[10 * 66 * CH];       // 52800 B; head reused as out-stage

  const int tid = threadIdx.x;
  const int q8 = (int)gridDim.x >> 3;
  const int bid = ((int)blockIdx.x & 7) * q8 + ((int)blockIdx.x >> 3);
  const int n = bid >> 7;
  const int tb = bid & 127;
  const int y0 = (tb >> 2) << 3;           // 32 y-tiles of 8 rows
  const int x0 = (tb & 3) << 6;

  const u16* src = incl + (size_t)n * IMG_CL + ((size_t)y0 * IW + x0) * CH;
  for (int k = 0; k < 7; ++k) {            // 3300 16B chunks, lane-linear LDS
    int i = tid + (k << 9);
    if (i < 3300) {
      int r = i / 330, o = i - r * 330;
      GLDS16(src + (size_t)r * IWCH + o * 8, s_in + i * 8);
    }
  }
  __syncthreads();

  const int w = tid >> 6;                  // wave -> output row y0+w (0..7)
  const int l = tid & 63;
  const int g = l >> 4;
  const int m = l & 15;

  f32x4 acc[4][3];
  #pragma unroll
  for (int xt = 0; xt < 4; ++xt)
    #pragma unroll
    for (int t = 0; t < 3; ++t) acc[xt][t] = (f32x4){0.f, 0.f, 0.f, 0.f};

  bf16x8 aC[4], bC[3], aN[4], bN[3];
  auto lf = [&](int s, bf16x8* A, bf16x8* B) {
    const int dy = s >> 2;
    const int c = ((s & 3) << 2) + g;
    int dx, icb;
    if (c >= 15)      { dx = 0; icb = 0; }
    else if (c >= 10) { dx = 2; icb = (c - 10) * 8; }
    else if (c >= 5)  { dx = 1; icb = (c - 5) * 8; }
    else              { dx = 0; icb = c * 8; }
    const int abase = (w + dy) * (66 * CH) + (m + dx) * CH + icb;
    A[0] = *(const bf16x8*)(s_in + abase);
    A[1] = *(const bf16x8*)(s_in + abase + 16 * CH);
    A[2] = *(const bf16x8*)(s_in + abase + 32 * CH);
    A[3] = *(const bf16x8*)(s_in + abase + 48 * CH);
    const int wb = s * 32 + g * 8;
    B[0] = *(const bf16x8*)(wt + m * 384 + wb);
    B[1] = *(const bf16x8*)(wt + (m + 16) * 384 + wb);
    B[2] = *(const bf16x8*)(wt + (m + 32) * 384 + wb);
  };

  lf(0, aC, bC);
  #pragma unroll
  for (int s = 0; s < 12; ++s) {
    if (s < 11) lf(s + 1, aN, bN);
    #pragma unroll
    for (int t = 0; t < 3; ++t)
      #pragma unroll
      for (int xt = 0; xt < 4; ++xt)
        acc[xt][t] = PLANAR_OUT
          ? __builtin_amdgcn_mfma_f32_16x16x32_bf16(aC[xt], bC[t], acc[xt][t], 0, 0, 0)
          : __builtin_amdgcn_mfma_f32_16x16x32_bf16(bC[t], aC[xt], acc[xt][t], 0, 0, 0);
    if (s < 11) {
      #pragma unroll
      for (int q = 0; q < 4; ++q) aC[q] = aN[q];
      #pragma unroll
      for (int q = 0; q < 3; ++q) bC[q] = bN[q];
    }
  }

  const int y = y0 + w;

  if (PLANAR_OUT) {
    const float bv0 = bias[m];
    const float bv1 = bias[m + 16];
    const float bv2 = (m < 8) ? bias[m + 32] : 0.f;
    #pragma unroll
    for (int t = 0; t < 3; ++t) {
      const int oc = m + 16 * t;
      if (t == 2 && m >= 8) continue;
      const float bv = (t == 0) ? bv0 : (t == 1) ? bv1 : bv2;
      #pragma unroll
      for (int xt = 0; xt < 4; ++xt) {
        const int xb = x0 + xt * 16 + 4 * g;
        float v[4];
        #pragma unroll
        for (int i = 0; i < 4; ++i) v[i] = actf(acc[xt][t][i] + bv, ACT);
        *(float4*)((float*)outp + (((size_t)(n * CH + oc)) << 16) + ((size_t)y << 8) + xb)
            = make_float4(v[0], v[1], v[2], v[3]);
      }
    }
  } else {
    __syncthreads();
    u16* s_out = s_in + w * 3072;          // per-wave 6144 B (8 x 6144 <= 52800)
    float4 bv[3];
    bv[0] = *(const float4*)(bias + 4 * g);
    bv[1] = *(const float4*)(bias + 16 + 4 * g);
    bv[2] = (g < 2) ? *(const float4*)(bias + 32 + 4 * g)
                    : make_float4(0.f, 0.f, 0.f, 0.f);
    #pragma unroll
    for (int t = 0; t < 3; ++t) {
      if (t == 2 && g >= 2) continue;
      #pragma unroll
      for (int xt = 0; xt < 4; ++xt) {
        const int pxl = xt * 16 + m;
        float v[4];
        #pragma unroll
        for (int i = 0; i < 4; ++i)
          v[i] = actf(acc[xt][t][i] + ((const float*)&bv[t])[i], ACT);
        uint2 pk;
        pk.x = (u32)f2b(v[0]) | ((u32)f2b(v[1]) << 16);
        pk.y = (u32)f2b(v[2]) | ((u32)f2b(v[3]) << 16);
        int byt = pxl * 80 + (16 * t + 4 * g) * 2;
        byt ^= ((pxl >> 3) & 7) << 4;
        *(uint2*)((char*)s_out + byt) = pk;
      }
    }
    const size_t rowu = (size_t)n * IMG_CL + ((size_t)(y + 1) * IW + (x0 + 1)) * CH;
    #pragma unroll
    for (int q = 0; q < 5; ++q) {
      int byt = l * 80 + q * 16;
      byt ^= ((l >> 3) & 7) << 4;
      uint4 d = *(const uint4*)((const char*)s_out + byt);
      if (RES) {
        uint4 rv = *(const uint4*)(rescl + rowu + (size_t)l * 40 + q * 8);
        d.x = addbf2(d.x, rv.x); d.y = addbf2(d.y, rv.y);
        d.z = addbf2(d.z, rv.z); d.w = addbf2(d.w, rv.w);
      }
      *(uint4*)((u16*)outp + rowu + (size_t)l * 40 + q * 8) = d;
    }
  }
}

// ---- depthwise conv k3 s8 p2 d2 on cl bf16 -> planar f32 (8,40,32,32) ----
__global__ __launch_bounds__(256)
void dwconv_k(const u16* __restrict__ incl, const float* __restrict__ w,
              const float* __restrict__ b, float* __restrict__ out)
{
  int idx = blockIdx.x * 256 + threadIdx.x;
  if (idx >= 8 * 32 * 32 * CH) return;
  int c = idx % CH;
  int p = idx / CH;
  int ox = p & 31;
  int oy = (p >> 5) & 31;
  int n = p >> 10;
  float acc = b[c];
  const u16* ip = incl + (size_t)n * IMG_CL;
  #pragma unroll
  for (int dy = 0; dy < 3; ++dy) {
    int y = oy * 8 - 2 + dy * 2;
    if ((unsigned)y >= 256u) continue;
    #pragma unroll
    for (int dx = 0; dx < 3; ++dx) {
      int x = ox * 8 - 2 + dx * 2;
      if ((unsigned)x >= 256u) continue;
      acc += w[c * 9 + dy * 3 + dx] * b2f(ip[((size_t)(y + 1) * IW + (x + 1)) * CH + c]);
    }
  }
  out[((size_t)(n * CH + c) << 10) + oy * 32 + ox] = acc;
}

// ---- per-8x8-block iDCT on planar f32 32x32 ------------------------------
__global__ __launch_bounds__(256)
void idct8_k(const float* __restrict__ in, float* __restrict__ out)
{
  __shared__ float ctab[8];
  if (threadIdx.x < 8) {
    const float c_[8] = {1.f, 0.70710678118654752f, 0.f, -0.70710678118654752f,
                         -1.f, -0.70710678118654752f, 0.f, 0.70710678118654752f};
    ctab[threadIdx.x] = c_[threadIdx.x];
  }
  __syncthreads();
  int idx = blockIdx.x * 256 + threadIdx.x;
  if (idx >= 8 * CH * 32 * 32) return;
  int ox = idx & 31, oy = (idx >> 5) & 31, bc = idx >> 10;
  int k = oy & 7, lq = ox & 7;
  const float* ip = in + bc * 1024 + (oy & ~7) * 32 + (ox & ~7);
  float acc = 0.f;
  #pragma unroll
  for (int mm = 0; mm < 8; ++mm) {
    float rk = ctab[(k * mm) & 7];
    float s = 0.f;
    #pragma unroll
    for (int nn = 0; nn < 8; ++nn)
      s += ctab[(lq * nn) & 7] * ip[mm * 32 + nn];
    acc += rk * s;
  }
  out[idx] = acc * 0.125f;
}

// ---- MFMA 1x1 conv + sigmoid + bilinear(32->256) multiply; cl bf16 -------
__global__ __launch_bounds__(256)
void wgtmul_k(const u16* __restrict__ t1cl, const u16* __restrict__ wt3,
              const float* __restrict__ b3, const float* __restrict__ dct,
              u16* __restrict__ outcl)
{
  __shared__ float s_yw[40 * 33];
  __shared__ u16 s_out[4 * 3072];

  const int q8 = (int)gridDim.x >> 3;
  const int bid = ((int)blockIdx.x & 7) * q8 + ((int)blockIdx.x >> 3);
  const int n = bid >> 8;
  const int y = bid & 255;
  const int tid = threadIdx.x;

  float sy = (y + 0.5f) * 0.125f - 0.5f;
  float yq = floorf(sy);
  float fy = sy - yq;
  int y0c = max((int)yq, 0), y1c = min((int)yq + 1, 31);

  for (int i = tid; i < 1280; i += 256) {
    int oc = i >> 5, c = i & 31;
    const float* sp = dct + ((size_t)(n * CH + oc) << 10);
    s_yw[oc * 33 + c] = (1.f - fy) * sp[y0c * 32 + c] + fy * sp[y1c * 32 + c];
  }
  __syncthreads();

  const int w = tid >> 6;
  const int l = tid & 63;
  const int g = l >> 4;
  const int m = l & 15;
  const int xb = w << 6;

  const u16* tp = t1cl + (size_t)n * IMG_CL + ((size_t)(y + 1) * IW + 1) * CH;

  f32x4 acc[4][3];
  #pragma unroll
  for (int xt = 0; xt < 4; ++xt)
    #pragma unroll
    for (int t = 0; t < 3; ++t) acc[xt][t] = (f32x4){0.f, 0.f, 0.f, 0.f};

  #pragma unroll
  for (int xt = 0; xt < 4; ++xt) {
    const u16* ap = tp + (size_t)(xb + xt * 16 + m) * CH;
    bf16x8 a0 = *(const bf16x8*)(ap + 8 * g);
    bf16x8 a1 = *(const bf16x8*)(ap + 32 + 8 * g);
    #pragma unroll
    for (int t = 0; t < 3; ++t) {
      bf16x8 b0 = *(const bf16x8*)(wt3 + (m + 16 * t) * 384 + 8 * g);
      bf16x8 b1 = *(const bf16x8*)(wt3 + (m + 16 * t) * 384 + 32 + 8 * g);
      acc[xt][t] = __builtin_amdgcn_mfma_f32_16x16x32_bf16(b0, a0, acc[xt][t], 0, 0, 0);
      acc[xt][t] = __builtin_amdgcn_mfma_f32_16x16x32_bf16(b1, a1, acc[xt][t], 0, 0, 0);
    }
  }

  u16* so = s_out + w * 3072;
  float4 bv[3];
  bv[0] = *(const float4*)(b3 + 4 * g);
  bv[1] = *(const float4*)(b3 + 16 + 4 * g);
  bv[2] = (g < 2) ? *(const float4*)(b3 + 32 + 4 * g) : make_float4(0.f, 0.f, 0.f, 0.f);
  #pragma unroll
  for (int t = 0; t < 3; ++t) {
    if (t == 2 && g >= 2) continue;
    #pragma unroll
    for (int xt = 0; xt < 4; ++xt) {
      const int pxl = xt * 16 + m;
      const int px = xb + pxl;
      float sx = (px + 0.5f) * 0.125f - 0.5f;
      float xq = floorf(sx);
      float fx = sx - xq;
      int x0c = max((int)xq, 0), x1c = min((int)xq + 1, 31);
      u16 r4[4];
      #pragma unroll
      for (int i = 0; i < 4; ++i) {
        int oc = 16 * t + 4 * g + i;
        float wgt = 1.f / (1.f + expf(-(acc[xt][t][i] + ((const float*)&bv[t])[i])));
        float bil = (1.f - fx) * s_yw[oc * 33 + x0c] + fx * s_yw[oc * 33 + x1c];
        r4[i] = f2b(wgt * bil);
      }
      uint2 pk;
      pk.x = (u32)r4[0] | ((u32)r4[1] << 16);
      pk.y = (u32)r4[2] | ((u32)r4[3] << 16);
      int byt = pxl * 80 + (16 * t + 4 * g) * 2;
      byt ^= ((pxl >> 3) & 7) << 4;
      *(uint2*)((char*)so + byt) = pk;
    }
  }
  const size_t rowu = (size_t)n * IMG_CL + ((size_t)(y + 1) * IW + (xb + 1)) * CH;
  #pragma unroll
  for (int q = 0; q < 5; ++q) {
    int byt = l * 80 + q * 16;
    byt ^= ((l >> 3) & 7) << 4;
    uint4 d = *(const uint4*)((const char*)so + byt);
    *(uint4*)(outcl + rowu + (size_t)l * 40 + q * 8) = d;
  }
}

extern "C" void kernel_launch(void* const* d_in, const int* in_sizes, int n_in,
                              void* d_out, int out_size, void* d_ws, size_t ws_size,
                              hipStream_t stream)
{
  const float* x       = (const float*)d_in[0];
  const float* conv_w  = (const float*)d_in[1];
  const float* conv_b  = (const float*)d_in[2];
  const float* ddct_w  = (const float*)d_in[3];
  const float* ddct_b  = (const float*)d_in[4];
  const float* dctc_w  = (const float*)d_in[5];
  const float* dctc_b  = (const float*)d_in[6];
  const float* w1_w    = (const float*)d_in[7];
  const float* w1_b    = (const float*)d_in[8];
  const float* w3_w    = (const float*)d_in[9];
  const float* w3_b    = (const float*)d_in[10];
  const float* after_w = (const float*)d_in[11];
  const float* after_b = (const float*)d_in[12];

  char* ws = (char*)d_ws;
  const size_t CLB = (size_t)8 * IMG_CL * 2;          // 42,600,960 B
  u16*   xcl    = (u16*)ws;                           // x, later dd
  u16*   cl_a   = (u16*)(ws + CLB);                   // dct_feat, later prod
  u16*   cl_c   = (u16*)(ws + 2 * CLB);               // t1
  float* small0 = (float*)(ws + 3 * CLB);             // 1,310,720 B
  float* small1 = (float*)(ws + 3 * CLB + 1310720);   // 1,310,720 B
  u16*   wt     = (u16*)(ws + 3 * CLB + 2621440);     // 184,320 B (5 sets)

  // 0. weight transform + input cl conversion + ring zeroing (xcl, cl_a)
  prep_w_k<<<360, 256, 0, stream>>>(conv_w, ddct_w, w1_w, after_w, w3_w, wt);
  prep_x_k<<<8 * IW, 256, 0, stream>>>(x, xcl, cl_a);
  // 1+5. dct_feat = gelu(conv(x)) -> cl_a ; t1 = relu(conv(x,w1)) -> cl_c
  fconv15w_k<<<2048, 512, 0, stream>>>(xcl, wt, wt + 2 * WT_SET, conv_b, w1_b,
                                       cl_a, cl_c);
  // 2. dd = gelu(conv(dct_feat)) + dct_feat        -> xcl (x dead)
  convm_k<1, true, false><<<1024, 512, 0, stream>>>(cl_a, wt + WT_SET, ddct_b, cl_a, xcl);
  // 3. depthwise strided conv                      -> small0
  dwconv_k<<<1280, 256, 0, stream>>>(xcl, dctc_w, dctc_b, small0);
  // 4. per-block 8x8 iDCT                          -> small1
  idct8_k<<<1280, 256, 0, stream>>>(small0, small1);
  // 6. prod = sigmoid(1x1(t1)) * bilinear(idct)    -> cl_a (dct_feat dead)
  wgtmul_k<<<2048, 256, 0, stream>>>(cl_c, wt + 4 * WT_SET, w3_b, small1, cl_a);
  // 7. out = conv(prod, after)                     -> d_out fp32 planar
  convm_k<0, false, true><<<1024, 512, 0, stream>>>(cl_a, wt + 3 * WT_SET, after_b, nullptr, (void*)d_out);
}

// Round 10
// 272.336 us; speedup vs baseline: 1.4411x; 1.1135x over previous
//
#include <hip/hip_runtime.h>

typedef unsigned short u16;
typedef unsigned int u32;
typedef __attribute__((ext_vector_type(8))) short bf16x8;
typedef __attribute__((ext_vector_type(4))) float f32x4;

#define CH 40
#define IW 258                   // ring-padded width (256 + 2)
#define IWCH (IW * CH)           // 10320
#define IMG_CL (IW * IW * CH)    // u16 elements per image, channel-last padded
#define WT_SET (48 * 384)        // u16 per weight set (row-major, global-read path)
#define WCM_SET (48 * 40 * 8)    // u16 per chunk-major set (LDS path) = 15360

#define GLDS16(g, l) __builtin_amdgcn_global_load_lds( \
    (const __attribute__((address_space(1))) void*)(g), \
    (__attribute__((address_space(3))) void*)(l), 16, 0, 0)

__device__ __forceinline__ float b2f(u16 u) {
  union { u32 i; float f; } v; v.i = ((u32)u) << 16; return v.f;
}
__device__ __forceinline__ u16 f2b(float f) {
  union { float f; u32 i; } v; v.f = f;
  u32 r = v.i + 0x7fffu + ((v.i >> 16) & 1u);
  return (u16)(r >> 16);
}
__device__ __forceinline__ u32 addbf2(u32 a, u32 b) {
  union { u32 i; float f; } lo_a, lo_b, hi_a, hi_b;
  lo_a.i = a << 16; lo_b.i = b << 16;
  hi_a.i = a & 0xffff0000u; hi_b.i = b & 0xffff0000u;
  float lo = lo_a.f + lo_b.f, hi = hi_a.f + hi_b.f;
  return (u32)f2b(lo) | ((u32)f2b(hi) << 16);
}
// tanh-approx gelu: |err vs exact erf-gelu| <= ~3.2e-4, branch-free, __expf HW exp
__device__ __forceinline__ float actf(float t, int ACT) {
  if (ACT == 1) {
    float u2 = t * (1.5957691216057308f + 0.07135481627000862f * t * t); // 2*0.79788456*(t+0.044715t^3)
    float e = __expf(u2);
    return t - t / (e + 1.f);        // t*(1 - 1/(e+1)) = 0.5t(1+tanh(u))
  }
  if (ACT == 2) return fmaxf(t, 0.f);
  return t;
}

// ---- weights -> Wt bf16 [48][384] x5 sets + chunk-major [48][40][8] x2 ----
__global__ __launch_bounds__(256)
void prep_w_k(const float* __restrict__ w0, const float* __restrict__ w1,
              const float* __restrict__ w2, const float* __restrict__ w3,
              const float* __restrict__ w4, u16* __restrict__ wt,
              u16* __restrict__ wcm)
{
  int i = blockIdx.x * 256 + threadIdx.x;      // 92160 + 30720 = 122880
  if (i >= 5 * WT_SET + 2 * WCM_SET) return;
  if (i < 5 * WT_SET) {
    int k = i % 384;
    int oc = (i / 384) % 48;
    int set = i / WT_SET;
    u16 v = 0;
    if (set == 4) {
      if (oc < 40 && k < 40) v = f2b(w4[oc * 40 + k]);
    } else {
      int dy = k >> 7;
      int r = k & 127;
      if (oc < 40 && r < 120) {
        int dx = r / 40;
        int ic = r - dx * 40;
        const float* w = (set == 0) ? w0 : (set == 1) ? w1 : (set == 2) ? w2 : w3;
        v = f2b(w[((oc * 40 + ic) * 3 + dy) * 3 + dx]);
      }
    }
    wt[i] = v;
  } else {
    int j = i - 5 * WT_SET;
    int set2 = j / WCM_SET;                    // 0 -> conv_w, 1 -> w1_w
    int r2 = j - set2 * WCM_SET;
    int c = r2 / 320;                          // k-chunk 0..47
    int rem = r2 - c * 320;
    int oc = rem >> 3;
    int e = rem & 7;
    int k = c * 8 + e;
    int dy = k >> 7;
    int r = k & 127;
    u16 v = 0;
    if (r < 120) {
      int dx = r / 40;
      int ic = r - dx * 40;
      const float* w = set2 ? w2 : w0;
      v = f2b(w[((oc * 40 + ic) * 3 + dy) * 3 + dx]);
    }
    wcm[j] = v;
  }
}

// ---- x fp32 planar -> xcl bf16 channel-last + zero rings of xcl, cla -----
__global__ __launch_bounds__(256)
void prep_x_k(const float* __restrict__ x, u16* __restrict__ xcl,
              u16* __restrict__ cla)
{
  const int n = blockIdx.x / IW;
  const int yr = blockIdx.x % IW;
  const int t = threadIdx.x;
  const size_t base = (size_t)n * IMG_CL + (size_t)yr * IWCH;
  const uint4 z = {0u, 0u, 0u, 0u};

  if (yr == 0 || yr == IW - 1) {
    for (int i = t; i < IWCH / 8; i += 256) {
      ((uint4*)(xcl + base))[i] = z;
      ((uint4*)(cla + base))[i] = z;
    }
    return;
  }
  if (t < 5) {
    ((uint4*)(xcl + base))[t] = z;
    ((uint4*)(cla + base))[t] = z;
  } else if (t < 10) {
    size_t b2 = base + (size_t)(IW - 1) * CH;
    ((uint4*)(xcl + b2))[t - 5] = z;
    ((uint4*)(cla + b2))[t - 5] = z;
  }
  const int y = yr - 1;
  const float* xp = x + (size_t)n * CH * 65536 + (size_t)y * 256 + t;
  __attribute__((aligned(16))) u16 buf[40];
  #pragma unroll
  for (int ic = 0; ic < 40; ++ic) buf[ic] = f2b(xp[(size_t)ic * 65536]);
  u16* dst = xcl + base + (size_t)(t + 1) * CH;
  #pragma unroll
  for (int q = 0; q < 5; ++q) ((uint4*)dst)[q] = ((const uint4*)buf)[q];
}

// ---- all-LDS-operand MFMA conv 3x3: input tile AND weight set in LDS -----
// 256 thr / 4 waves, wave = row; weights chunk-major [48ch][40oc][8k] in LDS.
template<int ACT>
__global__ __launch_bounds__(256, 2)
void convl_k(const u16* __restrict__ incl, const u16* __restrict__ wcm,
             const float* __restrict__ bias, u16* __restrict__ outcl)
{
  __shared__ __align__(16) u16 s_mem[31200];   // 62400 B: input 15840 + weights 15360
  u16* s_in = s_mem;
  u16* s_w  = s_mem + 15840;

  const int tid = threadIdx.x;
  const int bid = ((int)blockIdx.x & 7) * 256 + ((int)blockIdx.x >> 3);
  const int n = bid >> 8;
  const int tb = bid & 255;
  const int y0 = (tb >> 2) << 2;
  const int x0 = (tb & 3) << 6;

  const u16* src = incl + (size_t)n * IMG_CL + ((size_t)y0 * IW + x0) * CH;
  #pragma unroll
  for (int k = 0; k < 8; ++k) {                // input: 1980 x 16B, lane-linear
    int i = tid + (k << 8);
    if (i < 1980) {
      int r = i / 330, o = i - r * 330;
      GLDS16(src + (size_t)r * IWCH + o * 8, s_in + i * 8);
    }
  }
  #pragma unroll
  for (int k = 0; k < 8; ++k) {                // weights: 1920 x 16B linear (L2-hot)
    int i = tid + (k << 8);
    if (i < 1920) GLDS16(wcm + i * 8, s_w + i * 8);
  }
  __syncthreads();

  const int w = tid >> 6;                      // wave -> output row y0+w
  const int l = tid & 63;
  const int g = l >> 4;
  const int m = l & 15;

  f32x4 acc[4][3];
  #pragma unroll
  for (int xt = 0; xt < 4; ++xt)
    #pragma unroll
    for (int tt = 0; tt < 3; ++tt) acc[xt][tt] = (f32x4){0.f, 0.f, 0.f, 0.f};

  #pragma unroll
  for (int s = 0; s < 12; ++s) {
    const int dy = s >> 2;
    const int c = ((s & 3) << 2) + g;          // within-dy k-chunk 0..15
    int dx, icb;
    if (c >= 15)      { dx = 0; icb = 0; }     // zero-weight pad chunk
    else if (c >= 10) { dx = 2; icb = (c - 10) * 8; }
    else if (c >= 5)  { dx = 1; icb = (c - 5) * 8; }
    else              { dx = 0; icb = c * 8; }
    const int abase = (w + dy) * (66 * CH) + (m + dx) * CH + icb;
    bf16x8 a0 = *(const bf16x8*)(s_in + abase);
    bf16x8 a1 = *(const bf16x8*)(s_in + abase + 16 * CH);
    bf16x8 a2 = *(const bf16x8*)(s_in + abase + 32 * CH);
    bf16x8 a3 = *(const bf16x8*)(s_in + abase + 48 * CH);

    const int ch = (s << 2) + g;               // global k-chunk 0..47
    const u16* wrow = s_w + ch * 320;          // [40 oc][8] u16
    bf16x8 b0 = *(const bf16x8*)(wrow + m * 8);
    bf16x8 b1 = *(const bf16x8*)(wrow + (m + 16) * 8);
    bf16x8 b2 = *(const bf16x8*)(wrow + (m >= 8 ? 312 : (m + 32) * 8)); // clamp; rows 40+ discarded

    acc[0][0] = __builtin_amdgcn_mfma_f32_16x16x32_bf16(b0, a0, acc[0][0], 0, 0, 0);
    acc[1][0] = __builtin_amdgcn_mfma_f32_16x16x32_bf16(b0, a1, acc[1][0], 0, 0, 0);
    acc[2][0] = __builtin_amdgcn_mfma_f32_16x16x32_bf16(b0, a2, acc[2][0], 0, 0, 0);
    acc[3][0] = __builtin_amdgcn_mfma_f32_16x16x32_bf16(b0, a3, acc[3][0], 0, 0, 0);
    acc[0][1] = __builtin_amdgcn_mfma_f32_16x16x32_bf16(b1, a0, acc[0][1], 0, 0, 0);
    acc[1][1] = __builtin_amdgcn_mfma_f32_16x16x32_bf16(b1, a1, acc[1][1], 0, 0, 0);
    acc[2][1] = __builtin_amdgcn_mfma_f32_16x16x32_bf16(b1, a2, acc[2][1], 0, 0, 0);
    acc[3][1] = __builtin_amdgcn_mfma_f32_16x16x32_bf16(b1, a3, acc[3][1], 0, 0, 0);
    acc[0][2] = __builtin_amdgcn_mfma_f32_16x16x32_bf16(b2, a0, acc[0][2], 0, 0, 0);
    acc[1][2] = __builtin_amdgcn_mfma_f32_16x16x32_bf16(b2, a1, acc[1][2], 0, 0, 0);
    acc[2][2] = __builtin_amdgcn_mfma_f32_16x16x32_bf16(b2, a2, acc[2][2], 0, 0, 0);
    acc[3][2] = __builtin_amdgcn_mfma_f32_16x16x32_bf16(b2, a3, acc[3][2], 0, 0, 0);
  }

  const int y = y0 + w;
  __syncthreads();                             // all K-loop LDS reads done

  char* so = (char*)s_mem + w * 5120;          // per-wave restage region (<=20480B)
  float4 bv[3];
  bv[0] = *(const float4*)(bias + 4 * g);
  bv[1] = *(const float4*)(bias + 16 + 4 * g);
  bv[2] = (g < 2) ? *(const float4*)(bias + 32 + 4 * g)
                  : make_float4(0.f, 0.f, 0.f, 0.f);
  #pragma unroll
  for (int tt = 0; tt < 3; ++tt) {
    if (tt == 2 && g >= 2) continue;           // oc >= 40: padding
    #pragma unroll
    for (int xt = 0; xt < 4; ++xt) {
      const int pxl = xt * 16 + m;
      float v[4];
      #pragma unroll
      for (int i = 0; i < 4; ++i)
        v[i] = actf(acc[xt][tt][i] + ((const float*)&bv[tt])[i], ACT);
      uint2 pk;
      pk.x = (u32)f2b(v[0]) | ((u32)f2b(v[1]) << 16);
      pk.y = (u32)f2b(v[2]) | ((u32)f2b(v[3]) << 16);
      int byt = pxl * 80 + (16 * tt + 4 * g) * 2;
      byt ^= ((pxl >> 3) & 7) << 4;
      *(uint2*)(so + byt) = pk;
    }
  }
  const size_t rowu = (size_t)n * IMG_CL + ((size_t)(y + 1) * IW + (x0 + 1)) * CH;
  #pragma unroll
  for (int q = 0; q < 5; ++q) {
    int byt = l * 80 + q * 16;
    byt ^= ((l >> 3) & 7) << 4;
    uint4 d = *(const uint4*)(so + byt);
    *(uint4*)(outcl + rowu + (size_t)l * 40 + q * 8) = d;
  }
}

// ---- MFMA implicit-GEMM conv 3x3 pad 1, 8 rows x 64 px, 8 waves (r9) -----
template<int ACT, bool RES, bool PLANAR_OUT>
__global__ __launch_bounds__(512, 4)
void convm_k(const u16* __restrict__ incl, const u16* __restrict__ wt,
             const float* __restrict__ bias, const u16* __restrict__ rescl,
             void* __restrict__ outp)
{
  __shared__ u16 s_in[10 * 66 * CH];       // 52800 B; head reused as out-stage

  const int tid = threadIdx.x;
  const int q8 = (int)gridDim.x >> 3;
  const int bid = ((int)blockIdx.x & 7) * q8 + ((int)blockIdx.x >> 3);
  const int n = bid >> 7;
  const int tb = bid & 127;
  const int y0 = (tb >> 2) << 3;
  const int x0 = (tb & 3) << 6;

  const u16* src = incl + (size_t)n * IMG_CL + ((size_t)y0 * IW + x0) * CH;
  for (int k = 0; k < 7; ++k) {
    int i = tid + (k << 9);
    if (i < 3300) {
      int r = i / 330, o = i - r * 330;
      GLDS16(src + (size_t)r * IWCH + o * 8, s_in + i * 8);
    }
  }
  __syncthreads();

  const int w = tid >> 6;
  const int l = tid & 63;
  const int g = l >> 4;
  const int m = l & 15;

  f32x4 acc[4][3];
  #pragma unroll
  for (int xt = 0; xt < 4; ++xt)
    #pragma unroll
    for (int t = 0; t < 3; ++t) acc[xt][t] = (f32x4){0.f, 0.f, 0.f, 0.f};

  bf16x8 aC[4], bC[3], aN[4], bN[3];
  auto lf = [&](int s, bf16x8* A, bf16x8* B) {
    const int dy = s >> 2;
    const int c = ((s & 3) << 2) + g;
    int dx, icb;
    if (c >= 15)      { dx = 0; icb = 0; }
    else if (c >= 10) { dx = 2; icb = (c - 10) * 8; }
    else if (c >= 5)  { dx = 1; icb = (c - 5) * 8; }
    else              { dx = 0; icb = c * 8; }
    const int abase = (w + dy) * (66 * CH) + (m + dx) * CH + icb;
    A[0] = *(const bf16x8*)(s_in + abase);
    A[1] = *(const bf16x8*)(s_in + abase + 16 * CH);
    A[2] = *(const bf16x8*)(s_in + abase + 32 * CH);
    A[3] = *(const bf16x8*)(s_in + abase + 48 * CH);
    const int wb = s * 32 + g * 8;
    B[0] = *(const bf16x8*)(wt + m * 384 + wb);
    B[1] = *(const bf16x8*)(wt + (m + 16) * 384 + wb);
    B[2] = *(const bf16x8*)(wt + (m + 32) * 384 + wb);
  };

  lf(0, aC, bC);
  #pragma unroll
  for (int s = 0; s < 12; ++s) {
    if (s < 11) lf(s + 1, aN, bN);
    #pragma unroll
    for (int t = 0; t < 3; ++t)
      #pragma unroll
      for (int xt = 0; xt < 4; ++xt)
        acc[xt][t] = PLANAR_OUT
          ? __builtin_amdgcn_mfma_f32_16x16x32_bf16(aC[xt], bC[t], acc[xt][t], 0, 0, 0)
          : __builtin_amdgcn_mfma_f32_16x16x32_bf16(bC[t], aC[xt], acc[xt][t], 0, 0, 0);
    if (s < 11) {
      #pragma unroll
      for (int q = 0; q < 4; ++q) aC[q] = aN[q];
      #pragma unroll
      for (int q = 0; q < 3; ++q) bC[q] = bN[q];
    }
  }

  const int y = y0 + w;

  if (PLANAR_OUT) {
    const float bv0 = bias[m];
    const float bv1 = bias[m + 16];
    const float bv2 = (m < 8) ? bias[m + 32] : 0.f;
    #pragma unroll
    for (int t = 0; t < 3; ++t) {
      const int oc = m + 16 * t;
      if (t == 2 && m >= 8) continue;
      const float bv = (t == 0) ? bv0 : (t == 1) ? bv1 : bv2;
      #pragma unroll
      for (int xt = 0; xt < 4; ++xt) {
        const int xb = x0 + xt * 16 + 4 * g;
        float v[4];
        #pragma unroll
        for (int i = 0; i < 4; ++i) v[i] = actf(acc[xt][t][i] + bv, ACT);
        *(float4*)((float*)outp + (((size_t)(n * CH + oc)) << 16) + ((size_t)y << 8) + xb)
            = make_float4(v[0], v[1], v[2], v[3]);
      }
    }
  } else {
    __syncthreads();
    u16* s_out = s_in + w * 3072;
    float4 bv[3];
    bv[0] = *(const float4*)(bias + 4 * g);
    bv[1] = *(const float4*)(bias + 16 + 4 * g);
    bv[2] = (g < 2) ? *(const float4*)(bias + 32 + 4 * g)
                    : make_float4(0.f, 0.f, 0.f, 0.f);
    #pragma unroll
    for (int t = 0; t < 3; ++t) {
      if (t == 2 && g >= 2) continue;
      #pragma unroll
      for (int xt = 0; xt < 4; ++xt) {
        const int pxl = xt * 16 + m;
        float v[4];
        #pragma unroll
        for (int i = 0; i < 4; ++i)
          v[i] = actf(acc[xt][t][i] + ((const float*)&bv[t])[i], ACT);
        uint2 pk;
        pk.x = (u32)f2b(v[0]) | ((u32)f2b(v[1]) << 16);
        pk.y = (u32)f2b(v[2]) | ((u32)f2b(v[3]) << 16);
        int byt = pxl * 80 + (16 * t + 4 * g) * 2;
        byt ^= ((pxl >> 3) & 7) << 4;
        *(uint2*)((char*)s_out + byt) = pk;
      }
    }
    const size_t rowu = (size_t)n * IMG_CL + ((size_t)(y + 1) * IW + (x0 + 1)) * CH;
    #pragma unroll
    for (int q = 0; q < 5; ++q) {
      int byt = l * 80 + q * 16;
      byt ^= ((l >> 3) & 7) << 4;
      uint4 d = *(const uint4*)((const char*)s_out + byt);
      if (RES) {
        uint4 rv = *(const uint4*)(rescl + rowu + (size_t)l * 40 + q * 8);
        d.x = addbf2(d.x, rv.x); d.y = addbf2(d.y, rv.y);
        d.z = addbf2(d.z, rv.z); d.w = addbf2(d.w, rv.w);
      }
      *(uint4*)((u16*)outp + rowu + (size_t)l * 40 + q * 8) = d;
    }
  }
}

// ---- depthwise conv k3 s8 p2 d2 on cl bf16 -> planar f32 (8,40,32,32) ----
__global__ __launch_bounds__(256)
void dwconv_k(const u16* __restrict__ incl, const float* __restrict__ w,
              const float* __restrict__ b, float* __restrict__ out)
{
  int idx = blockIdx.x * 256 + threadIdx.x;
  if (idx >= 8 * 32 * 32 * CH) return;
  int c = idx % CH;
  int p = idx / CH;
  int ox = p & 31;
  int oy = (p >> 5) & 31;
  int n = p >> 10;
  float acc = b[c];
  const u16* ip = incl + (size_t)n * IMG_CL;
  #pragma unroll
  for (int dy = 0; dy < 3; ++dy) {
    int y = oy * 8 - 2 + dy * 2;
    if ((unsigned)y >= 256u) continue;
    #pragma unroll
    for (int dx = 0; dx < 3; ++dx) {
      int x = ox * 8 - 2 + dx * 2;
      if ((unsigned)x >= 256u) continue;
      acc += w[c * 9 + dy * 3 + dx] * b2f(ip[((size_t)(y + 1) * IW + (x + 1)) * CH + c]);
    }
  }
  out[((size_t)(n * CH + c) << 10) + oy * 32 + ox] = acc;
}

// ---- per-8x8-block iDCT on planar f32 32x32 ------------------------------
__global__ __launch_bounds__(256)
void idct8_k(const float* __restrict__ in, float* __restrict__ out)
{
  __shared__ float ctab[8];
  if (threadIdx.x < 8) {
    const float c_[8] = {1.f, 0.70710678118654752f, 0.f, -0.70710678118654752f,
                         -1.f, -0.70710678118654752f, 0.f, 0.70710678118654752f};
    ctab[threadIdx.x] = c_[threadIdx.x];
  }
  __syncthreads();
  int idx = blockIdx.x * 256 + threadIdx.x;
  if (idx >= 8 * CH * 32 * 32) return;
  int ox = idx & 31, oy = (idx >> 5) & 31, bc = idx >> 10;
  int k = oy & 7, lq = ox & 7;
  const float* ip = in + bc * 1024 + (oy & ~7) * 32 + (ox & ~7);
  float acc = 0.f;
  #pragma unroll
  for (int mm = 0; mm < 8; ++mm) {
    float rk = ctab[(k * mm) & 7];
    float s = 0.f;
    #pragma unroll
    for (int nn = 0; nn < 8; ++nn)
      s += ctab[(lq * nn) & 7] * ip[mm * 32 + nn];
    acc += rk * s;
  }
  out[idx] = acc * 0.125f;
}

// ---- MFMA 1x1 conv + sigmoid + bilinear(32->256) multiply; cl bf16 -------
__global__ __launch_bounds__(256)
void wgtmul_k(const u16* __restrict__ t1cl, const u16* __restrict__ wt3,
              const float* __restrict__ b3, const float* __restrict__ dct,
              u16* __restrict__ outcl)
{
  __shared__ float s_yw[40 * 33];
  __shared__ u16 s_out[4 * 3072];

  const int q8 = (int)gridDim.x >> 3;
  const int bid = ((int)blockIdx.x & 7) * q8 + ((int)blockIdx.x >> 3);
  const int n = bid >> 8;
  const int y = bid & 255;
  const int tid = threadIdx.x;

  float sy = (y + 0.5f) * 0.125f - 0.5f;
  float yq = floorf(sy);
  float fy = sy - yq;
  int y0c = max((int)yq, 0), y1c = min((int)yq + 1, 31);

  for (int i = tid; i < 1280; i += 256) {
    int oc = i >> 5, c = i & 31;
    const float* sp = dct + ((size_t)(n * CH + oc) << 10);
    s_yw[oc * 33 + c] = (1.f - fy) * sp[y0c * 32 + c] + fy * sp[y1c * 32 + c];
  }
  __syncthreads();

  const int w = tid >> 6;
  const int l = tid & 63;
  const int g = l >> 4;
  const int m = l & 15;
  const int xb = w << 6;

  const u16* tp = t1cl + (size_t)n * IMG_CL + ((size_t)(y + 1) * IW + 1) * CH;

  f32x4 acc[4][3];
  #pragma unroll
  for (int xt = 0; xt < 4; ++xt)
    #pragma unroll
    for (int t = 0; t < 3; ++t) acc[xt][t] = (f32x4){0.f, 0.f, 0.f, 0.f};

  #pragma unroll
  for (int xt = 0; xt < 4; ++xt) {
    const u16* ap = tp + (size_t)(xb + xt * 16 + m) * CH;
    bf16x8 a0 = *(const bf16x8*)(ap + 8 * g);
    bf16x8 a1 = *(const bf16x8*)(ap + 32 + 8 * g);
    #pragma unroll
    for (int t = 0; t < 3; ++t) {
      bf16x8 b0 = *(const bf16x8*)(wt3 + (m + 16 * t) * 384 + 8 * g);
      bf16x8 b1 = *(const bf16x8*)(wt3 + (m + 16 * t) * 384 + 32 + 8 * g);
      acc[xt][t] = __builtin_amdgcn_mfma_f32_16x16x32_bf16(b0, a0, acc[xt][t], 0, 0, 0);
      acc[xt][t] = __builtin_amdgcn_mfma_f32_16x16x32_bf16(b1, a1, acc[xt][t], 0, 0, 0);
    }
  }

  u16* so = s_out + w * 3072;
  float4 bv[3];
  bv[0] = *(const float4*)(b3 + 4 * g);
  bv[1] = *(const float4*)(b3 + 16 + 4 * g);
  bv[2] = (g < 2) ? *(const float4*)(b3 + 32 + 4 * g) : make_float4(0.f, 0.f, 0.f, 0.f);
  #pragma unroll
  for (int t = 0; t < 3; ++t) {
    if (t == 2 && g >= 2) continue;
    #pragma unroll
    for (int xt = 0; xt < 4; ++xt) {
      const int pxl = xt * 16 + m;
      const int px = xb + pxl;
      float sx = (px + 0.5f) * 0.125f - 0.5f;
      float xq = floorf(sx);
      float fx = sx - xq;
      int x0c = max((int)xq, 0), x1c = min((int)xq + 1, 31);
      u16 r4[4];
      #pragma unroll
      for (int i = 0; i < 4; ++i) {
        int oc = 16 * t + 4 * g + i;
        float wgt = 1.f / (1.f + __expf(-(acc[xt][t][i] + ((const float*)&bv[t])[i])));
        float bil = (1.f - fx) * s_yw[oc * 33 + x0c] + fx * s_yw[oc * 33 + x1c];
        r4[i] = f2b(wgt * bil);
      }
      uint2 pk;
      pk.x = (u32)r4[0] | ((u32)r4[1] << 16);
      pk.y = (u32)r4[2] | ((u32)r4[3] << 16);
      int byt = pxl * 80 + (16 * t + 4 * g) * 2;
      byt ^= ((pxl >> 3) & 7) << 4;
      *(uint2*)((char*)so + byt) = pk;
    }
  }
  const size_t rowu = (size_t)n * IMG_CL + ((size_t)(y + 1) * IW + (xb + 1)) * CH;
  #pragma unroll
  for (int q = 0; q < 5; ++q) {
    int byt = l * 80 + q * 16;
    byt ^= ((l >> 3) & 7) << 4;
    uint4 d = *(const uint4*)((const char*)so + byt);
    *(uint4*)(outcl + rowu + (size_t)l * 40 + q * 8) = d;
  }
}

extern "C" void kernel_launch(void* const* d_in, const int* in_sizes, int n_in,
                              void* d_out, int out_size, void* d_ws, size_t ws_size,
                              hipStream_t stream)
{
  const float* x       = (const float*)d_in[0];
  const float* conv_w  = (const float*)d_in[1];
  const float* conv_b  = (const float*)d_in[2];
  const float* ddct_w  = (const float*)d_in[3];
  const float* ddct_b  = (const float*)d_in[4];
  const float* dctc_w  = (const float*)d_in[5];
  const float* dctc_b  = (const float*)d_in[6];
  const float* w1_w    = (const float*)d_in[7];
  const float* w1_b    = (const float*)d_in[8];
  const float* w3_w    = (const float*)d_in[9];
  const float* w3_b    = (const float*)d_in[10];
  const float* after_w = (const float*)d_in[11];
  const float* after_b = (const float*)d_in[12];

  char* ws = (char*)d_ws;
  const size_t CLB = (size_t)8 * IMG_CL * 2;          // 42,600,960 B
  u16*   xcl    = (u16*)ws;                           // x, later dd
  u16*   cl_a   = (u16*)(ws + CLB);                   // dct_feat, later prod
  u16*   cl_c   = (u16*)(ws + 2 * CLB);               // t1
  float* small0 = (float*)(ws + 3 * CLB);             // 1,310,720 B
  float* small1 = (float*)(ws + 3 * CLB + 1310720);   // 1,310,720 B
  u16*   wt     = (u16*)(ws + 3 * CLB + 2621440);     // 184,320 B (5 sets)
  u16*   wcm    = (u16*)(ws + 3 * CLB + 2621440 + 184320); // 61,440 B (2 cm sets)

  // 0. weight transforms + input cl conversion + ring zeroing
  prep_w_k<<<480, 256, 0, stream>>>(conv_w, ddct_w, w1_w, after_w, w3_w, wt, wcm);
  prep_x_k<<<8 * IW, 256, 0, stream>>>(x, xcl, cl_a);
  // 1. dct_feat = gelu(conv(x))                    -> cl_a   (all-LDS kernel)
  convl_k<1><<<2048, 256, 0, stream>>>(xcl, wcm, conv_b, cl_a);
  // 5. t1 = relu(conv(x, w1))                      -> cl_c   (all-LDS kernel)
  convl_k<2><<<2048, 256, 0, stream>>>(xcl, wcm + WCM_SET, w1_b, cl_c);
  // 2. dd = gelu(conv(dct_feat)) + dct_feat        -> xcl (x dead)
  convm_k<1, true, false><<<1024, 512, 0, stream>>>(cl_a, wt + WT_SET, ddct_b, cl_a, xcl);
  // 3. depthwise strided conv                      -> small0
  dwconv_k<<<1280, 256, 0, stream>>>(xcl, dctc_w, dctc_b, small0);
  // 4. per-block 8x8 iDCT                          -> small1
  idct8_k<<<1280, 256, 0, stream>>>(small0, small1);
  // 6. prod = sigmoid(1x1(t1)) * bilinear(idct)    -> cl_a (dct_feat dead)
  wgtmul_k<<<2048, 256, 0, stream>>>(cl_c, wt + 4 * WT_SET, w3_b, small1, cl_a);
  // 7. out = conv(prod, after)                     -> d_out fp32 planar
  convm_k<0, false, true><<<1024, 512, 0, stream>>>(cl_a, wt + 3 * WT_SET, after_b, nullptr, (void*)d_out);
}

// Round 12
// 245.891 us; speedup vs baseline: 1.5961x; 1.1075x over previous
//
#include <hip/hip_runtime.h>

typedef unsigned short u16;
typedef unsigned int u32;
typedef __attribute__((ext_vector_type(8))) short bf16x8;
typedef __attribute__((ext_vector_type(4))) float f32x4;

#define CH 40
#define IW 258                   // ring-padded width (256 + 2)
#define IWCH (IW * CH)           // 10320
#define IMG_CL (IW * IW * CH)    // u16 elements per image, channel-last padded
#define WT_SET (48 * 384)        // u16 per weight set (row-major)
#define WCM_SET (48 * 40 * 8)    // u16 per chunk-major set (LDS path) = 15360

#define GLDS16(g, l) __builtin_amdgcn_global_load_lds( \
    (const __attribute__((address_space(1))) void*)(g), \
    (__attribute__((address_space(3))) void*)(l), 16, 0, 0)

__device__ __forceinline__ float b2f(u16 u) {
  union { u32 i; float f; } v; v.i = ((u32)u) << 16; return v.f;
}
__device__ __forceinline__ u16 f2b(float f) {
  union { float f; u32 i; } v; v.f = f;
  u32 r = v.i + 0x7fffu + ((v.i >> 16) & 1u);
  return (u16)(r >> 16);
}
__device__ __forceinline__ u32 addbf2(u32 a, u32 b) {
  union { u32 i; float f; } lo_a, lo_b, hi_a, hi_b;
  lo_a.i = a << 16; lo_b.i = b << 16;
  hi_a.i = a & 0xffff0000u; hi_b.i = b & 0xffff0000u;
  float lo = lo_a.f + lo_b.f, hi = hi_a.f + hi_b.f;
  return (u32)f2b(lo) | ((u32)f2b(hi) << 16);
}
// tanh-approx gelu (validated r10: |err| ~3e-4, absmax unchanged)
__device__ __forceinline__ float actf(float t, int ACT) {
  if (ACT == 1) {
    float u2 = t * (1.5957691216057308f + 0.07135481627000862f * t * t);
    float e = __expf(u2);
    return t - t / (e + 1.f);
  }
  if (ACT == 2) return fmaxf(t, 0.f);
  return t;
}

// ---- weights: row-major [48][384] x5 + chunk-major [48][40][8] x4 --------
// cm sets: 0=conv_w, 1=w1_w, 2=ddct_w (unused this round), 3=after_w
__global__ __launch_bounds__(256)
void prep_w_k(const float* __restrict__ w0, const float* __restrict__ w1,
              const float* __restrict__ w2, const float* __restrict__ w3,
              const float* __restrict__ w4, u16* __restrict__ wt,
              u16* __restrict__ wcm)
{
  int i = blockIdx.x * 256 + threadIdx.x;      // 92160 + 61440 = 153600
  if (i >= 5 * WT_SET + 4 * WCM_SET) return;
  if (i < 5 * WT_SET) {
    int k = i % 384;
    int oc = (i / 384) % 48;
    int set = i / WT_SET;
    u16 v = 0;
    if (set == 4) {
      if (oc < 40 && k < 40) v = f2b(w4[oc * 40 + k]);
    } else {
      int dy = k >> 7;
      int r = k & 127;
      if (oc < 40 && r < 120) {
        int dx = r / 40;
        int ic = r - dx * 40;
        const float* w = (set == 0) ? w0 : (set == 1) ? w1 : (set == 2) ? w2 : w3;
        v = f2b(w[((oc * 40 + ic) * 3 + dy) * 3 + dx]);
      }
    }
    wt[i] = v;
  } else {
    int j = i - 5 * WT_SET;
    int set2 = j / WCM_SET;                    // 0 conv, 1 w1, 2 ddct, 3 after
    int r2 = j - set2 * WCM_SET;
    int c = r2 / 320;                          // k-chunk 0..47
    int rem = r2 - c * 320;
    int oc = rem >> 3;
    int e = rem & 7;
    int k = c * 8 + e;
    int dy = k >> 7;
    int r = k & 127;
    u16 v = 0;
    if (r < 120) {
      int dx = r / 40;
      int ic = r - dx * 40;
      const float* w = (set2 == 0) ? w0 : (set2 == 1) ? w2 : (set2 == 2) ? w1 : w3;
      v = f2b(w[((oc * 40 + ic) * 3 + dy) * 3 + dx]);
    }
    wcm[j] = v;
  }
}

// ---- x fp32 planar -> xcl bf16 channel-last + zero rings of xcl, cla -----
__global__ __launch_bounds__(256)
void prep_x_k(const float* __restrict__ x, u16* __restrict__ xcl,
              u16* __restrict__ cla)
{
  const int n = blockIdx.x / IW;
  const int yr = blockIdx.x % IW;
  const int t = threadIdx.x;
  const size_t base = (size_t)n * IMG_CL + (size_t)yr * IWCH;
  const uint4 z = {0u, 0u, 0u, 0u};

  if (yr == 0 || yr == IW - 1) {
    for (int i = t; i < IWCH / 8; i += 256) {
      ((uint4*)(xcl + base))[i] = z;
      ((uint4*)(cla + base))[i] = z;
    }
    return;
  }
  if (t < 5) {
    ((uint4*)(xcl + base))[t] = z;
    ((uint4*)(cla + base))[t] = z;
  } else if (t < 10) {
    size_t b2 = base + (size_t)(IW - 1) * CH;
    ((uint4*)(xcl + b2))[t - 5] = z;
    ((uint4*)(cla + b2))[t - 5] = z;
  }
  const int y = yr - 1;
  const float* xp = x + (size_t)n * CH * 65536 + (size_t)y * 256 + t;
  __attribute__((aligned(16))) u16 buf[40];
  #pragma unroll
  for (int ic = 0; ic < 40; ++ic) buf[ic] = f2b(xp[(size_t)ic * 65536]);
  u16* dst = xcl + base + (size_t)(t + 1) * CH;
  #pragma unroll
  for (int q = 0; q < 5; ++q) ((uint4*)dst)[q] = ((const uint4*)buf)[q];
}

// ---- all-LDS-operand MFMA conv 3x3 (input tile + weights in LDS) ---------
// PLANAR=false: swapped operands, restage, cl bf16 out. PLANAR=true: direct f32.
template<int ACT, bool PLANAR>
__global__ __launch_bounds__(256, 2)
void convl_k(const u16* __restrict__ incl, const u16* __restrict__ wcm,
             const float* __restrict__ bias, void* __restrict__ outp)
{
  __shared__ __align__(16) u16 s_mem[31200];   // input 15840 + weights 15360
  u16* s_in = s_mem;
  u16* s_w  = s_mem + 15840;

  const int tid = threadIdx.x;
  const int bid = ((int)blockIdx.x & 7) * 256 + ((int)blockIdx.x >> 3);
  const int n = bid >> 8;
  const int tb = bid & 255;
  const int y0 = (tb >> 2) << 2;
  const int x0 = (tb & 3) << 6;

  const u16* src = incl + (size_t)n * IMG_CL + ((size_t)y0 * IW + x0) * CH;
  #pragma unroll
  for (int k = 0; k < 8; ++k) {
    int i = tid + (k << 8);
    if (i < 1980) {
      int r = i / 330, o = i - r * 330;
      GLDS16(src + (size_t)r * IWCH + o * 8, s_in + i * 8);
    }
  }
  #pragma unroll
  for (int k = 0; k < 8; ++k) {
    int i = tid + (k << 8);
    if (i < 1920) GLDS16(wcm + i * 8, s_w + i * 8);
  }
  __syncthreads();

  const int w = tid >> 6;
  const int l = tid & 63;
  const int g = l >> 4;
  const int m = l & 15;

  f32x4 acc[4][3];
  #pragma unroll
  for (int xt = 0; xt < 4; ++xt)
    #pragma unroll
    for (int tt = 0; tt < 3; ++tt) acc[xt][tt] = (f32x4){0.f, 0.f, 0.f, 0.f};

  #pragma unroll
  for (int s = 0; s < 12; ++s) {
    const int dy = s >> 2;
    const int c = ((s & 3) << 2) + g;
    int dx, icb;
    if (c >= 15)      { dx = 0; icb = 0; }
    else if (c >= 10) { dx = 2; icb = (c - 10) * 8; }
    else if (c >= 5)  { dx = 1; icb = (c - 5) * 8; }
    else              { dx = 0; icb = c * 8; }
    const int abase = (w + dy) * (66 * CH) + (m + dx) * CH + icb;
    bf16x8 a0 = *(const bf16x8*)(s_in + abase);
    bf16x8 a1 = *(const bf16x8*)(s_in + abase + 16 * CH);
    bf16x8 a2 = *(const bf16x8*)(s_in + abase + 32 * CH);
    bf16x8 a3 = *(const bf16x8*)(s_in + abase + 48 * CH);

    const int ch = (s << 2) + g;
    const u16* wrow = s_w + ch * 320;
    bf16x8 b0 = *(const bf16x8*)(wrow + m * 8);
    bf16x8 b1 = *(const bf16x8*)(wrow + (m + 16) * 8);
    bf16x8 b2 = *(const bf16x8*)(wrow + (m >= 8 ? 312 : (m + 32) * 8));

    #pragma unroll
    for (int xt = 0; xt < 4; ++xt) {
      bf16x8 aX = (xt == 0) ? a0 : (xt == 1) ? a1 : (xt == 2) ? a2 : a3;
      if (PLANAR) {
        acc[xt][0] = __builtin_amdgcn_mfma_f32_16x16x32_bf16(aX, b0, acc[xt][0], 0, 0, 0);
        acc[xt][1] = __builtin_amdgcn_mfma_f32_16x16x32_bf16(aX, b1, acc[xt][1], 0, 0, 0);
        acc[xt][2] = __builtin_amdgcn_mfma_f32_16x16x32_bf16(aX, b2, acc[xt][2], 0, 0, 0);
      } else {
        acc[xt][0] = __builtin_amdgcn_mfma_f32_16x16x32_bf16(b0, aX, acc[xt][0], 0, 0, 0);
        acc[xt][1] = __builtin_amdgcn_mfma_f32_16x16x32_bf16(b1, aX, acc[xt][1], 0, 0, 0);
        acc[xt][2] = __builtin_amdgcn_mfma_f32_16x16x32_bf16(b2, aX, acc[xt][2], 0, 0, 0);
      }
    }
  }

  const int y = y0 + w;

  if (PLANAR) {
    const float bv0 = bias[m];
    const float bv1 = bias[m + 16];
    const float bv2 = (m < 8) ? bias[m + 32] : 0.f;
    #pragma unroll
    for (int tt = 0; tt < 3; ++tt) {
      const int oc = m + 16 * tt;
      if (tt == 2 && m >= 8) continue;
      const float bv = (tt == 0) ? bv0 : (tt == 1) ? bv1 : bv2;
      #pragma unroll
      for (int xt = 0; xt < 4; ++xt) {
        const int xb = x0 + xt * 16 + 4 * g;
        float v[4];
        #pragma unroll
        for (int i = 0; i < 4; ++i) v[i] = actf(acc[xt][tt][i] + bv, ACT);
        *(float4*)((float*)outp + (((size_t)(n * CH + oc)) << 16) + ((size_t)y << 8) + xb)
            = make_float4(v[0], v[1], v[2], v[3]);
      }
    }
  } else {
    __syncthreads();
    char* so = (char*)s_mem + w * 5120;
    float4 bv[3];
    bv[0] = *(const float4*)(bias + 4 * g);
    bv[1] = *(const float4*)(bias + 16 + 4 * g);
    bv[2] = (g < 2) ? *(const float4*)(bias + 32 + 4 * g)
                    : make_float4(0.f, 0.f, 0.f, 0.f);
    #pragma unroll
    for (int tt = 0; tt < 3; ++tt) {
      if (tt == 2 && g >= 2) continue;
      #pragma unroll
      for (int xt = 0; xt < 4; ++xt) {
        const int pxl = xt * 16 + m;
        float v[4];
        #pragma unroll
        for (int i = 0; i < 4; ++i)
          v[i] = actf(acc[xt][tt][i] + ((const float*)&bv[tt])[i], ACT);
        uint2 pk;
        pk.x = (u32)f2b(v[0]) | ((u32)f2b(v[1]) << 16);
        pk.y = (u32)f2b(v[2]) | ((u32)f2b(v[3]) << 16);
        int byt = pxl * 80 + (16 * tt + 4 * g) * 2;
        byt ^= ((pxl >> 3) & 7) << 4;
        *(uint2*)(so + byt) = pk;
      }
    }
    const size_t rowu = (size_t)n * IMG_CL + ((size_t)(y + 1) * IW + (x0 + 1)) * CH;
    #pragma unroll
    for (int q = 0; q < 5; ++q) {
      int byt = l * 80 + q * 16;
      byt ^= ((l >> 3) & 7) << 4;
      uint4 d = *(const uint4*)(so + byt);
      *(uint4*)((u16*)outp + rowu + (size_t)l * 40 + q * 8) = d;
    }
  }
}

// ---- MFMA implicit-GEMM conv 3x3 pad 1, 8 rows x 64 px, 8 waves (r10) ----
template<int ACT, bool RES>
__global__ __launch_bounds__(512, 4)
void convm_k(const u16* __restrict__ incl, const u16* __restrict__ wt,
             const float* __restrict__ bias, const u16* __restrict__ rescl,
             void* __restrict__ outp)
{
  __shared__ u16 s_in[10 * 66 * CH];       // 52800 B; head reused as out-stage

  const int tid = threadIdx.x;
  const int q8 = (int)gridDim.x >> 3;
  const int bid = ((int)blockIdx.x & 7) * q8 + ((int)blockIdx.x >> 3);
  const int n = bid >> 7;
  const int tb = bid & 127;
  const int y0 = (tb >> 2) << 3;
  const int x0 = (tb & 3) << 6;

  const u16* src = incl + (size_t)n * IMG_CL + ((size_t)y0 * IW + x0) * CH;
  for (int k = 0; k < 7; ++k) {
    int i = tid + (k << 9);
    if (i < 3300) {
      int r = i / 330, o = i - r * 330;
      GLDS16(src + (size_t)r * IWCH + o * 8, s_in + i * 8);
    }
  }
  __syncthreads();

  const int w = tid >> 6;
  const int l = tid & 63;
  const int g = l >> 4;
  const int m = l & 15;

  f32x4 acc[4][3];
  #pragma unroll
  for (int xt = 0; xt < 4; ++xt)
    #pragma unroll
    for (int t = 0; t < 3; ++t) acc[xt][t] = (f32x4){0.f, 0.f, 0.f, 0.f};

  bf16x8 aC[4], bC[3], aN[4], bN[3];
  auto lf = [&](int s, bf16x8* A, bf16x8* B) {
    const int dy = s >> 2;
    const int c = ((s & 3) << 2) + g;
    int dx, icb;
    if (c >= 15)      { dx = 0; icb = 0; }
    else if (c >= 10) { dx = 2; icb = (c - 10) * 8; }
    else if (c >= 5)  { dx = 1; icb = (c - 5) * 8; }
    else              { dx = 0; icb = c * 8; }
    const int abase = (w + dy) * (66 * CH) + (m + dx) * CH + icb;
    A[0] = *(const bf16x8*)(s_in + abase);
    A[1] = *(const bf16x8*)(s_in + abase + 16 * CH);
    A[2] = *(const bf16x8*)(s_in + abase + 32 * CH);
    A[3] = *(const bf16x8*)(s_in + abase + 48 * CH);
    const int wb = s * 32 + g * 8;
    B[0] = *(const bf16x8*)(wt + m * 384 + wb);
    B[1] = *(const bf16x8*)(wt + (m + 16) * 384 + wb);
    B[2] = *(const bf16x8*)(wt + (m + 32) * 384 + wb);
  };

  lf(0, aC, bC);
  #pragma unroll
  for (int s = 0; s < 12; ++s) {
    if (s < 11) lf(s + 1, aN, bN);
    #pragma unroll
    for (int t = 0; t < 3; ++t)
      #pragma unroll
      for (int xt = 0; xt < 4; ++xt)
        acc[xt][t] = __builtin_amdgcn_mfma_f32_16x16x32_bf16(bC[t], aC[xt], acc[xt][t], 0, 0, 0);
    if (s < 11) {
      #pragma unroll
      for (int q = 0; q < 4; ++q) aC[q] = aN[q];
      #pragma unroll
      for (int q = 0; q < 3; ++q) bC[q] = bN[q];
    }
  }

  const int y = y0 + w;

  __syncthreads();
  u16* s_out = s_in + w * 3072;
  float4 bv[3];
  bv[0] = *(const float4*)(bias + 4 * g);
  bv[1] = *(const float4*)(bias + 16 + 4 * g);
  bv[2] = (g < 2) ? *(const float4*)(bias + 32 + 4 * g)
                  : make_float4(0.f, 0.f, 0.f, 0.f);
  #pragma unroll
  for (int t = 0; t < 3; ++t) {
    if (t == 2 && g >= 2) continue;
    #pragma unroll
    for (int xt = 0; xt < 4; ++xt) {
      const int pxl = xt * 16 + m;
      float v[4];
      #pragma unroll
      for (int i = 0; i < 4; ++i)
        v[i] = actf(acc[xt][t][i] + ((const float*)&bv[t])[i], ACT);
      uint2 pk;
      pk.x = (u32)f2b(v[0]) | ((u32)f2b(v[1]) << 16);
      pk.y = (u32)f2b(v[2]) | ((u32)f2b(v[3]) << 16);
      int byt = pxl * 80 + (16 * t + 4 * g) * 2;
      byt ^= ((pxl >> 3) & 7) << 4;
      *(uint2*)((char*)s_out + byt) = pk;
    }
  }
  const size_t rowu = (size_t)n * IMG_CL + ((size_t)(y + 1) * IW + (x0 + 1)) * CH;
  #pragma unroll
  for (int q = 0; q < 5; ++q) {
    int byt = l * 80 + q * 16;
    byt ^= ((l >> 3) & 7) << 4;
    uint4 d = *(const uint4*)((const char*)s_out + byt);
    if (RES) {
      uint4 rv = *(const uint4*)(rescl + rowu + (size_t)l * 40 + q * 8);
      d.x = addbf2(d.x, rv.x); d.y = addbf2(d.y, rv.y);
      d.z = addbf2(d.z, rv.z); d.w = addbf2(d.w, rv.w);
    }
    *(uint4*)((u16*)outp + rowu + (size_t)l * 40 + q * 8) = d;
  }
}

// ---- depthwise conv k3 s8 p2 d2 on cl bf16 -> planar f32 (8,40,32,32) ----
__global__ __launch_bounds__(256)
void dwconv_k(const u16* __restrict__ incl, const float* __restrict__ w,
              const float* __restrict__ b, float* __restrict__ out)
{
  int idx = blockIdx.x * 256 + threadIdx.x;
  if (idx >= 8 * 32 * 32 * CH) return;
  int c = idx % CH;
  int p = idx / CH;
  int ox = p & 31;
  int oy = (p >> 5) & 31;
  int n = p >> 10;
  float acc = b[c];
  const u16* ip = incl + (size_t)n * IMG_CL;
  #pragma unroll
  for (int dy = 0; dy < 3; ++dy) {
    int y = oy * 8 - 2 + dy * 2;
    if ((unsigned)y >= 256u) continue;
    #pragma unroll
    for (int dx = 0; dx < 3; ++dx) {
      int x = ox * 8 - 2 + dx * 2;
      if ((unsigned)x >= 256u) continue;
      acc += w[c * 9 + dy * 3 + dx] * b2f(ip[((size_t)(y + 1) * IW + (x + 1)) * CH + c]);
    }
  }
  out[((size_t)(n * CH + c) << 10) + oy * 32 + ox] = acc;
}

// ---- per-8x8-block iDCT on planar f32 32x32 ------------------------------
__global__ __launch_bounds__(256)
void idct8_k(const float* __restrict__ in, float* __restrict__ out)
{
  __shared__ float ctab[8];
  if (threadIdx.x < 8) {
    const float c_[8] = {1.f, 0.70710678118654752f, 0.f, -0.70710678118654752f,
                         -1.f, -0.70710678118654752f, 0.f, 0.70710678118654752f};
    ctab[threadIdx.x] = c_[threadIdx.x];
  }
  __syncthreads();
  int idx = blockIdx.x * 256 + threadIdx.x;
  if (idx >= 8 * CH * 32 * 32) return;
  int ox = idx & 31, oy = (idx >> 5) & 31, bc = idx >> 10;
  int k = oy & 7, lq = ox & 7;
  const float* ip = in + bc * 1024 + (oy & ~7) * 32 + (ox & ~7);
  float acc = 0.f;
  #pragma unroll
  for (int mm = 0; mm < 8; ++mm) {
    float rk = ctab[(k * mm) & 7];
    float s = 0.f;
    #pragma unroll
    for (int nn = 0; nn < 8; ++nn)
      s += ctab[(lq * nn) & 7] * ip[mm * 32 + nn];
    acc += rk * s;
  }
  out[idx] = acc * 0.125f;
}

// ---- MFMA 1x1 conv + sigmoid + bilinear(32->256) multiply; cl bf16 -------
__global__ __launch_bounds__(256)
void wgtmul_k(const u16* __restrict__ t1cl, const u16* __restrict__ wt3,
              const float* __restrict__ b3, const float* __restrict__ dct,
              u16* __restrict__ outcl)
{
  __shared__ float s_yw[40 * 33];
  __shared__ u16 s_out[4 * 3072];

  const int q8 = (int)gridDim.x >> 3;
  const int bid = ((int)blockIdx.x & 7) * q8 + ((int)blockIdx.x >> 3);
  const int n = bid >> 8;
  const int y = bid & 255;
  const int tid = threadIdx.x;

  float sy = (y + 0.5f) * 0.125f - 0.5f;
  float yq = floorf(sy);
  float fy = sy - yq;
  int y0c = max((int)yq, 0), y1c = min((int)yq + 1, 31);

  for (int i = tid; i < 1280; i += 256) {
    int oc = i >> 5, c = i & 31;
    const float* sp = dct + ((size_t)(n * CH + oc) << 10);
    s_yw[oc * 33 + c] = (1.f - fy) * sp[y0c * 32 + c] + fy * sp[y1c * 32 + c];
  }
  __syncthreads();

  const int w = tid >> 6;
  const int l = tid & 63;
  const int g = l >> 4;
  const int m = l & 15;
  const int xb = w << 6;

  const u16* tp = t1cl + (size_t)n * IMG_CL + ((size_t)(y + 1) * IW + 1) * CH;

  f32x4 acc[4][3];
  #pragma unroll
  for (int xt = 0; xt < 4; ++xt)
    #pragma unroll
    for (int t = 0; t < 3; ++t) acc[xt][t] = (f32x4){0.f, 0.f, 0.f, 0.f};

  #pragma unroll
  for (int xt = 0; xt < 4; ++xt) {
    const u16* ap = tp + (size_t)(xb + xt * 16 + m) * CH;
    bf16x8 a0 = *(const bf16x8*)(ap + 8 * g);
    bf16x8 a1 = *(const bf16x8*)(ap + 32 + 8 * g);
    #pragma unroll
    for (int t = 0; t < 3; ++t) {
      bf16x8 b0 = *(const bf16x8*)(wt3 + (m + 16 * t) * 384 + 8 * g);
      bf16x8 b1 = *(const bf16x8*)(wt3 + (m + 16 * t) * 384 + 32 + 8 * g);
      acc[xt][t] = __builtin_amdgcn_mfma_f32_16x16x32_bf16(b0, a0, acc[xt][t], 0, 0, 0);
      acc[xt][t] = __builtin_amdgcn_mfma_f32_16x16x32_bf16(b1, a1, acc[xt][t], 0, 0, 0);
    }
  }

  u16* so = s_out + w * 3072;
  float4 bv[3];
  bv[0] = *(const float4*)(b3 + 4 * g);
  bv[1] = *(const float4*)(b3 + 16 + 4 * g);
  bv[2] = (g < 2) ? *(const float4*)(b3 + 32 + 4 * g) : make_float4(0.f, 0.f, 0.f, 0.f);
  #pragma unroll
  for (int t = 0; t < 3; ++t) {
    if (t == 2 && g >= 2) continue;
    #pragma unroll
    for (int xt = 0; xt < 4; ++xt) {
      const int pxl = xt * 16 + m;
      const int px = xb + pxl;
      float sx = (px + 0.5f) * 0.125f - 0.5f;
      float xq = floorf(sx);
      float fx = sx - xq;
      int x0c = max((int)xq, 0), x1c = min((int)xq + 1, 31);
      u16 r4[4];
      #pragma unroll
      for (int i = 0; i < 4; ++i) {
        int oc = 16 * t + 4 * g + i;
        float wgt = 1.f / (1.f + __expf(-(acc[xt][t][i] + ((const float*)&bv[t])[i])));
        float bil = (1.f - fx) * s_yw[oc * 33 + x0c] + fx * s_yw[oc * 33 + x1c];
        r4[i] = f2b(wgt * bil);
      }
      uint2 pk;
      pk.x = (u32)r4[0] | ((u32)r4[1] << 16);
      pk.y = (u32)r4[2] | ((u32)r4[3] << 16);
      int byt = pxl * 80 + (16 * t + 4 * g) * 2;
      byt ^= ((pxl >> 3) & 7) << 4;
      *(uint2*)((char*)so + byt) = pk;
    }
  }
  const size_t rowu = (size_t)n * IMG_CL + ((size_t)(y + 1) * IW + (xb + 1)) * CH;
  #pragma unroll
  for (int q = 0; q < 5; ++q) {
    int byt = l * 80 + q * 16;
    byt ^= ((l >> 3) & 7) << 4;
    uint4 d = *(const uint4*)((const char*)so + byt);
    *(uint4*)(outcl + rowu + (size_t)l * 40 + q * 8) = d;
  }
}

extern "C" void kernel_launch(void* const* d_in, const int* in_sizes, int n_in,
                              void* d_out, int out_size, void* d_ws, size_t ws_size,
                              hipStream_t stream)
{
  const float* x       = (const float*)d_in[0];
  const float* conv_w  = (const float*)d_in[1];
  const float* conv_b  = (const float*)d_in[2];
  const float* ddct_w  = (const float*)d_in[3];
  const float* ddct_b  = (const float*)d_in[4];
  const float* dctc_w  = (const float*)d_in[5];
  const float* dctc_b  = (const float*)d_in[6];
  const float* w1_w    = (const float*)d_in[7];
  const float* w1_b    = (const float*)d_in[8];
  const float* w3_w    = (const float*)d_in[9];
  const float* w3_b    = (const float*)d_in[10];
  const float* after_w = (const float*)d_in[11];
  const float* after_b = (const float*)d_in[12];

  char* ws = (char*)d_ws;
  const size_t CLB = (size_t)8 * IMG_CL * 2;          // 42,600,960 B
  u16*   xcl    = (u16*)ws;                           // x, later dd
  u16*   cl_a   = (u16*)(ws + CLB);                   // dct_feat, later prod
  u16*   cl_c   = (u16*)(ws + 2 * CLB);               // t1
  char*  base3  = ws + 3 * CLB;
  float* small0 = (float*)base3;                      // 1,310,720 B
  float* small1 = (float*)(base3 + 1310720);          // 1,310,720 B
  u16*   wt     = (u16*)(base3 + 2621440);            // 184,320 B (5 sets)
  u16*   wcm    = (u16*)(base3 + 2805760);            // 122,880 B (4 cm sets)

  // 0. weight transforms + input cl conversion + ring zeroing
  prep_w_k<<<600, 256, 0, stream>>>(conv_w, ddct_w, w1_w, after_w, w3_w, wt, wcm);
  prep_x_k<<<8 * IW, 256, 0, stream>>>(x, xcl, cl_a);
  // 1. dct_feat = gelu(conv(x))                    -> cl_a
  convl_k<1, false><<<2048, 256, 0, stream>>>(xcl, wcm, conv_b, cl_a);
  // 5. t1 = relu(conv(x, w1))                      -> cl_c
  convl_k<2, false><<<2048, 256, 0, stream>>>(xcl, wcm + WCM_SET, w1_b, cl_c);
  // 2. dd = gelu(conv(dct_feat)) + dct_feat        -> xcl (x dead)  [dense, r10]
  convm_k<1, true><<<1024, 512, 0, stream>>>(cl_a, wt + WT_SET, ddct_b, cl_a, xcl);
  // 3. depthwise strided conv                      -> small0
  dwconv_k<<<1280, 256, 0, stream>>>(xcl, dctc_w, dctc_b, small0);
  // 4. per-block 8x8 iDCT                          -> small1
  idct8_k<<<1280, 256, 0, stream>>>(small0, small1);
  // 6. prod = sigmoid(1x1(t1)) * bilinear(idct)    -> cl_a (dct_feat dead)
  wgtmul_k<<<2048, 256, 0, stream>>>(cl_c, wt + 4 * WT_SET, w3_b, small1, cl_a);
  // 7. out = conv(prod, after)                     -> d_out fp32 planar  [NEW: convl]
  convl_k<0, true><<<2048, 256, 0, stream>>>(cl_a, wcm + 3 * WCM_SET, after_b, (void*)d_out);
}

// Round 13
// 200.881 us; speedup vs baseline: 1.9538x; 1.2241x over previous
//
#include <hip/hip_runtime.h>

typedef unsigned short u16;
typedef unsigned int u32;
typedef __attribute__((ext_vector_type(8))) short bf16x8;
typedef __attribute__((ext_vector_type(4))) float f32x4;

#define CH 40
#define IW 258                   // ring-padded width (256 + 2)
#define IWCH (IW * CH)           // 10320
#define IMG_CL (IW * IW * CH)    // u16 elements per image, channel-last padded
#define WT_SET (48 * 384)        // u16 per row-major set (wgtmul uses set 4)
#define WCM_SET (48 * 40 * 8)    // u16 per chunk-major set = 15360
#define WSC_SET (46 * 40 * 8)    // u16 sconv set: 45 real chunks + 1 zero = 14720

#define GLDS16(g, l) __builtin_amdgcn_global_load_lds( \
    (const __attribute__((address_space(1))) void*)(g), \
    (__attribute__((address_space(3))) void*)(l), 16, 0, 0)

__device__ __forceinline__ float b2f(u16 u) {
  union { u32 i; float f; } v; v.i = ((u32)u) << 16; return v.f;
}
__device__ __forceinline__ u16 f2b(float f) {
  union { float f; u32 i; } v; v.f = f;
  u32 r = v.i + 0x7fffu + ((v.i >> 16) & 1u);
  return (u16)(r >> 16);
}
__device__ __forceinline__ u32 addbf2(u32 a, u32 b) {
  union { u32 i; float f; } lo_a, lo_b, hi_a, hi_b;
  lo_a.i = a << 16; lo_b.i = b << 16;
  hi_a.i = a & 0xffff0000u; hi_b.i = b & 0xffff0000u;
  float lo = lo_a.f + lo_b.f, hi = hi_a.f + hi_b.f;
  return (u32)f2b(lo) | ((u32)f2b(hi) << 16);
}
// tanh-approx gelu (validated r10: |err| ~3e-4, absmax unchanged)
__device__ __forceinline__ float actf(float t, int ACT) {
  if (ACT == 1) {
    float u2 = t * (1.5957691216057308f + 0.07135481627000862f * t * t);
    float e = __expf(u2);
    return t - t / (e + 1.f);
  }
  if (ACT == 2) return fmaxf(t, 0.f);
  return t;
}

// ---- weights: row-major x5 + chunk-major x4 + sconv 46-chunk set ---------
// cm sets: 0=conv_w, 1=w1_w, 2=ddct_w, 3=after_w
// wsc (ddct_w): [46ch][40oc][8k], ch = dy*15 + dx*5 + ic/8 (45 real, ch45 = 0)
__global__ __launch_bounds__(256)
void prep_w_k(const float* __restrict__ w0, const float* __restrict__ w1,
              const float* __restrict__ w2, const float* __restrict__ w3,
              const float* __restrict__ w4, u16* __restrict__ wt,
              u16* __restrict__ wcm, u16* __restrict__ wsc)
{
  int i = blockIdx.x * 256 + threadIdx.x;   // 92160 + 61440 + 14720 = 168320
  if (i >= 5 * WT_SET + 4 * WCM_SET + WSC_SET) return;
  if (i < 5 * WT_SET) {
    int k = i % 384;
    int oc = (i / 384) % 48;
    int set = i / WT_SET;
    u16 v = 0;
    if (set == 4) {
      if (oc < 40 && k < 40) v = f2b(w4[oc * 40 + k]);
    } else {
      int dy = k >> 7;
      int r = k & 127;
      if (oc < 40 && r < 120) {
        int dx = r / 40;
        int ic = r - dx * 40;
        const float* w = (set == 0) ? w0 : (set == 1) ? w1 : (set == 2) ? w2 : w3;
        v = f2b(w[((oc * 40 + ic) * 3 + dy) * 3 + dx]);
      }
    }
    wt[i] = v;
  } else if (i < 5 * WT_SET + 4 * WCM_SET) {
    int j = i - 5 * WT_SET;
    int set2 = j / WCM_SET;                 // 0 conv, 1 w1, 2 ddct, 3 after
    int r2 = j - set2 * WCM_SET;
    int c = r2 / 320;
    int rem = r2 - c * 320;
    int oc = rem >> 3;
    int e = rem & 7;
    int k = c * 8 + e;
    int dy = k >> 7;
    int r = k & 127;
    u16 v = 0;
    if (r < 120) {
      int dx = r / 40;
      int ic = r - dx * 40;
      const float* w = (set2 == 0) ? w0 : (set2 == 1) ? w2 : (set2 == 2) ? w1 : w3;
      v = f2b(w[((oc * 40 + ic) * 3 + dy) * 3 + dx]);
    }
    wcm[j] = v;
  } else {
    int j2 = i - 5 * WT_SET - 4 * WCM_SET;  // [0, 14720)
    int c2 = j2 / 320;
    int rem = j2 - c2 * 320;
    int oc = rem >> 3;
    int e = rem & 7;
    u16 v = 0;
    if (c2 < 45) {
      int dy = c2 / 15, cc = c2 % 15;
      int dx = cc / 5, icq = cc % 5;
      int ic = icq * 8 + e;
      v = f2b(w1[((oc * 40 + ic) * 3 + dy) * 3 + dx]);  // w1 = ddct_w
    }
    wsc[j2] = v;
  }
}

// ---- x fp32 planar -> xcl bf16 channel-last + zero rings of xcl, cla -----
__global__ __launch_bounds__(256)
void prep_x_k(const float* __restrict__ x, u16* __restrict__ xcl,
              u16* __restrict__ cla)
{
  const int n = blockIdx.x / IW;
  const int yr = blockIdx.x % IW;
  const int t = threadIdx.x;
  const size_t base = (size_t)n * IMG_CL + (size_t)yr * IWCH;
  const uint4 z = {0u, 0u, 0u, 0u};

  if (yr == 0 || yr == IW - 1) {
    for (int i = t; i < IWCH / 8; i += 256) {
      ((uint4*)(xcl + base))[i] = z;
      ((uint4*)(cla + base))[i] = z;
    }
    return;
  }
  if (t < 5) {
    ((uint4*)(xcl + base))[t] = z;
    ((uint4*)(cla + base))[t] = z;
  } else if (t < 10) {
    size_t b2 = base + (size_t)(IW - 1) * CH;
    ((uint4*)(xcl + b2))[t - 5] = z;
    ((uint4*)(cla + b2))[t - 5] = z;
  }
  const int y = yr - 1;
  const float* xp = x + (size_t)n * CH * 65536 + (size_t)y * 256 + t;
  __attribute__((aligned(16))) u16 buf[40];
  #pragma unroll
  for (int ic = 0; ic < 40; ++ic) buf[ic] = f2b(xp[(size_t)ic * 65536]);
  u16* dst = xcl + base + (size_t)(t + 1) * CH;
  #pragma unroll
  for (int q = 0; q < 5; ++q) ((uint4*)dst)[q] = ((const uint4*)buf)[q];
}

// ---- all-LDS-operand MFMA conv 3x3 (input tile + weights in LDS) ---------
// PLANAR=false: swapped operands, restage, cl bf16 out. PLANAR=true: direct f32.
template<int ACT, bool PLANAR>
__global__ __launch_bounds__(256, 2)
void convl_k(const u16* __restrict__ incl, const u16* __restrict__ wcm,
             const float* __restrict__ bias, void* __restrict__ outp)
{
  __shared__ __align__(16) u16 s_mem[31200];   // input 15840 + weights 15360
  u16* s_in = s_mem;
  u16* s_w  = s_mem + 15840;

  const int tid = threadIdx.x;
  const int bid = ((int)blockIdx.x & 7) * 256 + ((int)blockIdx.x >> 3);
  const int n = bid >> 8;
  const int tb = bid & 255;
  const int y0 = (tb >> 2) << 2;
  const int x0 = (tb & 3) << 6;

  const u16* src = incl + (size_t)n * IMG_CL + ((size_t)y0 * IW + x0) * CH;
  #pragma unroll
  for (int k = 0; k < 8; ++k) {
    int i = tid + (k << 8);
    if (i < 1980) {
      int r = i / 330, o = i - r * 330;
      GLDS16(src + (size_t)r * IWCH + o * 8, s_in + i * 8);
    }
  }
  #pragma unroll
  for (int k = 0; k < 8; ++k) {
    int i = tid + (k << 8);
    if (i < 1920) GLDS16(wcm + i * 8, s_w + i * 8);
  }
  __syncthreads();

  const int w = tid >> 6;
  const int l = tid & 63;
  const int g = l >> 4;
  const int m = l & 15;

  f32x4 acc[4][3];
  #pragma unroll
  for (int xt = 0; xt < 4; ++xt)
    #pragma unroll
    for (int tt = 0; tt < 3; ++tt) acc[xt][tt] = (f32x4){0.f, 0.f, 0.f, 0.f};

  #pragma unroll
  for (int s = 0; s < 12; ++s) {
    const int dy = s >> 2;
    const int c = ((s & 3) << 2) + g;
    int dx, icb;
    if (c >= 15)      { dx = 0; icb = 0; }
    else if (c >= 10) { dx = 2; icb = (c - 10) * 8; }
    else if (c >= 5)  { dx = 1; icb = (c - 5) * 8; }
    else              { dx = 0; icb = c * 8; }
    const int abase = (w + dy) * (66 * CH) + (m + dx) * CH + icb;
    bf16x8 a0 = *(const bf16x8*)(s_in + abase);
    bf16x8 a1 = *(const bf16x8*)(s_in + abase + 16 * CH);
    bf16x8 a2 = *(const bf16x8*)(s_in + abase + 32 * CH);
    bf16x8 a3 = *(const bf16x8*)(s_in + abase + 48 * CH);

    const int ch = (s << 2) + g;
    const u16* wrow = s_w + ch * 320;
    bf16x8 b0 = *(const bf16x8*)(wrow + m * 8);
    bf16x8 b1 = *(const bf16x8*)(wrow + (m + 16) * 8);
    bf16x8 b2 = *(const bf16x8*)(wrow + (m >= 8 ? 312 : (m + 32) * 8));

    #pragma unroll
    for (int xt = 0; xt < 4; ++xt) {
      bf16x8 aX = (xt == 0) ? a0 : (xt == 1) ? a1 : (xt == 2) ? a2 : a3;
      if (PLANAR) {
        acc[xt][0] = __builtin_amdgcn_mfma_f32_16x16x32_bf16(aX, b0, acc[xt][0], 0, 0, 0);
        acc[xt][1] = __builtin_amdgcn_mfma_f32_16x16x32_bf16(aX, b1, acc[xt][1], 0, 0, 0);
        acc[xt][2] = __builtin_amdgcn_mfma_f32_16x16x32_bf16(aX, b2, acc[xt][2], 0, 0, 0);
      } else {
        acc[xt][0] = __builtin_amdgcn_mfma_f32_16x16x32_bf16(b0, aX, acc[xt][0], 0, 0, 0);
        acc[xt][1] = __builtin_amdgcn_mfma_f32_16x16x32_bf16(b1, aX, acc[xt][1], 0, 0, 0);
        acc[xt][2] = __builtin_amdgcn_mfma_f32_16x16x32_bf16(b2, aX, acc[xt][2], 0, 0, 0);
      }
    }
  }

  const int y = y0 + w;

  if (PLANAR) {
    const float bv0 = bias[m];
    const float bv1 = bias[m + 16];
    const float bv2 = (m < 8) ? bias[m + 32] : 0.f;
    #pragma unroll
    for (int tt = 0; tt < 3; ++tt) {
      const int oc = m + 16 * tt;
      if (tt == 2 && m >= 8) continue;
      const float bv = (tt == 0) ? bv0 : (tt == 1) ? bv1 : bv2;
      #pragma unroll
      for (int xt = 0; xt < 4; ++xt) {
        const int xb = x0 + xt * 16 + 4 * g;
        float v[4];
        #pragma unroll
        for (int i = 0; i < 4; ++i) v[i] = actf(acc[xt][tt][i] + bv, ACT);
        *(float4*)((float*)outp + (((size_t)(n * CH + oc)) << 16) + ((size_t)y << 8) + xb)
            = make_float4(v[0], v[1], v[2], v[3]);
      }
    }
  } else {
    __syncthreads();
    char* so = (char*)s_mem + w * 5120;
    float4 bv[3];
    bv[0] = *(const float4*)(bias + 4 * g);
    bv[1] = *(const float4*)(bias + 16 + 4 * g);
    bv[2] = (g < 2) ? *(const float4*)(bias + 32 + 4 * g)
                    : make_float4(0.f, 0.f, 0.f, 0.f);
    #pragma unroll
    for (int tt = 0; tt < 3; ++tt) {
      if (tt == 2 && g >= 2) continue;
      #pragma unroll
      for (int xt = 0; xt < 4; ++xt) {
        const int pxl = xt * 16 + m;
        float v[4];
        #pragma unroll
        for (int i = 0; i < 4; ++i)
          v[i] = actf(acc[xt][tt][i] + ((const float*)&bv[tt])[i], ACT);
        uint2 pk;
        pk.x = (u32)f2b(v[0]) | ((u32)f2b(v[1]) << 16);
        pk.y = (u32)f2b(v[2]) | ((u32)f2b(v[3]) << 16);
        int byt = pxl * 80 + (16 * tt + 4 * g) * 2;
        byt ^= ((pxl >> 3) & 7) << 4;
        *(uint2*)(so + byt) = pk;
      }
    }
    const size_t rowu = (size_t)n * IMG_CL + ((size_t)(y + 1) * IW + (x0 + 1)) * CH;
    #pragma unroll
    for (int q = 0; q < 5; ++q) {
      int byt = l * 80 + q * 16;
      byt ^= ((l >> 3) & 7) << 4;
      uint4 d = *(const uint4*)(so + byt);
      *(uint4*)((u16*)outp + rowu + (size_t)l * 40 + q * 8) = d;
    }
  }
}

// ---- SPARSE conv2 (FIXED LDS sizing): dd at dwconv sample points only ----
// -> compact [n][96][96][40] bf16. Block = (n, oy, 8-ox group); wave = dyi.
__global__ __launch_bounds__(256, 2)
void sconv_k(const u16* __restrict__ cla, const u16* __restrict__ wsc,
             const float* __restrict__ bias, u16* __restrict__ ddc)
{
  __shared__ __align__(16) u16 s_mem[32640];   // s_in 17920 + s_w 14720 = 65280 B
  u16* s_in = s_mem;
  u16* s_w  = s_mem + 17920;                   // weights; reused as restage after

  const int tid = threadIdx.x;
  const int bid = ((int)blockIdx.x & 7) * 128 + ((int)blockIdx.x >> 3); // 1024
  const int n = bid >> 7;
  const int oy = (bid >> 2) & 31;
  const int xg = bid & 3;

  // stage padded rows 8oy-2 .. 8oy+4 (7), 64 px from padded-x 64xg-2.
  // oy==0 / xg==0 negative offsets read mapped garbage that feeds only
  // edge points whose outputs are forced to zero in the writeback.
  const u16* src = cla + (ptrdiff_t)((size_t)n * IMG_CL)
                       + (ptrdiff_t)(8 * oy - 2) * IWCH + (64 * xg - 2) * CH;
  #pragma unroll
  for (int k = 0; k < 9; ++k) {        // 2240 input 16B chunks
    int i = tid + (k << 8);
    if (i < 2240) {
      int r = i / 320, o = i - r * 320;
      GLDS16(src + (ptrdiff_t)r * IWCH + o * 8, s_in + i * 8);
    }
  }
  #pragma unroll
  for (int k = 0; k < 8; ++k) {        // 1840 weight 16B chunks (46*320*2/16)
    int i = tid + (k << 8);
    if (i < 1840) GLDS16(wsc + i * 8, s_w + i * 8);
  }
  __syncthreads();

  const int w = tid >> 6;
  const int l = tid & 63;
  const int g = l >> 4;
  const int m = l & 15;

  // two M-tiles: points p0 = m, p1 = min(16+m, 23)
  const int p0 = m;
  const int p1 = (m < 8) ? 16 + m : 23;
  const int rb0 = 8 * (p0 / 3) + 2 * (p0 % 3);
  const int rb1 = 8 * (p1 / 3) + 2 * (p1 % 3);

  f32x4 acc[2][3];
  #pragma unroll
  for (int mt = 0; mt < 2; ++mt)
    #pragma unroll
    for (int tt = 0; tt < 3; ++tt) acc[mt][tt] = (f32x4){0.f, 0.f, 0.f, 0.f};

  if (w < 3) {
    #pragma unroll
    for (int s = 0; s < 12; ++s) {
      const int dy = s >> 2;
      const int c = ((s & 3) << 2) + g;
      int dx, icb;
      if (c >= 15)      { dx = 0; icb = 0; }   // zero chunk (ch 45)
      else if (c >= 10) { dx = 2; icb = (c - 10) * 8; }
      else if (c >= 5)  { dx = 1; icb = (c - 5) * 8; }
      else              { dx = 0; icb = c * 8; }
      const int rowb = (2 * w + dy) * 2560;    // staged row = 2*dyi + dy
      bf16x8 a0 = *(const bf16x8*)(s_in + rowb + (rb0 + dx) * CH + icb);
      bf16x8 a1 = *(const bf16x8*)(s_in + rowb + (rb1 + dx) * CH + icb);

      const u16* wrow = s_w + ((c == 15) ? 45 * 320 : (dy * 15 + c) * 320);
      bf16x8 b0 = *(const bf16x8*)(wrow + m * 8);
      bf16x8 b1 = *(const bf16x8*)(wrow + (m + 16) * 8);
      bf16x8 b2 = *(const bf16x8*)(wrow + (m >= 8 ? 312 : (m + 32) * 8));

      acc[0][0] = __builtin_amdgcn_mfma_f32_16x16x32_bf16(b0, a0, acc[0][0], 0, 0, 0);
      acc[1][0] = __builtin_amdgcn_mfma_f32_16x16x32_bf16(b0, a1, acc[1][0], 0, 0, 0);
      acc[0][1] = __builtin_amdgcn_mfma_f32_16x16x32_bf16(b1, a0, acc[0][1], 0, 0, 0);
      acc[1][1] = __builtin_amdgcn_mfma_f32_16x16x32_bf16(b1, a1, acc[1][1], 0, 0, 0);
      acc[0][2] = __builtin_amdgcn_mfma_f32_16x16x32_bf16(b2, a0, acc[0][2], 0, 0, 0);
      acc[1][2] = __builtin_amdgcn_mfma_f32_16x16x32_bf16(b2, a1, acc[1][2], 0, 0, 0);
    }
  }

  __syncthreads();                     // all waves' s_w/s_in reads complete
  if (w == 3) return;                  // no barriers after this point

  // restage gelu(acc+bias) into reused s_w region (per-wave 2048 B)
  char* so = (char*)s_w + w * 2048;
  float4 bv[3];
  bv[0] = *(const float4*)(bias + 4 * g);
  bv[1] = *(const float4*)(bias + 16 + 4 * g);
  bv[2] = (g < 2) ? *(const float4*)(bias + 32 + 4 * g)
                  : make_float4(0.f, 0.f, 0.f, 0.f);
  #pragma unroll
  for (int tt = 0; tt < 3; ++tt) {
    if (tt == 2 && g >= 2) continue;
    #pragma unroll
    for (int mt = 0; mt < 2; ++mt) {
      const int p = mt * 16 + m;
      if (p >= 24) continue;
      float v[4];
      #pragma unroll
      for (int i = 0; i < 4; ++i)
        v[i] = actf(acc[mt][tt][i] + ((const float*)&bv[tt])[i], 1);
      uint2 pk;
      pk.x = (u32)f2b(v[0]) | ((u32)f2b(v[1]) << 16);
      pk.y = (u32)f2b(v[2]) | ((u32)f2b(v[3]) << 16);
      int byt = p * 80 + (16 * tt + 4 * g) * 2;
      byt ^= ((p >> 3) & 7) << 4;
      *(uint2*)(so + byt) = pk;
    }
  }

  // writeback 120 chunks (24 pts x 5 octets): residual gather + edge zeroing
  const int yi = oy * 3 + w;
  const int y = 8 * oy - 2 + 2 * w;
  const bool rowinv = (y < 0);
  #pragma unroll
  for (int pass = 0; pass < 2; ++pass) {
    int j = pass * 64 + l;
    if (j >= 120) continue;
    int p = j / 5, oct = j % 5;
    int byt = p * 80 + oct * 16;
    byt ^= ((p >> 3) & 7) << 4;
    uint4 d = *(const uint4*)(so + byt);
    int x = 64 * xg + 8 * (p / 3) + 2 * (p % 3) - 2;
    if (rowinv || x < 0) {
      d = (uint4){0u, 0u, 0u, 0u};
    } else {
      const u16* rp = cla + (size_t)n * IMG_CL
                    + ((size_t)(y + 1) * IW + (x + 1)) * CH + oct * 8;
      uint4 rv = *(const uint4*)rp;
      d.x = addbf2(d.x, rv.x); d.y = addbf2(d.y, rv.y);
      d.z = addbf2(d.z, rv.z); d.w = addbf2(d.w, rv.w);
    }
    *(uint4*)(ddc + (((size_t)(n * 96 + yi)) * 96 + 24 * xg + p) * CH + oct * 8) = d;
  }
}

// ---- depthwise conv on compact dd: 9 dense taps (zeros encode clipping) --
__global__ __launch_bounds__(256)
void dwconv_c(const u16* __restrict__ ddc, const float* __restrict__ w,
              const float* __restrict__ b, float* __restrict__ out)
{
  int idx = blockIdx.x * 256 + threadIdx.x;
  if (idx >= 8 * 32 * 32 * CH) return;
  int c = idx % CH;
  int p = idx / CH;
  int ox = p & 31;
  int oy = (p >> 5) & 31;
  int n = p >> 10;
  float acc = b[c];
  const u16* base = ddc + (((size_t)(n * 96 + oy * 3)) * 96 + ox * 3) * CH + c;
  #pragma unroll
  for (int dyi = 0; dyi < 3; ++dyi)
    #pragma unroll
    for (int dxi = 0; dxi < 3; ++dxi)
      acc += w[c * 9 + dyi * 3 + dxi] * b2f(base[((size_t)dyi * 96 + dxi) * CH]);
  out[((size_t)(n * CH + c) << 10) + oy * 32 + ox] = acc;
}

// ---- per-8x8-block iDCT on planar f32 32x32 ------------------------------
__global__ __launch_bounds__(256)
void idct8_k(const float* __restrict__ in, float* __restrict__ out)
{
  __shared__ float ctab[8];
  if (threadIdx.x < 8) {
    const float c_[8] = {1.f, 0.70710678118654752f, 0.f, -0.70710678118654752f,
                         -1.f, -0.70710678118654752f, 0.f, 0.70710678118654752f};
    ctab[threadIdx.x] = c_[threadIdx.x];
  }
  __syncthreads();
  int idx = blockIdx.x * 256 + threadIdx.x;
  if (idx >= 8 * CH * 32 * 32) return;
  int ox = idx & 31, oy = (idx >> 5) & 31, bc = idx >> 10;
  int k = oy & 7, lq = ox & 7;
  const float* ip = in + bc * 1024 + (oy & ~7) * 32 + (ox & ~7);
  float acc = 0.f;
  #pragma unroll
  for (int mm = 0; mm < 8; ++mm) {
    float rk = ctab[(k * mm) & 7];
    float s = 0.f;
    #pragma unroll
    for (int nn = 0; nn < 8; ++nn)
      s += ctab[(lq * nn) & 7] * ip[mm * 32 + nn];
    acc += rk * s;
  }
  out[idx] = acc * 0.125f;
}

// ---- MFMA 1x1 conv + sigmoid + bilinear(32->256) multiply; cl bf16 -------
__global__ __launch_bounds__(256)
void wgtmul_k(const u16* __restrict__ t1cl, const u16* __restrict__ wt3,
              const float* __restrict__ b3, const float* __restrict__ dct,
              u16* __restrict__ outcl)
{
  __shared__ float s_yw[40 * 33];
  __shared__ u16 s_out[4 * 3072];

  const int q8 = (int)gridDim.x >> 3;
  const int bid = ((int)blockIdx.x & 7) * q8 + ((int)blockIdx.x >> 3);
  const int n = bid >> 8;
  const int y = bid & 255;
  const int tid = threadIdx.x;

  float sy = (y + 0.5f) * 0.125f - 0.5f;
  float yq = floorf(sy);
  float fy = sy - yq;
  int y0c = max((int)yq, 0), y1c = min((int)yq + 1, 31);

  for (int i = tid; i < 1280; i += 256) {
    int oc = i >> 5, c = i & 31;
    const float* sp = dct + ((size_t)(n * CH + oc) << 10);
    s_yw[oc * 33 + c] = (1.f - fy) * sp[y0c * 32 + c] + fy * sp[y1c * 32 + c];
  }
  __syncthreads();

  const int w = tid >> 6;
  const int l = tid & 63;
  const int g = l >> 4;
  const int m = l & 15;
  const int xb = w << 6;

  const u16* tp = t1cl + (size_t)n * IMG_CL + ((size_t)(y + 1) * IW + 1) * CH;

  f32x4 acc[4][3];
  #pragma unroll
  for (int xt = 0; xt < 4; ++xt)
    #pragma unroll
    for (int t = 0; t < 3; ++t) acc[xt][t] = (f32x4){0.f, 0.f, 0.f, 0.f};

  #pragma unroll
  for (int xt = 0; xt < 4; ++xt) {
    const u16* ap = tp + (size_t)(xb + xt * 16 + m) * CH;
    bf16x8 a0 = *(const bf16x8*)(ap + 8 * g);
    bf16x8 a1 = *(const bf16x8*)(ap + 32 + 8 * g);
    #pragma unroll
    for (int t = 0; t < 3; ++t) {
      bf16x8 b0 = *(const bf16x8*)(wt3 + (m + 16 * t) * 384 + 8 * g);
      bf16x8 b1 = *(const bf16x8*)(wt3 + (m + 16 * t) * 384 + 32 + 8 * g);
      acc[xt][t] = __builtin_amdgcn_mfma_f32_16x16x32_bf16(b0, a0, acc[xt][t], 0, 0, 0);
      acc[xt][t] = __builtin_amdgcn_mfma_f32_16x16x32_bf16(b1, a1, acc[xt][t], 0, 0, 0);
    }
  }

  u16* so = s_out + w * 3072;
  float4 bv[3];
  bv[0] = *(const float4*)(b3 + 4 * g);
  bv[1] = *(const float4*)(b3 + 16 + 4 * g);
  bv[2] = (g < 2) ? *(const float4*)(b3 + 32 + 4 * g) : make_float4(0.f, 0.f, 0.f, 0.f);
  #pragma unroll
  for (int t = 0; t < 3; ++t) {
    if (t == 2 && g >= 2) continue;
    #pragma unroll
    for (int xt = 0; xt < 4; ++xt) {
      const int pxl = xt * 16 + m;
      const int px = xb + pxl;
      float sx = (px + 0.5f) * 0.125f - 0.5f;
      float xq = floorf(sx);
      float fx = sx - xq;
      int x0c = max((int)xq, 0), x1c = min((int)xq + 1, 31);
      u16 r4[4];
      #pragma unroll
      for (int i = 0; i < 4; ++i) {
        int oc = 16 * t + 4 * g + i;
        float wgt = 1.f / (1.f + __expf(-(acc[xt][t][i] + ((const float*)&bv[t])[i])));
        float bil = (1.f - fx) * s_yw[oc * 33 + x0c] + fx * s_yw[oc * 33 + x1c];
        r4[i] = f2b(wgt * bil);
      }
      uint2 pk;
      pk.x = (u32)r4[0] | ((u32)r4[1] << 16);
      pk.y = (u32)r4[2] | ((u32)r4[3] << 16);
      int byt = pxl * 80 + (16 * t + 4 * g) * 2;
      byt ^= ((pxl >> 3) & 7) << 4;
      *(uint2*)((char*)so + byt) = pk;
    }
  }
  const size_t rowu = (size_t)n * IMG_CL + ((size_t)(y + 1) * IW + (xb + 1)) * CH;
  #pragma unroll
  for (int q = 0; q < 5; ++q) {
    int byt = l * 80 + q * 16;
    byt ^= ((l >> 3) & 7) << 4;
    uint4 d = *(const uint4*)((const char*)so + byt);
    *(uint4*)(outcl + rowu + (size_t)l * 40 + q * 8) = d;
  }
}

extern "C" void kernel_launch(void* const* d_in, const int* in_sizes, int n_in,
                              void* d_out, int out_size, void* d_ws, size_t ws_size,
                              hipStream_t stream)
{
  const float* x       = (const float*)d_in[0];
  const float* conv_w  = (const float*)d_in[1];
  const float* conv_b  = (const float*)d_in[2];
  const float* ddct_w  = (const float*)d_in[3];
  const float* ddct_b  = (const float*)d_in[4];
  const float* dctc_w  = (const float*)d_in[5];
  const float* dctc_b  = (const float*)d_in[6];
  const float* w1_w    = (const float*)d_in[7];
  const float* w1_b    = (const float*)d_in[8];
  const float* w3_w    = (const float*)d_in[9];
  const float* w3_b    = (const float*)d_in[10];
  const float* after_w = (const float*)d_in[11];
  const float* after_b = (const float*)d_in[12];

  char* ws = (char*)d_ws;
  const size_t CLB = (size_t)8 * IMG_CL * 2;          // 42,600,960 B
  u16*   xcl    = (u16*)ws;                           // x (bf16 cl)
  u16*   cl_a   = (u16*)(ws + CLB);                   // dct_feat, later prod
  u16*   cl_c   = (u16*)(ws + 2 * CLB);               // t1
  char*  base3  = ws + 3 * CLB;
  float* small0 = (float*)base3;                      // 1,310,720 B
  float* small1 = (float*)(base3 + 1310720);          // 1,310,720 B
  u16*   wt     = (u16*)(base3 + 2621440);            // 184,320 B (5 rm sets)
  u16*   wcm    = (u16*)(base3 + 2805760);            // 122,880 B (4 cm sets)
  u16*   wsc    = (u16*)(base3 + 2928640);            // 29,440 B (sconv set)
  u16*   ddc    = (u16*)(base3 + 2958080);            // 5,898,240 B compact dd

  // 0. weight transforms + input cl conversion + ring zeroing
  prep_w_k<<<658, 256, 0, stream>>>(conv_w, ddct_w, w1_w, after_w, w3_w,
                                    wt, wcm, wsc);
  prep_x_k<<<8 * IW, 256, 0, stream>>>(x, xcl, cl_a);
  // 1. dct_feat = gelu(conv(x))                    -> cl_a
  convl_k<1, false><<<2048, 256, 0, stream>>>(xcl, wcm, conv_b, cl_a);
  // 5. t1 = relu(conv(x, w1))                      -> cl_c
  convl_k<2, false><<<2048, 256, 0, stream>>>(xcl, wcm + WCM_SET, w1_b, cl_c);
  // 2. SPARSE dd at dwconv sample points           -> ddc (compact)
  sconv_k<<<1024, 256, 0, stream>>>(cl_a, wsc, ddct_b, ddc);
  // 3. depthwise strided conv on compact dd        -> small0
  dwconv_c<<<1280, 256, 0, stream>>>(ddc, dctc_w, dctc_b, small0);
  // 4. per-block 8x8 iDCT                          -> small1
  idct8_k<<<1280, 256, 0, stream>>>(small0, small1);
  // 6. prod = sigmoid(1x1(t1)) * bilinear(idct)    -> cl_a (dct_feat dead)
  wgtmul_k<<<2048, 256, 0, stream>>>(cl_c, wt + 4 * WT_SET, w3_b, small1, cl_a);
  // 7. out = conv(prod, after)                     -> d_out fp32 planar
  convl_k<0, true><<<2048, 256, 0, stream>>>(cl_a, wcm + 3 * WCM_SET, after_b, (void*)d_out);
}

// Round 14
// 196.152 us; speedup vs baseline: 2.0009x; 1.0241x over previous
//
#include <hip/hip_runtime.h>

typedef unsigned short u16;
typedef unsigned int u32;
typedef __attribute__((ext_vector_type(8))) short bf16x8;
typedef __attribute__((ext_vector_type(4))) float f32x4;

#define CH 40
#define IW 258                   // ring-padded width (256 + 2)
#define IWCH (IW * CH)           // 10320
#define IMG_CL (IW * IW * CH)    // u16 elements per image, channel-last padded
#define WT_SET (48 * 384)        // u16 per row-major set (wgtmul uses set 4)
#define WCM_SET (48 * 40 * 8)    // u16 per chunk-major set = 15360
#define WSC_SET (46 * 40 * 8)    // u16 compressed set: 45 real + 1 zero = 14720

#define GLDS16(g, l) __builtin_amdgcn_global_load_lds( \
    (const __attribute__((address_space(1))) void*)(g), \
    (__attribute__((address_space(3))) void*)(l), 16, 0, 0)

__device__ __forceinline__ float b2f(u16 u) {
  union { u32 i; float f; } v; v.i = ((u32)u) << 16; return v.f;
}
__device__ __forceinline__ u16 f2b(float f) {
  union { float f; u32 i; } v; v.f = f;
  u32 r = v.i + 0x7fffu + ((v.i >> 16) & 1u);
  return (u16)(r >> 16);
}
__device__ __forceinline__ u32 addbf2(u32 a, u32 b) {
  union { u32 i; float f; } lo_a, lo_b, hi_a, hi_b;
  lo_a.i = a << 16; lo_b.i = b << 16;
  hi_a.i = a & 0xffff0000u; hi_b.i = b & 0xffff0000u;
  float lo = lo_a.f + lo_b.f, hi = hi_a.f + hi_b.f;
  return (u32)f2b(lo) | ((u32)f2b(hi) << 16);
}
// tanh-approx gelu (validated r10: |err| ~3e-4, absmax unchanged)
__device__ __forceinline__ float actf(float t, int ACT) {
  if (ACT == 1) {
    float u2 = t * (1.5957691216057308f + 0.07135481627000862f * t * t);
    float e = __expf(u2);
    return t - t / (e + 1.f);
  }
  if (ACT == 2) return fmaxf(t, 0.f);
  return t;
}

// ---- weights: row-major x5 + chunk-major x4 + compressed 46-chunk x3 -----
// wcm sets: 0=conv_w, 1=w1_w, 2=ddct_w, 3=after_w (conv7 uses set 3)
// wsc sets ([46ch][40oc][8k], ch = dy*15+dx*5+icq, ch45 = 0):
//   0=conv_w, 1=w1_w, 2=ddct_w
__global__ __launch_bounds__(256)
void prep_w_k(const float* __restrict__ w0, const float* __restrict__ w1,
              const float* __restrict__ w2, const float* __restrict__ w3,
              const float* __restrict__ w4, u16* __restrict__ wt,
              u16* __restrict__ wcm, u16* __restrict__ wsc)
{
  int i = blockIdx.x * 256 + threadIdx.x;   // 92160 + 61440 + 44160 = 197760
  if (i >= 5 * WT_SET + 4 * WCM_SET + 3 * WSC_SET) return;
  if (i < 5 * WT_SET) {
    int k = i % 384;
    int oc = (i / 384) % 48;
    int set = i / WT_SET;
    u16 v = 0;
    if (set == 4) {
      if (oc < 40 && k < 40) v = f2b(w4[oc * 40 + k]);
    } else {
      int dy = k >> 7;
      int r = k & 127;
      if (oc < 40 && r < 120) {
        int dx = r / 40;
        int ic = r - dx * 40;
        const float* w = (set == 0) ? w0 : (set == 1) ? w1 : (set == 2) ? w2 : w3;
        v = f2b(w[((oc * 40 + ic) * 3 + dy) * 3 + dx]);
      }
    }
    wt[i] = v;
  } else if (i < 5 * WT_SET + 4 * WCM_SET) {
    int j = i - 5 * WT_SET;
    int set2 = j / WCM_SET;                 // 0 conv, 1 w1, 2 ddct, 3 after
    int r2 = j - set2 * WCM_SET;
    int c = r2 / 320;
    int rem = r2 - c * 320;
    int oc = rem >> 3;
    int e = rem & 7;
    int k = c * 8 + e;
    int dy = k >> 7;
    int r = k & 127;
    u16 v = 0;
    if (r < 120) {
      int dx = r / 40;
      int ic = r - dx * 40;
      const float* w = (set2 == 0) ? w0 : (set2 == 1) ? w2 : (set2 == 2) ? w1 : w3;
      v = f2b(w[((oc * 40 + ic) * 3 + dy) * 3 + dx]);
    }
    wcm[j] = v;
  } else {
    int j2 = i - 5 * WT_SET - 4 * WCM_SET;  // [0, 3*14720)
    int set3 = j2 / WSC_SET;                // 0 conv_w, 1 w1_w, 2 ddct_w
    int r3 = j2 - set3 * WSC_SET;
    int c2 = r3 / 320;
    int rem = r3 - c2 * 320;
    int oc = rem >> 3;
    int e = rem & 7;
    u16 v = 0;
    if (c2 < 45) {
      int dy = c2 / 15, cc = c2 % 15;
      int dx = cc / 5, icq = cc % 5;
      int ic = icq * 8 + e;
      const float* w = (set3 == 0) ? w0 : (set3 == 1) ? w2 : w1;
      v = f2b(w[((oc * 40 + ic) * 3 + dy) * 3 + dx]);
    }
    wsc[j2] = v;
  }
}

// ---- x fp32 planar -> xcl bf16 channel-last + zero rings of xcl, cla -----
__global__ __launch_bounds__(256)
void prep_x_k(const float* __restrict__ x, u16* __restrict__ xcl,
              u16* __restrict__ cla)
{
  const int n = blockIdx.x / IW;
  const int yr = blockIdx.x % IW;
  const int t = threadIdx.x;
  const size_t base = (size_t)n * IMG_CL + (size_t)yr * IWCH;
  const uint4 z = {0u, 0u, 0u, 0u};

  if (yr == 0 || yr == IW - 1) {
    for (int i = t; i < IWCH / 8; i += 256) {
      ((uint4*)(xcl + base))[i] = z;
      ((uint4*)(cla + base))[i] = z;
    }
    return;
  }
  if (t < 5) {
    ((uint4*)(xcl + base))[t] = z;
    ((uint4*)(cla + base))[t] = z;
  } else if (t < 10) {
    size_t b2 = base + (size_t)(IW - 1) * CH;
    ((uint4*)(xcl + b2))[t - 5] = z;
    ((uint4*)(cla + b2))[t - 5] = z;
  }
  const int y = yr - 1;
  const float* xp = x + (size_t)n * CH * 65536 + (size_t)y * 256 + t;
  __attribute__((aligned(16))) u16 buf[40];
  #pragma unroll
  for (int ic = 0; ic < 40; ++ic) buf[ic] = f2b(xp[(size_t)ic * 65536]);
  u16* dst = xcl + base + (size_t)(t + 1) * CH;
  #pragma unroll
  for (int q = 0; q < 5; ++q) ((uint4*)dst)[q] = ((const uint4*)buf)[q];
}

// ---- fused conv1+conv5, two weight passes over ONE staged x tile ---------
// Pass A: gelu(conv(x,wA)) -> outA cl ; Pass B: relu(conv(x,wB)) -> outB cl.
__global__ __launch_bounds__(256, 2)
void fconv2p_k(const u16* __restrict__ incl, const u16* __restrict__ wscA,
               const u16* __restrict__ wscB, const float* __restrict__ biasA,
               const float* __restrict__ biasB, u16* __restrict__ outA,
               u16* __restrict__ outB)
{
  __shared__ __align__(16) u16 s_mem[30560];   // x 15840 + w 14720 = 61120 B
  u16* s_in = s_mem;
  u16* s_w  = s_mem + 15840;                   // weight region; reused as restage

  const int tid = threadIdx.x;
  const int bid = ((int)blockIdx.x & 7) * 256 + ((int)blockIdx.x >> 3);
  const int n = bid >> 8;
  const int tb = bid & 255;
  const int y0 = (tb >> 2) << 2;
  const int x0 = (tb & 3) << 6;

  const u16* src = incl + (size_t)n * IMG_CL + ((size_t)y0 * IW + x0) * CH;
  #pragma unroll
  for (int k = 0; k < 8; ++k) {                // x tile: 1980 16B chunks
    int i = tid + (k << 8);
    if (i < 1980) {
      int r = i / 330, o = i - r * 330;
      GLDS16(src + (size_t)r * IWCH + o * 8, s_in + i * 8);
    }
  }
  #pragma unroll
  for (int k = 0; k < 8; ++k) {                // wA: 1840 16B chunks
    int i = tid + (k << 8);
    if (i < 1840) GLDS16(wscA + i * 8, s_w + i * 8);
  }
  __syncthreads();

  const int w = tid >> 6;
  const int l = tid & 63;
  const int g = l >> 4;
  const int m = l & 15;

  f32x4 accA[4][3], accB[4][3];
  #pragma unroll
  for (int xt = 0; xt < 4; ++xt)
    #pragma unroll
    for (int tt = 0; tt < 3; ++tt) {
      accA[xt][tt] = (f32x4){0.f, 0.f, 0.f, 0.f};
      accB[xt][tt] = (f32x4){0.f, 0.f, 0.f, 0.f};
    }

  // ---- K-loop pass A -----------------------------------------------------
  #pragma unroll
  for (int s = 0; s < 12; ++s) {
    const int dy = s >> 2;
    const int c = ((s & 3) << 2) + g;
    int dx, icb;
    if (c >= 15)      { dx = 0; icb = 0; }
    else if (c >= 10) { dx = 2; icb = (c - 10) * 8; }
    else if (c >= 5)  { dx = 1; icb = (c - 5) * 8; }
    else              { dx = 0; icb = c * 8; }
    const int abase = (w + dy) * (66 * CH) + (m + dx) * CH + icb;
    bf16x8 a0 = *(const bf16x8*)(s_in + abase);
    bf16x8 a1 = *(const bf16x8*)(s_in + abase + 16 * CH);
    bf16x8 a2 = *(const bf16x8*)(s_in + abase + 32 * CH);
    bf16x8 a3 = *(const bf16x8*)(s_in + abase + 48 * CH);
    const u16* wrow = s_w + ((c >= 15) ? 45 * 320 : (dy * 15 + c) * 320);
    bf16x8 b0 = *(const bf16x8*)(wrow + m * 8);
    bf16x8 b1 = *(const bf16x8*)(wrow + (m + 16) * 8);
    bf16x8 b2 = *(const bf16x8*)(wrow + (m >= 8 ? 312 : (m + 32) * 8));
    accA[0][0] = __builtin_amdgcn_mfma_f32_16x16x32_bf16(b0, a0, accA[0][0], 0, 0, 0);
    accA[1][0] = __builtin_amdgcn_mfma_f32_16x16x32_bf16(b0, a1, accA[1][0], 0, 0, 0);
    accA[2][0] = __builtin_amdgcn_mfma_f32_16x16x32_bf16(b0, a2, accA[2][0], 0, 0, 0);
    accA[3][0] = __builtin_amdgcn_mfma_f32_16x16x32_bf16(b0, a3, accA[3][0], 0, 0, 0);
    accA[0][1] = __builtin_amdgcn_mfma_f32_16x16x32_bf16(b1, a0, accA[0][1], 0, 0, 0);
    accA[1][1] = __builtin_amdgcn_mfma_f32_16x16x32_bf16(b1, a1, accA[1][1], 0, 0, 0);
    accA[2][1] = __builtin_amdgcn_mfma_f32_16x16x32_bf16(b1, a2, accA[2][1], 0, 0, 0);
    accA[3][1] = __builtin_amdgcn_mfma_f32_16x16x32_bf16(b1, a3, accA[3][1], 0, 0, 0);
    accA[0][2] = __builtin_amdgcn_mfma_f32_16x16x32_bf16(b2, a0, accA[0][2], 0, 0, 0);
    accA[1][2] = __builtin_amdgcn_mfma_f32_16x16x32_bf16(b2, a1, accA[1][2], 0, 0, 0);
    accA[2][2] = __builtin_amdgcn_mfma_f32_16x16x32_bf16(b2, a2, accA[2][2], 0, 0, 0);
    accA[3][2] = __builtin_amdgcn_mfma_f32_16x16x32_bf16(b2, a3, accA[3][2], 0, 0, 0);
  }

  __syncthreads();                             // all waves done reading wA
  #pragma unroll
  for (int k = 0; k < 8; ++k) {                // wB into same region
    int i = tid + (k << 8);
    if (i < 1840) GLDS16(wscB + i * 8, s_w + i * 8);
  }
  __syncthreads();                             // wB ready (vmcnt drained)

  // ---- K-loop pass B -----------------------------------------------------
  #pragma unroll
  for (int s = 0; s < 12; ++s) {
    const int dy = s >> 2;
    const int c = ((s & 3) << 2) + g;
    int dx, icb;
    if (c >= 15)      { dx = 0; icb = 0; }
    else if (c >= 10) { dx = 2; icb = (c - 10) * 8; }
    else if (c >= 5)  { dx = 1; icb = (c - 5) * 8; }
    else              { dx = 0; icb = c * 8; }
    const int abase = (w + dy) * (66 * CH) + (m + dx) * CH + icb;
    bf16x8 a0 = *(const bf16x8*)(s_in + abase);
    bf16x8 a1 = *(const bf16x8*)(s_in + abase + 16 * CH);
    bf16x8 a2 = *(const bf16x8*)(s_in + abase + 32 * CH);
    bf16x8 a3 = *(const bf16x8*)(s_in + abase + 48 * CH);
    const u16* wrow = s_w + ((c >= 15) ? 45 * 320 : (dy * 15 + c) * 320);
    bf16x8 b0 = *(const bf16x8*)(wrow + m * 8);
    bf16x8 b1 = *(const bf16x8*)(wrow + (m + 16) * 8);
    bf16x8 b2 = *(const bf16x8*)(wrow + (m >= 8 ? 312 : (m + 32) * 8));
    accB[0][0] = __builtin_amdgcn_mfma_f32_16x16x32_bf16(b0, a0, accB[0][0], 0, 0, 0);
    accB[1][0] = __builtin_amdgcn_mfma_f32_16x16x32_bf16(b0, a1, accB[1][0], 0, 0, 0);
    accB[2][0] = __builtin_amdgcn_mfma_f32_16x16x32_bf16(b0, a2, accB[2][0], 0, 0, 0);
    accB[3][0] = __builtin_amdgcn_mfma_f32_16x16x32_bf16(b0, a3, accB[3][0], 0, 0, 0);
    accB[0][1] = __builtin_amdgcn_mfma_f32_16x16x32_bf16(b1, a0, accB[0][1], 0, 0, 0);
    accB[1][1] = __builtin_amdgcn_mfma_f32_16x16x32_bf16(b1, a1, accB[1][1], 0, 0, 0);
    accB[2][1] = __builtin_amdgcn_mfma_f32_16x16x32_bf16(b1, a2, accB[2][1], 0, 0, 0);
    accB[3][1] = __builtin_amdgcn_mfma_f32_16x16x32_bf16(b1, a3, accB[3][1], 0, 0, 0);
    accB[0][2] = __builtin_amdgcn_mfma_f32_16x16x32_bf16(b2, a0, accB[0][2], 0, 0, 0);
    accB[1][2] = __builtin_amdgcn_mfma_f32_16x16x32_bf16(b2, a1, accB[1][2], 0, 0, 0);
    accB[2][2] = __builtin_amdgcn_mfma_f32_16x16x32_bf16(b2, a2, accB[2][2], 0, 0, 0);
    accB[3][2] = __builtin_amdgcn_mfma_f32_16x16x32_bf16(b2, a3, accB[3][2], 0, 0, 0);
  }

  const int y = y0 + w;
  const size_t rowu = (size_t)n * IMG_CL + ((size_t)(y + 1) * IW + (x0 + 1)) * CH;
  __syncthreads();                             // all waves done reading s_w/s_in

  // ---- epilogues: wave-private 5120 B restage regions in s_w --------------
  char* so = (char*)s_w + w * 5120;
  float4 bvA[3], bvB[3];
  bvA[0] = *(const float4*)(biasA + 4 * g);
  bvA[1] = *(const float4*)(biasA + 16 + 4 * g);
  bvA[2] = (g < 2) ? *(const float4*)(biasA + 32 + 4 * g) : make_float4(0.f, 0.f, 0.f, 0.f);
  bvB[0] = *(const float4*)(biasB + 4 * g);
  bvB[1] = *(const float4*)(biasB + 16 + 4 * g);
  bvB[2] = (g < 2) ? *(const float4*)(biasB + 32 + 4 * g) : make_float4(0.f, 0.f, 0.f, 0.f);

  // pass A restage + store (gelu)
  #pragma unroll
  for (int tt = 0; tt < 3; ++tt) {
    if (tt == 2 && g >= 2) continue;
    #pragma unroll
    for (int xt = 0; xt < 4; ++xt) {
      const int pxl = xt * 16 + m;
      float v[4];
      #pragma unroll
      for (int i = 0; i < 4; ++i)
        v[i] = actf(accA[xt][tt][i] + ((const float*)&bvA[tt])[i], 1);
      uint2 pk;
      pk.x = (u32)f2b(v[0]) | ((u32)f2b(v[1]) << 16);
      pk.y = (u32)f2b(v[2]) | ((u32)f2b(v[3]) << 16);
      int byt = pxl * 80 + (16 * tt + 4 * g) * 2;
      byt ^= ((pxl >> 3) & 7) << 4;
      *(uint2*)(so + byt) = pk;
    }
  }
  #pragma unroll
  for (int q = 0; q < 5; ++q) {
    int byt = l * 80 + q * 16;
    byt ^= ((l >> 3) & 7) << 4;
    uint4 d = *(const uint4*)(so + byt);
    *(uint4*)(outA + rowu + (size_t)l * 40 + q * 8) = d;
  }

  // pass B restage + store (relu) — same wave-private region, in-wave ordering
  #pragma unroll
  for (int tt = 0; tt < 3; ++tt) {
    if (tt == 2 && g >= 2) continue;
    #pragma unroll
    for (int xt = 0; xt < 4; ++xt) {
      const int pxl = xt * 16 + m;
      float v[4];
      #pragma unroll
      for (int i = 0; i < 4; ++i)
        v[i] = actf(accB[xt][tt][i] + ((const float*)&bvB[tt])[i], 2);
      uint2 pk;
      pk.x = (u32)f2b(v[0]) | ((u32)f2b(v[1]) << 16);
      pk.y = (u32)f2b(v[2]) | ((u32)f2b(v[3]) << 16);
      int byt = pxl * 80 + (16 * tt + 4 * g) * 2;
      byt ^= ((pxl >> 3) & 7) << 4;
      *(uint2*)(so + byt) = pk;
    }
  }
  #pragma unroll
  for (int q = 0; q < 5; ++q) {
    int byt = l * 80 + q * 16;
    byt ^= ((l >> 3) & 7) << 4;
    uint4 d = *(const uint4*)(so + byt);
    *(uint4*)(outB + rowu + (size_t)l * 40 + q * 8) = d;
  }
}

// ---- all-LDS-operand MFMA conv 3x3 (r12-verified; conv7 planar path) -----
template<int ACT, bool PLANAR>
__global__ __launch_bounds__(256, 2)
void convl_k(const u16* __restrict__ incl, const u16* __restrict__ wcm,
             const float* __restrict__ bias, void* __restrict__ outp)
{
  __shared__ __align__(16) u16 s_mem[31200];   // input 15840 + weights 15360
  u16* s_in = s_mem;
  u16* s_w  = s_mem + 15840;

  const int tid = threadIdx.x;
  const int bid = ((int)blockIdx.x & 7) * 256 + ((int)blockIdx.x >> 3);
  const int n = bid >> 8;
  const int tb = bid & 255;
  const int y0 = (tb >> 2) << 2;
  const int x0 = (tb & 3) << 6;

  const u16* src = incl + (size_t)n * IMG_CL + ((size_t)y0 * IW + x0) * CH;
  #pragma unroll
  for (int k = 0; k < 8; ++k) {
    int i = tid + (k << 8);
    if (i < 1980) {
      int r = i / 330, o = i - r * 330;
      GLDS16(src + (size_t)r * IWCH + o * 8, s_in + i * 8);
    }
  }
  #pragma unroll
  for (int k = 0; k < 8; ++k) {
    int i = tid + (k << 8);
    if (i < 1920) GLDS16(wcm + i * 8, s_w + i * 8);
  }
  __syncthreads();

  const int w = tid >> 6;
  const int l = tid & 63;
  const int g = l >> 4;
  const int m = l & 15;

  f32x4 acc[4][3];
  #pragma unroll
  for (int xt = 0; xt < 4; ++xt)
    #pragma unroll
    for (int tt = 0; tt < 3; ++tt) acc[xt][tt] = (f32x4){0.f, 0.f, 0.f, 0.f};

  #pragma unroll
  for (int s = 0; s < 12; ++s) {
    const int dy = s >> 2;
    const int c = ((s & 3) << 2) + g;
    int dx, icb;
    if (c >= 15)      { dx = 0; icb = 0; }
    else if (c >= 10) { dx = 2; icb = (c - 10) * 8; }
    else if (c >= 5)  { dx = 1; icb = (c - 5) * 8; }
    else              { dx = 0; icb = c * 8; }
    const int abase = (w + dy) * (66 * CH) + (m + dx) * CH + icb;
    bf16x8 a0 = *(const bf16x8*)(s_in + abase);
    bf16x8 a1 = *(const bf16x8*)(s_in + abase + 16 * CH);
    bf16x8 a2 = *(const bf16x8*)(s_in + abase + 32 * CH);
    bf16x8 a3 = *(const bf16x8*)(s_in + abase + 48 * CH);

    const int ch = (s << 2) + g;
    const u16* wrow = s_w + ch * 320;
    bf16x8 b0 = *(const bf16x8*)(wrow + m * 8);
    bf16x8 b1 = *(const bf16x8*)(wrow + (m + 16) * 8);
    bf16x8 b2 = *(const bf16x8*)(wrow + (m >= 8 ? 312 : (m + 32) * 8));

    #pragma unroll
    for (int xt = 0; xt < 4; ++xt) {
      bf16x8 aX = (xt == 0) ? a0 : (xt == 1) ? a1 : (xt == 2) ? a2 : a3;
      if (PLANAR) {
        acc[xt][0] = __builtin_amdgcn_mfma_f32_16x16x32_bf16(aX, b0, acc[xt][0], 0, 0, 0);
        acc[xt][1] = __builtin_amdgcn_mfma_f32_16x16x32_bf16(aX, b1, acc[xt][1], 0, 0, 0);
        acc[xt][2] = __builtin_amdgcn_mfma_f32_16x16x32_bf16(aX, b2, acc[xt][2], 0, 0, 0);
      } else {
        acc[xt][0] = __builtin_amdgcn_mfma_f32_16x16x32_bf16(b0, aX, acc[xt][0], 0, 0, 0);
        acc[xt][1] = __builtin_amdgcn_mfma_f32_16x16x32_bf16(b1, aX, acc[xt][1], 0, 0, 0);
        acc[xt][2] = __builtin_amdgcn_mfma_f32_16x16x32_bf16(b2, aX, acc[xt][2], 0, 0, 0);
      }
    }
  }

  const int y = y0 + w;

  if (PLANAR) {
    const float bv0 = bias[m];
    const float bv1 = bias[m + 16];
    const float bv2 = (m < 8) ? bias[m + 32] : 0.f;
    #pragma unroll
    for (int tt = 0; tt < 3; ++tt) {
      const int oc = m + 16 * tt;
      if (tt == 2 && m >= 8) continue;
      const float bv = (tt == 0) ? bv0 : (tt == 1) ? bv1 : bv2;
      #pragma unroll
      for (int xt = 0; xt < 4; ++xt) {
        const int xb = x0 + xt * 16 + 4 * g;
        float v[4];
        #pragma unroll
        for (int i = 0; i < 4; ++i) v[i] = actf(acc[xt][tt][i] + bv, ACT);
        *(float4*)((float*)outp + (((size_t)(n * CH + oc)) << 16) + ((size_t)y << 8) + xb)
            = make_float4(v[0], v[1], v[2], v[3]);
      }
    }
  } else {
    __syncthreads();
    char* so = (char*)s_mem + w * 5120;
    float4 bv[3];
    bv[0] = *(const float4*)(bias + 4 * g);
    bv[1] = *(const float4*)(bias + 16 + 4 * g);
    bv[2] = (g < 2) ? *(const float4*)(bias + 32 + 4 * g)
                    : make_float4(0.f, 0.f, 0.f, 0.f);
    #pragma unroll
    for (int tt = 0; tt < 3; ++tt) {
      if (tt == 2 && g >= 2) continue;
      #pragma unroll
      for (int xt = 0; xt < 4; ++xt) {
        const int pxl = xt * 16 + m;
        float v[4];
        #pragma unroll
        for (int i = 0; i < 4; ++i)
          v[i] = actf(acc[xt][tt][i] + ((const float*)&bv[tt])[i], ACT);
        uint2 pk;
        pk.x = (u32)f2b(v[0]) | ((u32)f2b(v[1]) << 16);
        pk.y = (u32)f2b(v[2]) | ((u32)f2b(v[3]) << 16);
        int byt = pxl * 80 + (16 * tt + 4 * g) * 2;
        byt ^= ((pxl >> 3) & 7) << 4;
        *(uint2*)(so + byt) = pk;
      }
    }
    const size_t rowu = (size_t)n * IMG_CL + ((size_t)(y + 1) * IW + (x0 + 1)) * CH;
    #pragma unroll
    for (int q = 0; q < 5; ++q) {
      int byt = l * 80 + q * 16;
      byt ^= ((l >> 3) & 7) << 4;
      uint4 d = *(const uint4*)(so + byt);
      *(uint4*)((u16*)outp + rowu + (size_t)l * 40 + q * 8) = d;
    }
  }
}

// ---- SPARSE conv2 (r13-verified): dd at dwconv sample points only --------
__global__ __launch_bounds__(256, 2)
void sconv_k(const u16* __restrict__ cla, const u16* __restrict__ wsc,
             const float* __restrict__ bias, u16* __restrict__ ddc)
{
  __shared__ __align__(16) u16 s_mem[32640];   // s_in 17920 + s_w 14720
  u16* s_in = s_mem;
  u16* s_w  = s_mem + 17920;

  const int tid = threadIdx.x;
  const int bid = ((int)blockIdx.x & 7) * 128 + ((int)blockIdx.x >> 3); // 1024
  const int n = bid >> 7;
  const int oy = (bid >> 2) & 31;
  const int xg = bid & 3;

  const u16* src = cla + (ptrdiff_t)((size_t)n * IMG_CL)
                       + (ptrdiff_t)(8 * oy - 2) * IWCH + (64 * xg - 2) * CH;
  #pragma unroll
  for (int k = 0; k < 9; ++k) {
    int i = tid + (k << 8);
    if (i < 2240) {
      int r = i / 320, o = i - r * 320;
      GLDS16(src + (ptrdiff_t)r * IWCH + o * 8, s_in + i * 8);
    }
  }
  #pragma unroll
  for (int k = 0; k < 8; ++k) {
    int i = tid + (k << 8);
    if (i < 1840) GLDS16(wsc + i * 8, s_w + i * 8);
  }
  __syncthreads();

  const int w = tid >> 6;
  const int l = tid & 63;
  const int g = l >> 4;
  const int m = l & 15;

  const int p0 = m;
  const int p1 = (m < 8) ? 16 + m : 23;
  const int rb0 = 8 * (p0 / 3) + 2 * (p0 % 3);
  const int rb1 = 8 * (p1 / 3) + 2 * (p1 % 3);

  f32x4 acc[2][3];
  #pragma unroll
  for (int mt = 0; mt < 2; ++mt)
    #pragma unroll
    for (int tt = 0; tt < 3; ++tt) acc[mt][tt] = (f32x4){0.f, 0.f, 0.f, 0.f};

  if (w < 3) {
    #pragma unroll
    for (int s = 0; s < 12; ++s) {
      const int dy = s >> 2;
      const int c = ((s & 3) << 2) + g;
      int dx, icb;
      if (c >= 15)      { dx = 0; icb = 0; }
      else if (c >= 10) { dx = 2; icb = (c - 10) * 8; }
      else if (c >= 5)  { dx = 1; icb = (c - 5) * 8; }
      else              { dx = 0; icb = c * 8; }
      const int rowb = (2 * w + dy) * 2560;
      bf16x8 a0 = *(const bf16x8*)(s_in + rowb + (rb0 + dx) * CH + icb);
      bf16x8 a1 = *(const bf16x8*)(s_in + rowb + (rb1 + dx) * CH + icb);

      const u16* wrow = s_w + ((c == 15) ? 45 * 320 : (dy * 15 + c) * 320);
      bf16x8 b0 = *(const bf16x8*)(wrow + m * 8);
      bf16x8 b1 = *(const bf16x8*)(wrow + (m + 16) * 8);
      bf16x8 b2 = *(const bf16x8*)(wrow + (m >= 8 ? 312 : (m + 32) * 8));

      acc[0][0] = __builtin_amdgcn_mfma_f32_16x16x32_bf16(b0, a0, acc[0][0], 0, 0, 0);
      acc[1][0] = __builtin_amdgcn_mfma_f32_16x16x32_bf16(b0, a1, acc[1][0], 0, 0, 0);
      acc[0][1] = __builtin_amdgcn_mfma_f32_16x16x32_bf16(b1, a0, acc[0][1], 0, 0, 0);
      acc[1][1] = __builtin_amdgcn_mfma_f32_16x16x32_bf16(b1, a1, acc[1][1], 0, 0, 0);
      acc[0][2] = __builtin_amdgcn_mfma_f32_16x16x32_bf16(b2, a0, acc[0][2], 0, 0, 0);
      acc[1][2] = __builtin_amdgcn_mfma_f32_16x16x32_bf16(b2, a1, acc[1][2], 0, 0, 0);
    }
  }

  __syncthreads();
  if (w == 3) return;

  char* so = (char*)s_w + w * 2048;
  float4 bv[3];
  bv[0] = *(const float4*)(bias + 4 * g);
  bv[1] = *(const float4*)(bias + 16 + 4 * g);
  bv[2] = (g < 2) ? *(const float4*)(bias + 32 + 4 * g)
                  : make_float4(0.f, 0.f, 0.f, 0.f);
  #pragma unroll
  for (int tt = 0; tt < 3; ++tt) {
    if (tt == 2 && g >= 2) continue;
    #pragma unroll
    for (int mt = 0; mt < 2; ++mt) {
      const int p = mt * 16 + m;
      if (p >= 24) continue;
      float v[4];
      #pragma unroll
      for (int i = 0; i < 4; ++i)
        v[i] = actf(acc[mt][tt][i] + ((const float*)&bv[tt])[i], 1);
      uint2 pk;
      pk.x = (u32)f2b(v[0]) | ((u32)f2b(v[1]) << 16);
      pk.y = (u32)f2b(v[2]) | ((u32)f2b(v[3]) << 16);
      int byt = p * 80 + (16 * tt + 4 * g) * 2;
      byt ^= ((p >> 3) & 7) << 4;
      *(uint2*)(so + byt) = pk;
    }
  }

  const int yi = oy * 3 + w;
  const int y = 8 * oy - 2 + 2 * w;
  const bool rowinv = (y < 0);
  #pragma unroll
  for (int pass = 0; pass < 2; ++pass) {
    int j = pass * 64 + l;
    if (j >= 120) continue;
    int p = j / 5, oct = j % 5;
    int byt = p * 80 + oct * 16;
    byt ^= ((p >> 3) & 7) << 4;
    uint4 d = *(const uint4*)(so + byt);
    int x = 64 * xg + 8 * (p / 3) + 2 * (p % 3) - 2;
    if (rowinv || x < 0) {
      d = (uint4){0u, 0u, 0u, 0u};
    } else {
      const u16* rp = cla + (size_t)n * IMG_CL
                    + ((size_t)(y + 1) * IW + (x + 1)) * CH + oct * 8;
      uint4 rv = *(const uint4*)rp;
      d.x = addbf2(d.x, rv.x); d.y = addbf2(d.y, rv.y);
      d.z = addbf2(d.z, rv.z); d.w = addbf2(d.w, rv.w);
    }
    *(uint4*)(ddc + (((size_t)(n * 96 + yi)) * 96 + 24 * xg + p) * CH + oct * 8) = d;
  }
}

// ---- depthwise conv on compact dd ----------------------------------------
__global__ __launch_bounds__(256)
void dwconv_c(const u16* __restrict__ ddc, const float* __restrict__ w,
              const float* __restrict__ b, float* __restrict__ out)
{
  int idx = blockIdx.x * 256 + threadIdx.x;
  if (idx >= 8 * 32 * 32 * CH) return;
  int c = idx % CH;
  int p = idx / CH;
  int ox = p & 31;
  int oy = (p >> 5) & 31;
  int n = p >> 10;
  float acc = b[c];
  const u16* base = ddc + (((size_t)(n * 96 + oy * 3)) * 96 + ox * 3) * CH + c;
  #pragma unroll
  for (int dyi = 0; dyi < 3; ++dyi)
    #pragma unroll
    for (int dxi = 0; dxi < 3; ++dxi)
      acc += w[c * 9 + dyi * 3 + dxi] * b2f(base[((size_t)dyi * 96 + dxi) * CH]);
  out[((size_t)(n * CH + c) << 10) + oy * 32 + ox] = acc;
}

// ---- per-8x8-block iDCT on planar f32 32x32 ------------------------------
__global__ __launch_bounds__(256)
void idct8_k(const float* __restrict__ in, float* __restrict__ out)
{
  __shared__ float ctab[8];
  if (threadIdx.x < 8) {
    const float c_[8] = {1.f, 0.70710678118654752f, 0.f, -0.70710678118654752f,
                         -1.f, -0.70710678118654752f, 0.f, 0.70710678118654752f};
    ctab[threadIdx.x] = c_[threadIdx.x];
  }
  __syncthreads();
  int idx = blockIdx.x * 256 + threadIdx.x;
  if (idx >= 8 * CH * 32 * 32) return;
  int ox = idx & 31, oy = (idx >> 5) & 31, bc = idx >> 10;
  int k = oy & 7, lq = ox & 7;
  const float* ip = in + bc * 1024 + (oy & ~7) * 32 + (ox & ~7);
  float acc = 0.f;
  #pragma unroll
  for (int mm = 0; mm < 8; ++mm) {
    float rk = ctab[(k * mm) & 7];
    float s = 0.f;
    #pragma unroll
    for (int nn = 0; nn < 8; ++nn)
      s += ctab[(lq * nn) & 7] * ip[mm * 32 + nn];
    acc += rk * s;
  }
  out[idx] = acc * 0.125f;
}

// ---- MFMA 1x1 conv + sigmoid + bilinear(32->256) multiply; cl bf16 -------
__global__ __launch_bounds__(256)
void wgtmul_k(const u16* __restrict__ t1cl, const u16* __restrict__ wt3,
              const float* __restrict__ b3, const float* __restrict__ dct,
              u16* __restrict__ outcl)
{
  __shared__ float s_yw[40 * 33];
  __shared__ u16 s_out[4 * 3072];

  const int q8 = (int)gridDim.x >> 3;
  const int bid = ((int)blockIdx.x & 7) * q8 + ((int)blockIdx.x >> 3);
  const int n = bid >> 8;
  const int y = bid & 255;
  const int tid = threadIdx.x;

  float sy = (y + 0.5f) * 0.125f - 0.5f;
  float yq = floorf(sy);
  float fy = sy - yq;
  int y0c = max((int)yq, 0), y1c = min((int)yq + 1, 31);

  for (int i = tid; i < 1280; i += 256) {
    int oc = i >> 5, c = i & 31;
    const float* sp = dct + ((size_t)(n * CH + oc) << 10);
    s_yw[oc * 33 + c] = (1.f - fy) * sp[y0c * 32 + c] + fy * sp[y1c * 32 + c];
  }
  __syncthreads();

  const int w = tid >> 6;
  const int l = tid & 63;
  const int g = l >> 4;
  const int m = l & 15;
  const int xb = w << 6;

  const u16* tp = t1cl + (size_t)n * IMG_CL + ((size_t)(y + 1) * IW + 1) * CH;

  f32x4 acc[4][3];
  #pragma unroll
  for (int xt = 0; xt < 4; ++xt)
    #pragma unroll
    for (int t = 0; t < 3; ++t) acc[xt][t] = (f32x4){0.f, 0.f, 0.f, 0.f};

  #pragma unroll
  for (int xt = 0; xt < 4; ++xt) {
    const u16* ap = tp + (size_t)(xb + xt * 16 + m) * CH;
    bf16x8 a0 = *(const bf16x8*)(ap + 8 * g);
    bf16x8 a1 = *(const bf16x8*)(ap + 32 + 8 * g);
    #pragma unroll
    for (int t = 0; t < 3; ++t) {
      bf16x8 b0 = *(const bf16x8*)(wt3 + (m + 16 * t) * 384 + 8 * g);
      bf16x8 b1 = *(const bf16x8*)(wt3 + (m + 16 * t) * 384 + 32 + 8 * g);
      acc[xt][t] = __builtin_amdgcn_mfma_f32_16x16x32_bf16(b0, a0, acc[xt][t], 0, 0, 0);
      acc[xt][t] = __builtin_amdgcn_mfma_f32_16x16x32_bf16(b1, a1, acc[xt][t], 0, 0, 0);
    }
  }

  u16* so = s_out + w * 3072;
  float4 bv[3];
  bv[0] = *(const float4*)(b3 + 4 * g);
  bv[1] = *(const float4*)(b3 + 16 + 4 * g);
  bv[2] = (g < 2) ? *(const float4*)(b3 + 32 + 4 * g) : make_float4(0.f, 0.f, 0.f, 0.f);
  #pragma unroll
  for (int t = 0; t < 3; ++t) {
    if (t == 2 && g >= 2) continue;
    #pragma unroll
    for (int xt = 0; xt < 4; ++xt) {
      const int pxl = xt * 16 + m;
      const int px = xb + pxl;
      float sx = (px + 0.5f) * 0.125f - 0.5f;
      float xq = floorf(sx);
      float fx = sx - xq;
      int x0c = max((int)xq, 0), x1c = min((int)xq + 1, 31);
      u16 r4[4];
      #pragma unroll
      for (int i = 0; i < 4; ++i) {
        int oc = 16 * t + 4 * g + i;
        float wgt = 1.f / (1.f + __expf(-(acc[xt][t][i] + ((const float*)&bv[t])[i])));
        float bil = (1.f - fx) * s_yw[oc * 33 + x0c] + fx * s_yw[oc * 33 + x1c];
        r4[i] = f2b(wgt * bil);
      }
      uint2 pk;
      pk.x = (u32)r4[0] | ((u32)r4[1] << 16);
      pk.y = (u32)r4[2] | ((u32)r4[3] << 16);
      int byt = pxl * 80 + (16 * t + 4 * g) * 2;
      byt ^= ((pxl >> 3) & 7) << 4;
      *(uint2*)((char*)so + byt) = pk;
    }
  }
  const size_t rowu = (size_t)n * IMG_CL + ((size_t)(y + 1) * IW + (xb + 1)) * CH;
  #pragma unroll
  for (int q = 0; q < 5; ++q) {
    int byt = l * 80 + q * 16;
    byt ^= ((l >> 3) & 7) << 4;
    uint4 d = *(const uint4*)((const char*)so + byt);
    *(uint4*)(outcl + rowu + (size_t)l * 40 + q * 8) = d;
  }
}

extern "C" void kernel_launch(void* const* d_in, const int* in_sizes, int n_in,
                              void* d_out, int out_size, void* d_ws, size_t ws_size,
                              hipStream_t stream)
{
  const float* x       = (const float*)d_in[0];
  const float* conv_w  = (const float*)d_in[1];
  const float* conv_b  = (const float*)d_in[2];
  const float* ddct_w  = (const float*)d_in[3];
  const float* ddct_b  = (const float*)d_in[4];
  const float* dctc_w  = (const float*)d_in[5];
  const float* dctc_b  = (const float*)d_in[6];
  const float* w1_w    = (const float*)d_in[7];
  const float* w1_b    = (const float*)d_in[8];
  const float* w3_w    = (const float*)d_in[9];
  const float* w3_b    = (const float*)d_in[10];
  const float* after_w = (const float*)d_in[11];
  const float* after_b = (const float*)d_in[12];

  char* ws = (char*)d_ws;
  const size_t CLB = (size_t)8 * IMG_CL * 2;          // 42,600,960 B
  u16*   xcl    = (u16*)ws;                           // x (bf16 cl)
  u16*   cl_a   = (u16*)(ws + CLB);                   // dct_feat, later prod
  u16*   cl_c   = (u16*)(ws + 2 * CLB);               // t1
  char*  base3  = ws + 3 * CLB;
  float* small0 = (float*)base3;                      // 1,310,720 B
  float* small1 = (float*)(base3 + 1310720);          // 1,310,720 B
  u16*   wt     = (u16*)(base3 + 2621440);            // 184,320 B (5 rm sets)
  u16*   wcm    = (u16*)(base3 + 2805760);            // 122,880 B (4 cm sets)
  u16*   wsc    = (u16*)(base3 + 2928640);            // 88,320 B (3 compressed)
  u16*   ddc    = (u16*)(base3 + 3016960);            // 5,898,240 B compact dd

  // 0. weight transforms + input cl conversion + ring zeroing
  prep_w_k<<<773, 256, 0, stream>>>(conv_w, ddct_w, w1_w, after_w, w3_w,
                                    wt, wcm, wsc);
  prep_x_k<<<8 * IW, 256, 0, stream>>>(x, xcl, cl_a);
  // 1+5. dct_feat = gelu(conv1(x)) -> cl_a ; t1 = relu(conv5(x)) -> cl_c
  //      (one x staging, two sequential weight passes)
  fconv2p_k<<<2048, 256, 0, stream>>>(xcl, wsc, wsc + WSC_SET,
                                      conv_b, w1_b, cl_a, cl_c);
  // 2. SPARSE dd at dwconv sample points           -> ddc (compact)
  sconv_k<<<1024, 256, 0, stream>>>(cl_a, wsc + 2 * WSC_SET, ddct_b, ddc);
  // 3. depthwise strided conv on compact dd        -> small0
  dwconv_c<<<1280, 256, 0, stream>>>(ddc, dctc_w, dctc_b, small0);
  // 4. per-block 8x8 iDCT                          -> small1
  idct8_k<<<1280, 256, 0, stream>>>(small0, small1);
  // 6. prod = sigmoid(1x1(t1)) * bilinear(idct)    -> cl_a (dct_feat dead)
  wgtmul_k<<<2048, 256, 0, stream>>>(cl_c, wt + 4 * WT_SET, w3_b, small1, cl_a);
  // 7. out = conv(prod, after)                     -> d_out fp32 planar
  convl_k<0, true><<<2048, 256, 0, stream>>>(cl_a, wcm + 3 * WCM_SET, after_b, (void*)d_out);
}

// Round 15
// 175.534 us; speedup vs baseline: 2.2359x; 1.1175x over previous
//
#include <hip/hip_runtime.h>

typedef unsigned short u16;
typedef unsigned int u32;
typedef __attribute__((ext_vector_type(8))) short bf16x8;
typedef __attribute__((ext_vector_type(4))) float f32x4;

#define CH 40
#define IW 258                   // ring-padded width (256 + 2)
#define IWCH (IW * CH)           // 10320
#define IMG_CL (IW * IW * CH)    // u16 elements per image, channel-last padded
#define WT_SET (48 * 384)        // u16: w3 row-major set (wgtmul)
#define WCM_SET (48 * 40 * 8)    // u16: after_w chunk-major set (conv7) = 15360
#define WSC_SET (46 * 40 * 8)    // u16 compressed set: 45 real + 1 zero = 14720

#define GLDS16(g, l) __builtin_amdgcn_global_load_lds( \
    (const __attribute__((address_space(1))) void*)(g), \
    (__attribute__((address_space(3))) void*)(l), 16, 0, 0)

__device__ __forceinline__ float b2f(u16 u) {
  union { u32 i; float f; } v; v.i = ((u32)u) << 16; return v.f;
}
__device__ __forceinline__ u16 f2b(float f) {
  union { float f; u32 i; } v; v.f = f;
  u32 r = v.i + 0x7fffu + ((v.i >> 16) & 1u);
  return (u16)(r >> 16);
}
__device__ __forceinline__ u32 addbf2(u32 a, u32 b) {
  union { u32 i; float f; } lo_a, lo_b, hi_a, hi_b;
  lo_a.i = a << 16; lo_b.i = b << 16;
  hi_a.i = a & 0xffff0000u; hi_b.i = b & 0xffff0000u;
  float lo = lo_a.f + lo_b.f, hi = hi_a.f + hi_b.f;
  return (u32)f2b(lo) | ((u32)f2b(hi) << 16);
}
// tanh-approx gelu (validated r10: |err| ~3e-4, absmax unchanged)
__device__ __forceinline__ float actf(float t, int ACT) {
  if (ACT == 1) {
    float u2 = t * (1.5957691216057308f + 0.07135481627000862f * t * t);
    float e = __expf(u2);
    return t - t / (e + 1.f);
  }
  if (ACT == 2) return fmaxf(t, 0.f);
  return t;
}

// ---- weights: w3 rm + after cm + compressed 46-chunk x3 ------------------
// wsc sets ([46ch][40oc][8k], ch = dy*15+dx*5+icq, ch45 = 0):
//   0=conv_w, 1=w1_w, 2=ddct_w
__global__ __launch_bounds__(256)
void prep_w_k(const float* __restrict__ w0, const float* __restrict__ w1,
              const float* __restrict__ w2, const float* __restrict__ w3,
              const float* __restrict__ w4, u16* __restrict__ wt4,
              u16* __restrict__ wcma, u16* __restrict__ wsc)
{
  int i = blockIdx.x * 256 + threadIdx.x;   // 18432 + 15360 + 44160 = 77952
  if (i >= WT_SET + WCM_SET + 3 * WSC_SET) return;
  if (i < WT_SET) {                          // w3 1x1 row-major [48][384]
    int k = i % 384;
    int oc = i / 384;
    u16 v = 0;
    if (oc < 40 && k < 40) v = f2b(w4[oc * 40 + k]);
    wt4[i] = v;
  } else if (i < WT_SET + WCM_SET) {         // after_w chunk-major [48][40][8]
    int j = i - WT_SET;
    int c = j / 320;
    int rem = j - c * 320;
    int oc = rem >> 3;
    int e = rem & 7;
    int k = c * 8 + e;
    int dy = k >> 7;
    int r = k & 127;
    u16 v = 0;
    if (r < 120) {
      int dx = r / 40;
      int ic = r - dx * 40;
      v = f2b(w3[((oc * 40 + ic) * 3 + dy) * 3 + dx]);
    }
    wcma[j] = v;
  } else {
    int j2 = i - WT_SET - WCM_SET;           // [0, 3*14720)
    int set3 = j2 / WSC_SET;                 // 0 conv_w, 1 w1_w, 2 ddct_w
    int r3 = j2 - set3 * WSC_SET;
    int c2 = r3 / 320;
    int rem = r3 - c2 * 320;
    int oc = rem >> 3;
    int e = rem & 7;
    u16 v = 0;
    if (c2 < 45) {
      int dy = c2 / 15, cc = c2 % 15;
      int dx = cc / 5, icq = cc % 5;
      int ic = icq * 8 + e;
      const float* w = (set3 == 0) ? w0 : (set3 == 1) ? w2 : w1;
      v = f2b(w[((oc * 40 + ic) * 3 + dy) * 3 + dx]);
    }
    wsc[j2] = v;
  }
}

// ---- zero the halo rings of cl_a (needed by sconv staging + conv7 halo) --
__global__ __launch_bounds__(256)
void ringz_k(u16* __restrict__ cla)
{
  const int n = blockIdx.x / IW;
  const int yr = blockIdx.x % IW;
  const int t = threadIdx.x;
  const size_t base = (size_t)n * IMG_CL + (size_t)yr * IWCH;
  const uint4 z = {0u, 0u, 0u, 0u};
  if (yr == 0 || yr == IW - 1) {
    for (int i = t; i < IWCH / 8; i += 256) ((uint4*)(cla + base))[i] = z;
    return;
  }
  if (t < 5) {
    ((uint4*)(cla + base))[t] = z;
  } else if (t < 10) {
    ((uint4*)(cla + base + (size_t)(IW - 1) * CH))[t - 5] = z;
  }
}

// ---- fused conv1+conv5: in-kernel x->bf16 conversion, two weight passes --
// Pass A: gelu(conv(x,wA)) -> outA cl ; Pass B: relu(conv(x,wB)) -> outB cl.
__global__ __launch_bounds__(256, 2)
void fconv2p_k(const float* __restrict__ xg, const u16* __restrict__ wscA,
               const u16* __restrict__ wscB, const float* __restrict__ biasA,
               const float* __restrict__ biasB, u16* __restrict__ outA,
               u16* __restrict__ outB)
{
  __shared__ __align__(16) u16 s_mem[30560];   // x 15840 + w 14720 = 61120 B
  u16* s_in = s_mem;
  u16* s_w  = s_mem + 15840;                   // weight region; reused as restage

  const int tid = threadIdx.x;
  const int bid = ((int)blockIdx.x & 7) * 256 + ((int)blockIdx.x >> 3);
  const int n = bid >> 8;
  const int tb = bid & 255;
  const int y0 = (tb >> 2) << 2;
  const int x0 = (tb & 3) << 6;

  // weights wA via async LDS copy (overlaps the conversion loads below)
  #pragma unroll
  for (int k = 0; k < 8; ++k) {
    int i = tid + (k << 8);
    if (i < 1840) GLDS16(wscA + i * 8, s_w + i * 8);
  }
  // stage x tile (6 rows x 66 px x 40 ic) from planar f32, converting to bf16
  const float* xsrc = xg + (size_t)n * CH * 65536;
  for (int slot = tid; slot < 396; slot += 256) {
    int r = slot / 66, p = slot - r * 66;
    int gy = y0 + r - 1, gx = x0 + p - 1;
    __attribute__((aligned(16))) u16 buf[40];
    if ((unsigned)gy < 256u && (unsigned)gx < 256u) {
      const float* xp = xsrc + (size_t)gy * 256 + gx;
      #pragma unroll
      for (int ic = 0; ic < 40; ++ic) buf[ic] = f2b(xp[(size_t)ic * 65536]);
    } else {
      #pragma unroll
      for (int ic = 0; ic < 40; ++ic) buf[ic] = 0;
    }
    u16* dst = s_in + slot * 40;
    #pragma unroll
    for (int q = 0; q < 5; ++q) ((uint4*)dst)[q] = ((const uint4*)buf)[q];
  }
  __syncthreads();

  const int w = tid >> 6;
  const int l = tid & 63;
  const int g = l >> 4;
  const int m = l & 15;

  f32x4 accA[4][3], accB[4][3];
  #pragma unroll
  for (int xt = 0; xt < 4; ++xt)
    #pragma unroll
    for (int tt = 0; tt < 3; ++tt) {
      accA[xt][tt] = (f32x4){0.f, 0.f, 0.f, 0.f};
      accB[xt][tt] = (f32x4){0.f, 0.f, 0.f, 0.f};
    }

  // ---- K-loop pass A -----------------------------------------------------
  #pragma unroll
  for (int s = 0; s < 12; ++s) {
    const int dy = s >> 2;
    const int c = ((s & 3) << 2) + g;
    int dx, icb;
    if (c >= 15)      { dx = 0; icb = 0; }
    else if (c >= 10) { dx = 2; icb = (c - 10) * 8; }
    else if (c >= 5)  { dx = 1; icb = (c - 5) * 8; }
    else              { dx = 0; icb = c * 8; }
    const int abase = (w + dy) * (66 * CH) + (m + dx) * CH + icb;
    bf16x8 a0 = *(const bf16x8*)(s_in + abase);
    bf16x8 a1 = *(const bf16x8*)(s_in + abase + 16 * CH);
    bf16x8 a2 = *(const bf16x8*)(s_in + abase + 32 * CH);
    bf16x8 a3 = *(const bf16x8*)(s_in + abase + 48 * CH);
    const u16* wrow = s_w + ((c >= 15) ? 45 * 320 : (dy * 15 + c) * 320);
    bf16x8 b0 = *(const bf16x8*)(wrow + m * 8);
    bf16x8 b1 = *(const bf16x8*)(wrow + (m + 16) * 8);
    bf16x8 b2 = *(const bf16x8*)(wrow + (m >= 8 ? 312 : (m + 32) * 8));
    accA[0][0] = __builtin_amdgcn_mfma_f32_16x16x32_bf16(b0, a0, accA[0][0], 0, 0, 0);
    accA[1][0] = __builtin_amdgcn_mfma_f32_16x16x32_bf16(b0, a1, accA[1][0], 0, 0, 0);
    accA[2][0] = __builtin_amdgcn_mfma_f32_16x16x32_bf16(b0, a2, accA[2][0], 0, 0, 0);
    accA[3][0] = __builtin_amdgcn_mfma_f32_16x16x32_bf16(b0, a3, accA[3][0], 0, 0, 0);
    accA[0][1] = __builtin_amdgcn_mfma_f32_16x16x32_bf16(b1, a0, accA[0][1], 0, 0, 0);
    accA[1][1] = __builtin_amdgcn_mfma_f32_16x16x32_bf16(b1, a1, accA[1][1], 0, 0, 0);
    accA[2][1] = __builtin_amdgcn_mfma_f32_16x16x32_bf16(b1, a2, accA[2][1], 0, 0, 0);
    accA[3][1] = __builtin_amdgcn_mfma_f32_16x16x32_bf16(b1, a3, accA[3][1], 0, 0, 0);
    accA[0][2] = __builtin_amdgcn_mfma_f32_16x16x32_bf16(b2, a0, accA[0][2], 0, 0, 0);
    accA[1][2] = __builtin_amdgcn_mfma_f32_16x16x32_bf16(b2, a1, accA[1][2], 0, 0, 0);
    accA[2][2] = __builtin_amdgcn_mfma_f32_16x16x32_bf16(b2, a2, accA[2][2], 0, 0, 0);
    accA[3][2] = __builtin_amdgcn_mfma_f32_16x16x32_bf16(b2, a3, accA[3][2], 0, 0, 0);
  }

  __syncthreads();                             // all waves done reading wA
  #pragma unroll
  for (int k = 0; k < 8; ++k) {                // wB into same region
    int i = tid + (k << 8);
    if (i < 1840) GLDS16(wscB + i * 8, s_w + i * 8);
  }
  __syncthreads();                             // wB ready (vmcnt drained)

  // ---- K-loop pass B -----------------------------------------------------
  #pragma unroll
  for (int s = 0; s < 12; ++s) {
    const int dy = s >> 2;
    const int c = ((s & 3) << 2) + g;
    int dx, icb;
    if (c >= 15)      { dx = 0; icb = 0; }
    else if (c >= 10) { dx = 2; icb = (c - 10) * 8; }
    else if (c >= 5)  { dx = 1; icb = (c - 5) * 8; }
    else              { dx = 0; icb = c * 8; }
    const int abase = (w + dy) * (66 * CH) + (m + dx) * CH + icb;
    bf16x8 a0 = *(const bf16x8*)(s_in + abase);
    bf16x8 a1 = *(const bf16x8*)(s_in + abase + 16 * CH);
    bf16x8 a2 = *(const bf16x8*)(s_in + abase + 32 * CH);
    bf16x8 a3 = *(const bf16x8*)(s_in + abase + 48 * CH);
    const u16* wrow = s_w + ((c >= 15) ? 45 * 320 : (dy * 15 + c) * 320);
    bf16x8 b0 = *(const bf16x8*)(wrow + m * 8);
    bf16x8 b1 = *(const bf16x8*)(wrow + (m + 16) * 8);
    bf16x8 b2 = *(const bf16x8*)(wrow + (m >= 8 ? 312 : (m + 32) * 8));
    accB[0][0] = __builtin_amdgcn_mfma_f32_16x16x32_bf16(b0, a0, accB[0][0], 0, 0, 0);
    accB[1][0] = __builtin_amdgcn_mfma_f32_16x16x32_bf16(b0, a1, accB[1][0], 0, 0, 0);
    accB[2][0] = __builtin_amdgcn_mfma_f32_16x16x32_bf16(b0, a2, accB[2][0], 0, 0, 0);
    accB[3][0] = __builtin_amdgcn_mfma_f32_16x16x32_bf16(b0, a3, accB[3][0], 0, 0, 0);
    accB[0][1] = __builtin_amdgcn_mfma_f32_16x16x32_bf16(b1, a0, accB[0][1], 0, 0, 0);
    accB[1][1] = __builtin_amdgcn_mfma_f32_16x16x32_bf16(b1, a1, accB[1][1], 0, 0, 0);
    accB[2][1] = __builtin_amdgcn_mfma_f32_16x16x32_bf16(b1, a2, accB[2][1], 0, 0, 0);
    accB[3][1] = __builtin_amdgcn_mfma_f32_16x16x32_bf16(b1, a3, accB[3][1], 0, 0, 0);
    accB[0][2] = __builtin_amdgcn_mfma_f32_16x16x32_bf16(b2, a0, accB[0][2], 0, 0, 0);
    accB[1][2] = __builtin_amdgcn_mfma_f32_16x16x32_bf16(b2, a1, accB[1][2], 0, 0, 0);
    accB[2][2] = __builtin_amdgcn_mfma_f32_16x16x32_bf16(b2, a2, accB[2][2], 0, 0, 0);
    accB[3][2] = __builtin_amdgcn_mfma_f32_16x16x32_bf16(b2, a3, accB[3][2], 0, 0, 0);
  }

  const int y = y0 + w;
  const size_t rowu = (size_t)n * IMG_CL + ((size_t)(y + 1) * IW + (x0 + 1)) * CH;
  __syncthreads();                             // all waves done reading s_w/s_in

  // ---- epilogues: wave-private 5120 B restage regions in s_w --------------
  char* so = (char*)s_w + w * 5120;
  float4 bvA[3], bvB[3];
  bvA[0] = *(const float4*)(biasA + 4 * g);
  bvA[1] = *(const float4*)(biasA + 16 + 4 * g);
  bvA[2] = (g < 2) ? *(const float4*)(biasA + 32 + 4 * g) : make_float4(0.f, 0.f, 0.f, 0.f);
  bvB[0] = *(const float4*)(biasB + 4 * g);
  bvB[1] = *(const float4*)(biasB + 16 + 4 * g);
  bvB[2] = (g < 2) ? *(const float4*)(biasB + 32 + 4 * g) : make_float4(0.f, 0.f, 0.f, 0.f);

  #pragma unroll
  for (int tt = 0; tt < 3; ++tt) {
    if (tt == 2 && g >= 2) continue;
    #pragma unroll
    for (int xt = 0; xt < 4; ++xt) {
      const int pxl = xt * 16 + m;
      float v[4];
      #pragma unroll
      for (int i = 0; i < 4; ++i)
        v[i] = actf(accA[xt][tt][i] + ((const float*)&bvA[tt])[i], 1);
      uint2 pk;
      pk.x = (u32)f2b(v[0]) | ((u32)f2b(v[1]) << 16);
      pk.y = (u32)f2b(v[2]) | ((u32)f2b(v[3]) << 16);
      int byt = pxl * 80 + (16 * tt + 4 * g) * 2;
      byt ^= ((pxl >> 3) & 7) << 4;
      *(uint2*)(so + byt) = pk;
    }
  }
  #pragma unroll
  for (int q = 0; q < 5; ++q) {
    int byt = l * 80 + q * 16;
    byt ^= ((l >> 3) & 7) << 4;
    uint4 d = *(const uint4*)(so + byt);
    *(uint4*)(outA + rowu + (size_t)l * 40 + q * 8) = d;
  }

  #pragma unroll
  for (int tt = 0; tt < 3; ++tt) {
    if (tt == 2 && g >= 2) continue;
    #pragma unroll
    for (int xt = 0; xt < 4; ++xt) {
      const int pxl = xt * 16 + m;
      float v[4];
      #pragma unroll
      for (int i = 0; i < 4; ++i)
        v[i] = actf(accB[xt][tt][i] + ((const float*)&bvB[tt])[i], 2);
      uint2 pk;
      pk.x = (u32)f2b(v[0]) | ((u32)f2b(v[1]) << 16);
      pk.y = (u32)f2b(v[2]) | ((u32)f2b(v[3]) << 16);
      int byt = pxl * 80 + (16 * tt + 4 * g) * 2;
      byt ^= ((pxl >> 3) & 7) << 4;
      *(uint2*)(so + byt) = pk;
    }
  }
  #pragma unroll
  for (int q = 0; q < 5; ++q) {
    int byt = l * 80 + q * 16;
    byt ^= ((l >> 3) & 7) << 4;
    uint4 d = *(const uint4*)(so + byt);
    *(uint4*)(outB + rowu + (size_t)l * 40 + q * 8) = d;
  }
}

// ---- all-LDS-operand MFMA conv 3x3 (r12-verified; conv7 planar path) -----
template<int ACT, bool PLANAR>
__global__ __launch_bounds__(256, 2)
void convl_k(const u16* __restrict__ incl, const u16* __restrict__ wcm,
             const float* __restrict__ bias, void* __restrict__ outp)
{
  __shared__ __align__(16) u16 s_mem[31200];   // input 15840 + weights 15360
  u16* s_in = s_mem;
  u16* s_w  = s_mem + 15840;

  const int tid = threadIdx.x;
  const int bid = ((int)blockIdx.x & 7) * 256 + ((int)blockIdx.x >> 3);
  const int n = bid >> 8;
  const int tb = bid & 255;
  const int y0 = (tb >> 2) << 2;
  const int x0 = (tb & 3) << 6;

  const u16* src = incl + (size_t)n * IMG_CL + ((size_t)y0 * IW + x0) * CH;
  #pragma unroll
  for (int k = 0; k < 8; ++k) {
    int i = tid + (k << 8);
    if (i < 1980) {
      int r = i / 330, o = i - r * 330;
      GLDS16(src + (size_t)r * IWCH + o * 8, s_in + i * 8);
    }
  }
  #pragma unroll
  for (int k = 0; k < 8; ++k) {
    int i = tid + (k << 8);
    if (i < 1920) GLDS16(wcm + i * 8, s_w + i * 8);
  }
  __syncthreads();

  const int w = tid >> 6;
  const int l = tid & 63;
  const int g = l >> 4;
  const int m = l & 15;

  f32x4 acc[4][3];
  #pragma unroll
  for (int xt = 0; xt < 4; ++xt)
    #pragma unroll
    for (int tt = 0; tt < 3; ++tt) acc[xt][tt] = (f32x4){0.f, 0.f, 0.f, 0.f};

  #pragma unroll
  for (int s = 0; s < 12; ++s) {
    const int dy = s >> 2;
    const int c = ((s & 3) << 2) + g;
    int dx, icb;
    if (c >= 15)      { dx = 0; icb = 0; }
    else if (c >= 10) { dx = 2; icb = (c - 10) * 8; }
    else if (c >= 5)  { dx = 1; icb = (c - 5) * 8; }
    else              { dx = 0; icb = c * 8; }
    const int abase = (w + dy) * (66 * CH) + (m + dx) * CH + icb;
    bf16x8 a0 = *(const bf16x8*)(s_in + abase);
    bf16x8 a1 = *(const bf16x8*)(s_in + abase + 16 * CH);
    bf16x8 a2 = *(const bf16x8*)(s_in + abase + 32 * CH);
    bf16x8 a3 = *(const bf16x8*)(s_in + abase + 48 * CH);

    const int ch = (s << 2) + g;
    const u16* wrow = s_w + ch * 320;
    bf16x8 b0 = *(const bf16x8*)(wrow + m * 8);
    bf16x8 b1 = *(const bf16x8*)(wrow + (m + 16) * 8);
    bf16x8 b2 = *(const bf16x8*)(wrow + (m >= 8 ? 312 : (m + 32) * 8));

    #pragma unroll
    for (int xt = 0; xt < 4; ++xt) {
      bf16x8 aX = (xt == 0) ? a0 : (xt == 1) ? a1 : (xt == 2) ? a2 : a3;
      if (PLANAR) {
        acc[xt][0] = __builtin_amdgcn_mfma_f32_16x16x32_bf16(aX, b0, acc[xt][0], 0, 0, 0);
        acc[xt][1] = __builtin_amdgcn_mfma_f32_16x16x32_bf16(aX, b1, acc[xt][1], 0, 0, 0);
        acc[xt][2] = __builtin_amdgcn_mfma_f32_16x16x32_bf16(aX, b2, acc[xt][2], 0, 0, 0);
      } else {
        acc[xt][0] = __builtin_amdgcn_mfma_f32_16x16x32_bf16(b0, aX, acc[xt][0], 0, 0, 0);
        acc[xt][1] = __builtin_amdgcn_mfma_f32_16x16x32_bf16(b1, aX, acc[xt][1], 0, 0, 0);
        acc[xt][2] = __builtin_amdgcn_mfma_f32_16x16x32_bf16(b2, aX, acc[xt][2], 0, 0, 0);
      }
    }
  }

  const int y = y0 + w;

  if (PLANAR) {
    const float bv0 = bias[m];
    const float bv1 = bias[m + 16];
    const float bv2 = (m < 8) ? bias[m + 32] : 0.f;
    #pragma unroll
    for (int tt = 0; tt < 3; ++tt) {
      const int oc = m + 16 * tt;
      if (tt == 2 && m >= 8) continue;
      const float bv = (tt == 0) ? bv0 : (tt == 1) ? bv1 : bv2;
      #pragma unroll
      for (int xt = 0; xt < 4; ++xt) {
        const int xb = x0 + xt * 16 + 4 * g;
        float v[4];
        #pragma unroll
        for (int i = 0; i < 4; ++i) v[i] = actf(acc[xt][tt][i] + bv, ACT);
        *(float4*)((float*)outp + (((size_t)(n * CH + oc)) << 16) + ((size_t)y << 8) + xb)
            = make_float4(v[0], v[1], v[2], v[3]);
      }
    }
  } else {
    __syncthreads();
    char* so = (char*)s_mem + w * 5120;
    float4 bv[3];
    bv[0] = *(const float4*)(bias + 4 * g);
    bv[1] = *(const float4*)(bias + 16 + 4 * g);
    bv[2] = (g < 2) ? *(const float4*)(bias + 32 + 4 * g)
                    : make_float4(0.f, 0.f, 0.f, 0.f);
    #pragma unroll
    for (int tt = 0; tt < 3; ++tt) {
      if (tt == 2 && g >= 2) continue;
      #pragma unroll
      for (int xt = 0; xt < 4; ++xt) {
        const int pxl = xt * 16 + m;
        float v[4];
        #pragma unroll
        for (int i = 0; i < 4; ++i)
          v[i] = actf(acc[xt][tt][i] + ((const float*)&bv[tt])[i], ACT);
        uint2 pk;
        pk.x = (u32)f2b(v[0]) | ((u32)f2b(v[1]) << 16);
        pk.y = (u32)f2b(v[2]) | ((u32)f2b(v[3]) << 16);
        int byt = pxl * 80 + (16 * tt + 4 * g) * 2;
        byt ^= ((pxl >> 3) & 7) << 4;
        *(uint2*)(so + byt) = pk;
      }
    }
    const size_t rowu = (size_t)n * IMG_CL + ((size_t)(y + 1) * IW + (x0 + 1)) * CH;
    #pragma unroll
    for (int q = 0; q < 5; ++q) {
      int byt = l * 80 + q * 16;
      byt ^= ((l >> 3) & 7) << 4;
      uint4 d = *(const uint4*)(so + byt);
      *(uint4*)((u16*)outp + rowu + (size_t)l * 40 + q * 8) = d;
    }
  }
}

// ---- SPARSE conv2 (r13-verified): dd at dwconv sample points only --------
__global__ __launch_bounds__(256, 2)
void sconv_k(const u16* __restrict__ cla, const u16* __restrict__ wsc,
             const float* __restrict__ bias, u16* __restrict__ ddc)
{
  __shared__ __align__(16) u16 s_mem[32640];   // s_in 17920 + s_w 14720
  u16* s_in = s_mem;
  u16* s_w  = s_mem + 17920;

  const int tid = threadIdx.x;
  const int bid = ((int)blockIdx.x & 7) * 128 + ((int)blockIdx.x >> 3); // 1024
  const int n = bid >> 7;
  const int oy = (bid >> 2) & 31;
  const int xg = bid & 3;

  const u16* src = cla + (ptrdiff_t)((size_t)n * IMG_CL)
                       + (ptrdiff_t)(8 * oy - 2) * IWCH + (64 * xg - 2) * CH;
  #pragma unroll
  for (int k = 0; k < 9; ++k) {
    int i = tid + (k << 8);
    if (i < 2240) {
      int r = i / 320, o = i - r * 320;
      GLDS16(src + (ptrdiff_t)r * IWCH + o * 8, s_in + i * 8);
    }
  }
  #pragma unroll
  for (int k = 0; k < 8; ++k) {
    int i = tid + (k << 8);
    if (i < 1840) GLDS16(wsc + i * 8, s_w + i * 8);
  }
  __syncthreads();

  const int w = tid >> 6;
  const int l = tid & 63;
  const int g = l >> 4;
  const int m = l & 15;

  const int p0 = m;
  const int p1 = (m < 8) ? 16 + m : 23;
  const int rb0 = 8 * (p0 / 3) + 2 * (p0 % 3);
  const int rb1 = 8 * (p1 / 3) + 2 * (p1 % 3);

  f32x4 acc[2][3];
  #pragma unroll
  for (int mt = 0; mt < 2; ++mt)
    #pragma unroll
    for (int tt = 0; tt < 3; ++tt) acc[mt][tt] = (f32x4){0.f, 0.f, 0.f, 0.f};

  if (w < 3) {
    #pragma unroll
    for (int s = 0; s < 12; ++s) {
      const int dy = s >> 2;
      const int c = ((s & 3) << 2) + g;
      int dx, icb;
      if (c >= 15)      { dx = 0; icb = 0; }
      else if (c >= 10) { dx = 2; icb = (c - 10) * 8; }
      else if (c >= 5)  { dx = 1; icb = (c - 5) * 8; }
      else              { dx = 0; icb = c * 8; }
      const int rowb = (2 * w + dy) * 2560;
      bf16x8 a0 = *(const bf16x8*)(s_in + rowb + (rb0 + dx) * CH + icb);
      bf16x8 a1 = *(const bf16x8*)(s_in + rowb + (rb1 + dx) * CH + icb);

      const u16* wrow = s_w + ((c == 15) ? 45 * 320 : (dy * 15 + c) * 320);
      bf16x8 b0 = *(const bf16x8*)(wrow + m * 8);
      bf16x8 b1 = *(const bf16x8*)(wrow + (m + 16) * 8);
      bf16x8 b2 = *(const bf16x8*)(wrow + (m >= 8 ? 312 : (m + 32) * 8));

      acc[0][0] = __builtin_amdgcn_mfma_f32_16x16x32_bf16(b0, a0, acc[0][0], 0, 0, 0);
      acc[1][0] = __builtin_amdgcn_mfma_f32_16x16x32_bf16(b0, a1, acc[1][0], 0, 0, 0);
      acc[0][1] = __builtin_amdgcn_mfma_f32_16x16x32_bf16(b1, a0, acc[0][1], 0, 0, 0);
      acc[1][1] = __builtin_amdgcn_mfma_f32_16x16x32_bf16(b1, a1, acc[1][1], 0, 0, 0);
      acc[0][2] = __builtin_amdgcn_mfma_f32_16x16x32_bf16(b2, a0, acc[0][2], 0, 0, 0);
      acc[1][2] = __builtin_amdgcn_mfma_f32_16x16x32_bf16(b2, a1, acc[1][2], 0, 0, 0);
    }
  }

  __syncthreads();
  if (w == 3) return;

  char* so = (char*)s_w + w * 2048;
  float4 bv[3];
  bv[0] = *(const float4*)(bias + 4 * g);
  bv[1] = *(const float4*)(bias + 16 + 4 * g);
  bv[2] = (g < 2) ? *(const float4*)(bias + 32 + 4 * g)
                  : make_float4(0.f, 0.f, 0.f, 0.f);
  #pragma unroll
  for (int tt = 0; tt < 3; ++tt) {
    if (tt == 2 && g >= 2) continue;
    #pragma unroll
    for (int mt = 0; mt < 2; ++mt) {
      const int p = mt * 16 + m;
      if (p >= 24) continue;
      float v[4];
      #pragma unroll
      for (int i = 0; i < 4; ++i)
        v[i] = actf(acc[mt][tt][i] + ((const float*)&bv[tt])[i], 1);
      uint2 pk;
      pk.x = (u32)f2b(v[0]) | ((u32)f2b(v[1]) << 16);
      pk.y = (u32)f2b(v[2]) | ((u32)f2b(v[3]) << 16);
      int byt = p * 80 + (16 * tt + 4 * g) * 2;
      byt ^= ((p >> 3) & 7) << 4;
      *(uint2*)(so + byt) = pk;
    }
  }

  const int yi = oy * 3 + w;
  const int y = 8 * oy - 2 + 2 * w;
  const bool rowinv = (y < 0);
  #pragma unroll
  for (int pass = 0; pass < 2; ++pass) {
    int j = pass * 64 + l;
    if (j >= 120) continue;
    int p = j / 5, oct = j % 5;
    int byt = p * 80 + oct * 16;
    byt ^= ((p >> 3) & 7) << 4;
    uint4 d = *(const uint4*)(so + byt);
    int x = 64 * xg + 8 * (p / 3) + 2 * (p % 3) - 2;
    if (rowinv || x < 0) {
      d = (uint4){0u, 0u, 0u, 0u};
    } else {
      const u16* rp = cla + (size_t)n * IMG_CL
                    + ((size_t)(y + 1) * IW + (x + 1)) * CH + oct * 8;
      uint4 rv = *(const uint4*)rp;
      d.x = addbf2(d.x, rv.x); d.y = addbf2(d.y, rv.y);
      d.z = addbf2(d.z, rv.z); d.w = addbf2(d.w, rv.w);
    }
    *(uint4*)(ddc + (((size_t)(n * 96 + yi)) * 96 + 24 * xg + p) * CH + oct * 8) = d;
  }
}

// ---- depthwise conv on compact dd ----------------------------------------
__global__ __launch_bounds__(256)
void dwconv_c(const u16* __restrict__ ddc, const float* __restrict__ w,
              const float* __restrict__ b, float* __restrict__ out)
{
  int idx = blockIdx.x * 256 + threadIdx.x;
  if (idx >= 8 * 32 * 32 * CH) return;
  int c = idx % CH;
  int p = idx / CH;
  int ox = p & 31;
  int oy = (p >> 5) & 31;
  int n = p >> 10;
  float acc = b[c];
  const u16* base = ddc + (((size_t)(n * 96 + oy * 3)) * 96 + ox * 3) * CH + c;
  #pragma unroll
  for (int dyi = 0; dyi < 3; ++dyi)
    #pragma unroll
    for (int dxi = 0; dxi < 3; ++dxi)
      acc += w[c * 9 + dyi * 3 + dxi] * b2f(base[((size_t)dyi * 96 + dxi) * CH]);
  out[((size_t)(n * CH + c) << 10) + oy * 32 + ox] = acc;
}

// ---- per-8x8-block iDCT on planar f32 32x32 ------------------------------
__global__ __launch_bounds__(256)
void idct8_k(const float* __restrict__ in, float* __restrict__ out)
{
  __shared__ float ctab[8];
  if (threadIdx.x < 8) {
    const float c_[8] = {1.f, 0.70710678118654752f, 0.f, -0.70710678118654752f,
                         -1.f, -0.70710678118654752f, 0.f, 0.70710678118654752f};
    ctab[threadIdx.x] = c_[threadIdx.x];
  }
  __syncthreads();
  int idx = blockIdx.x * 256 + threadIdx.x;
  if (idx >= 8 * CH * 32 * 32) return;
  int ox = idx & 31, oy = (idx >> 5) & 31, bc = idx >> 10;
  int k = oy & 7, lq = ox & 7;
  const float* ip = in + bc * 1024 + (oy & ~7) * 32 + (ox & ~7);
  float acc = 0.f;
  #pragma unroll
  for (int mm = 0; mm < 8; ++mm) {
    float rk = ctab[(k * mm) & 7];
    float s = 0.f;
    #pragma unroll
    for (int nn = 0; nn < 8; ++nn)
      s += ctab[(lq * nn) & 7] * ip[mm * 32 + nn];
    acc += rk * s;
  }
  out[idx] = acc * 0.125f;
}

// ---- MFMA 1x1 conv + sigmoid + bilinear(32->256) multiply; cl bf16 -------
__global__ __launch_bounds__(256)
void wgtmul_k(const u16* __restrict__ t1cl, const u16* __restrict__ wt3,
              const float* __restrict__ b3, const float* __restrict__ dct,
              u16* __restrict__ outcl)
{
  __shared__ float s_yw[40 * 33];
  __shared__ u16 s_out[4 * 3072];

  const int q8 = (int)gridDim.x >> 3;
  const int bid = ((int)blockIdx.x & 7) * q8 + ((int)blockIdx.x >> 3);
  const int n = bid >> 8;
  const int y = bid & 255;
  const int tid = threadIdx.x;

  float sy = (y + 0.5f) * 0.125f - 0.5f;
  float yq = floorf(sy);
  float fy = sy - yq;
  int y0c = max((int)yq, 0), y1c = min((int)yq + 1, 31);

  for (int i = tid; i < 1280; i += 256) {
    int oc = i >> 5, c = i & 31;
    const float* sp = dct + ((size_t)(n * CH + oc) << 10);
    s_yw[oc * 33 + c] = (1.f - fy) * sp[y0c * 32 + c] + fy * sp[y1c * 32 + c];
  }
  __syncthreads();

  const int w = tid >> 6;
  const int l = tid & 63;
  const int g = l >> 4;
  const int m = l & 15;
  const int xb = w << 6;

  const u16* tp = t1cl + (size_t)n * IMG_CL + ((size_t)(y + 1) * IW + 1) * CH;

  f32x4 acc[4][3];
  #pragma unroll
  for (int xt = 0; xt < 4; ++xt)
    #pragma unroll
    for (int t = 0; t < 3; ++t) acc[xt][t] = (f32x4){0.f, 0.f, 0.f, 0.f};

  #pragma unroll
  for (int xt = 0; xt < 4; ++xt) {
    const u16* ap = tp + (size_t)(xb + xt * 16 + m) * CH;
    bf16x8 a0 = *(const bf16x8*)(ap + 8 * g);
    bf16x8 a1 = *(const bf16x8*)(ap + 32 + 8 * g);
    #pragma unroll
    for (int t = 0; t < 3; ++t) {
      bf16x8 b0 = *(const bf16x8*)(wt3 + (m + 16 * t) * 384 + 8 * g);
      bf16x8 b1 = *(const bf16x8*)(wt3 + (m + 16 * t) * 384 + 32 + 8 * g);
      acc[xt][t] = __builtin_amdgcn_mfma_f32_16x16x32_bf16(b0, a0, acc[xt][t], 0, 0, 0);
      acc[xt][t] = __builtin_amdgcn_mfma_f32_16x16x32_bf16(b1, a1, acc[xt][t], 0, 0, 0);
    }
  }

  u16* so = s_out + w * 3072;
  float4 bv[3];
  bv[0] = *(const float4*)(b3 + 4 * g);
  bv[1] = *(const float4*)(b3 + 16 + 4 * g);
  bv[2] = (g < 2) ? *(const float4*)(b3 + 32 + 4 * g) : make_float4(0.f, 0.f, 0.f, 0.f);
  #pragma unroll
  for (int t = 0; t < 3; ++t) {
    if (t == 2 && g >= 2) continue;
    #pragma unroll
    for (int xt = 0; xt < 4; ++xt) {
      const int pxl = xt * 16 + m;
      const int px = xb + pxl;
      float sx = (px + 0.5f) * 0.125f - 0.5f;
      float xq = floorf(sx);
      float fx = sx - xq;
      int x0c = max((int)xq, 0), x1c = min((int)xq + 1, 31);
      u16 r4[4];
      #pragma unroll
      for (int i = 0; i < 4; ++i) {
        int oc = 16 * t + 4 * g + i;
        float wgt = 1.f / (1.f + __expf(-(acc[xt][t][i] + ((const float*)&bv[t])[i])));
        float bil = (1.f - fx) * s_yw[oc * 33 + x0c] + fx * s_yw[oc * 33 + x1c];
        r4[i] = f2b(wgt * bil);
      }
      uint2 pk;
      pk.x = (u32)r4[0] | ((u32)r4[1] << 16);
      pk.y = (u32)r4[2] | ((u32)r4[3] << 16);
      int byt = pxl * 80 + (16 * t + 4 * g) * 2;
      byt ^= ((pxl >> 3) & 7) << 4;
      *(uint2*)((char*)so + byt) = pk;
    }
  }
  const size_t rowu = (size_t)n * IMG_CL + ((size_t)(y + 1) * IW + (xb + 1)) * CH;
  #pragma unroll
  for (int q = 0; q < 5; ++q) {
    int byt = l * 80 + q * 16;
    byt ^= ((l >> 3) & 7) << 4;
    uint4 d = *(const uint4*)((const char*)so + byt);
    *(uint4*)(outcl + rowu + (size_t)l * 40 + q * 8) = d;
  }
}

extern "C" void kernel_launch(void* const* d_in, const int* in_sizes, int n_in,
                              void* d_out, int out_size, void* d_ws, size_t ws_size,
                              hipStream_t stream)
{
  const float* x       = (const float*)d_in[0];
  const float* conv_w  = (const float*)d_in[1];
  const float* conv_b  = (const float*)d_in[2];
  const float* ddct_w  = (const float*)d_in[3];
  const float* ddct_b  = (const float*)d_in[4];
  const float* dctc_w  = (const float*)d_in[5];
  const float* dctc_b  = (const float*)d_in[6];
  const float* w1_w    = (const float*)d_in[7];
  const float* w1_b    = (const float*)d_in[8];
  const float* w3_w    = (const float*)d_in[9];
  const float* w3_b    = (const float*)d_in[10];
  const float* after_w = (const float*)d_in[11];
  const float* after_b = (const float*)d_in[12];

  char* ws = (char*)d_ws;
  const size_t CLB = (size_t)8 * IMG_CL * 2;          // 42,600,960 B
  // small buffers FIRST so cl_a's oy==0 staging underflow stays in-bounds
  float* small0 = (float*)ws;                         // 1,310,720
  float* small1 = (float*)(ws + 1310720);             // 1,310,720
  u16*   wt4    = (u16*)(ws + 2621440);               // 36,864 (w3 rm)
  u16*   wcma   = (u16*)(ws + 2658304);               // 30,720 (after cm)
  u16*   wsc    = (u16*)(ws + 2689024);               // 88,320 (3 compressed)
  u16*   ddc    = (u16*)(ws + 2777344);               // 5,898,240 compact dd
  u16*   cl_a   = (u16*)(ws + 8675584);               // dct_feat, later prod
  u16*   cl_c   = (u16*)(ws + 8675584 + CLB);         // t1

  // 0. weight transforms + cl_a ring zeroing
  prep_w_k<<<305, 256, 0, stream>>>(conv_w, ddct_w, w1_w, after_w, w3_w,
                                    wt4, wcma, wsc);
  ringz_k<<<8 * IW, 256, 0, stream>>>(cl_a);
  // 1+5. dct_feat = gelu(conv1(x)) -> cl_a ; t1 = relu(conv5(x)) -> cl_c
  //      (x read + bf16 conversion fused into staging; prep_x deleted)
  fconv2p_k<<<2048, 256, 0, stream>>>(x, wsc, wsc + WSC_SET,
                                      conv_b, w1_b, cl_a, cl_c);
  // 2. SPARSE dd at dwconv sample points           -> ddc (compact)
  sconv_k<<<1024, 256, 0, stream>>>(cl_a, wsc + 2 * WSC_SET, ddct_b, ddc);
  // 3. depthwise strided conv on compact dd        -> small0
  dwconv_c<<<1280, 256, 0, stream>>>(ddc, dctc_w, dctc_b, small0);
  // 4. per-block 8x8 iDCT                          -> small1
  idct8_k<<<1280, 256, 0, stream>>>(small0, small1);
  // 6. prod = sigmoid(1x1(t1)) * bilinear(idct)    -> cl_a (dct_feat dead)
  wgtmul_k<<<2048, 256, 0, stream>>>(cl_c, wt4, w3_b, small1, cl_a);
  // 7. out = conv(prod, after)                     -> d_out fp32 planar
  convl_k<0, true><<<2048, 256, 0, stream>>>(cl_a, wcma, after_b, (void*)d_out);
}

// Round 16
// 169.260 us; speedup vs baseline: 2.3187x; 1.0371x over previous
//
#include <hip/hip_runtime.h>

typedef unsigned short u16;
typedef unsigned int u32;
typedef __attribute__((ext_vector_type(8))) short bf16x8;
typedef __attribute__((ext_vector_type(4))) float f32x4;

#define CH 40
#define IW 258                   // ring-padded width (256 + 2)
#define IWCH (IW * CH)           // 10320
#define IMG_CL (IW * IW * CH)    // u16 elements per image, channel-last padded
#define WT_SET (48 * 384)        // u16: w3 row-major set (wgtmul)
#define WCM_SET (48 * 40 * 8)    // u16: after_w chunk-major set (conv7) = 15360
#define WSC_SET (46 * 40 * 8)    // u16 compressed set: 45 real + 1 zero = 14720

#define GLDS16(g, l) __builtin_amdgcn_global_load_lds( \
    (const __attribute__((address_space(1))) void*)(g), \
    (__attribute__((address_space(3))) void*)(l), 16, 0, 0)

__device__ __forceinline__ float b2f(u16 u) {
  union { u32 i; float f; } v; v.i = ((u32)u) << 16; return v.f;
}
// HW packed f32->bf16 (RNE), replaces 2x manual f2b (~8 VALU ops -> 1)
__device__ __forceinline__ u32 pkbf(float lo, float hi) {
  u32 r;
  asm("v_cvt_pk_bf16_f32 %0, %1, %2" : "=v"(r) : "v"(lo), "v"(hi));
  return r;
}
__device__ __forceinline__ u16 f2b(float f) {
  union { float f; u32 i; } v; v.f = f;
  u32 r = v.i + 0x7fffu + ((v.i >> 16) & 1u);
  return (u16)(r >> 16);
}
__device__ __forceinline__ u32 addbf2(u32 a, u32 b) {
  union { u32 i; float f; } lo_a, lo_b, hi_a, hi_b;
  lo_a.i = a << 16; lo_b.i = b << 16;
  hi_a.i = a & 0xffff0000u; hi_b.i = b & 0xffff0000u;
  return pkbf(lo_a.f + lo_b.f, hi_a.f + hi_b.f);
}
// tanh-approx gelu (validated r10: |err| ~3e-4, absmax unchanged)
__device__ __forceinline__ float actf(float t, int ACT) {
  if (ACT == 1) {
    float u2 = t * (1.5957691216057308f + 0.07135481627000862f * t * t);
    float e = __expf(u2);
    return t - t / (e + 1.f);
  }
  if (ACT == 2) return fmaxf(t, 0.f);
  return t;
}

// ---- weights: w3 rm + after cm + compressed 46-chunk x3 ------------------
__global__ __launch_bounds__(256)
void prep_w_k(const float* __restrict__ w0, const float* __restrict__ w1,
              const float* __restrict__ w2, const float* __restrict__ w3,
              const float* __restrict__ w4, u16* __restrict__ wt4,
              u16* __restrict__ wcma, u16* __restrict__ wsc)
{
  int i = blockIdx.x * 256 + threadIdx.x;   // 18432 + 15360 + 44160 = 77952
  if (i >= WT_SET + WCM_SET + 3 * WSC_SET) return;
  if (i < WT_SET) {                          // w3 1x1 row-major [48][384]
    int k = i % 384;
    int oc = i / 384;
    u16 v = 0;
    if (oc < 40 && k < 40) v = f2b(w4[oc * 40 + k]);
    wt4[i] = v;
  } else if (i < WT_SET + WCM_SET) {         // after_w chunk-major [48][40][8]
    int j = i - WT_SET;
    int c = j / 320;
    int rem = j - c * 320;
    int oc = rem >> 3;
    int e = rem & 7;
    int k = c * 8 + e;
    int dy = k >> 7;
    int r = k & 127;
    u16 v = 0;
    if (r < 120) {
      int dx = r / 40;
      int ic = r - dx * 40;
      v = f2b(w3[((oc * 40 + ic) * 3 + dy) * 3 + dx]);
    }
    wcma[j] = v;
  } else {
    int j2 = i - WT_SET - WCM_SET;           // [0, 3*14720)
    int set3 = j2 / WSC_SET;                 // 0 conv_w, 1 w1_w, 2 ddct_w
    int r3 = j2 - set3 * WSC_SET;
    int c2 = r3 / 320;
    int rem = r3 - c2 * 320;
    int oc = rem >> 3;
    int e = rem & 7;
    u16 v = 0;
    if (c2 < 45) {
      int dy = c2 / 15, cc = c2 % 15;
      int dx = cc / 5, icq = cc % 5;
      int ic = icq * 8 + e;
      const float* w = (set3 == 0) ? w0 : (set3 == 1) ? w2 : w1;
      v = f2b(w[((oc * 40 + ic) * 3 + dy) * 3 + dx]);
    }
    wsc[j2] = v;
  }
}

// ---- zero the halo rings of cl_a (needed by sconv staging + conv7 halo) --
__global__ __launch_bounds__(256)
void ringz_k(u16* __restrict__ cla)
{
  const int n = blockIdx.x / IW;
  const int yr = blockIdx.x % IW;
  const int t = threadIdx.x;
  const size_t base = (size_t)n * IMG_CL + (size_t)yr * IWCH;
  const uint4 z = {0u, 0u, 0u, 0u};
  if (yr == 0 || yr == IW - 1) {
    for (int i = t; i < IWCH / 8; i += 256) ((uint4*)(cla + base))[i] = z;
    return;
  }
  if (t < 5) {
    ((uint4*)(cla + base))[t] = z;
  } else if (t < 10) {
    ((uint4*)(cla + base + (size_t)(IW - 1) * CH))[t - 5] = z;
  }
}

// ---- fused conv1+conv5: in-kernel x->bf16 conversion, two weight passes --
__global__ __launch_bounds__(256, 2)
void fconv2p_k(const float* __restrict__ xg, const u16* __restrict__ wscA,
               const u16* __restrict__ wscB, const float* __restrict__ biasA,
               const float* __restrict__ biasB, u16* __restrict__ outA,
               u16* __restrict__ outB)
{
  __shared__ __align__(16) u16 s_mem[30560];   // x 15840 + w 14720 = 61120 B
  u16* s_in = s_mem;
  u16* s_w  = s_mem + 15840;                   // weight region; reused as restage

  const int tid = threadIdx.x;
  const int bid = ((int)blockIdx.x & 7) * 256 + ((int)blockIdx.x >> 3);
  const int n = bid >> 8;
  const int tb = bid & 255;
  const int y0 = (tb >> 2) << 2;
  const int x0 = (tb & 3) << 6;

  // weights wA via async LDS copy (overlaps the conversion loads below)
  #pragma unroll
  for (int k = 0; k < 8; ++k) {
    int i = tid + (k << 8);
    if (i < 1840) GLDS16(wscA + i * 8, s_w + i * 8);
  }
  // stage x tile (6 rows x 66 px x 40 ic) from planar f32, packed-converting
  const float* xsrc = xg + (size_t)n * CH * 65536;
  for (int slot = tid; slot < 396; slot += 256) {
    int r = slot / 66, p = slot - r * 66;
    int gy = y0 + r - 1, gx = x0 + p - 1;
    __attribute__((aligned(16))) u32 buf[20];
    if ((unsigned)gy < 256u && (unsigned)gx < 256u) {
      const float* xp = xsrc + (size_t)gy * 256 + gx;
      #pragma unroll
      for (int icp = 0; icp < 20; ++icp)
        buf[icp] = pkbf(xp[(size_t)(2 * icp) * 65536],
                        xp[(size_t)(2 * icp + 1) * 65536]);
    } else {
      #pragma unroll
      for (int icp = 0; icp < 20; ++icp) buf[icp] = 0u;
    }
    u16* dst = s_in + slot * 40;
    #pragma unroll
    for (int q = 0; q < 5; ++q) ((uint4*)dst)[q] = ((const uint4*)buf)[q];
  }
  __syncthreads();

  const int w = tid >> 6;
  const int l = tid & 63;
  const int g = l >> 4;
  const int m = l & 15;

  f32x4 accA[4][3], accB[4][3];
  #pragma unroll
  for (int xt = 0; xt < 4; ++xt)
    #pragma unroll
    for (int tt = 0; tt < 3; ++tt) {
      accA[xt][tt] = (f32x4){0.f, 0.f, 0.f, 0.f};
      accB[xt][tt] = (f32x4){0.f, 0.f, 0.f, 0.f};
    }

  // ---- K-loop pass A -----------------------------------------------------
  #pragma unroll
  for (int s = 0; s < 12; ++s) {
    const int dy = s >> 2;
    const int c = ((s & 3) << 2) + g;
    int dx, icb;
    if (c >= 15)      { dx = 0; icb = 0; }
    else if (c >= 10) { dx = 2; icb = (c - 10) * 8; }
    else if (c >= 5)  { dx = 1; icb = (c - 5) * 8; }
    else              { dx = 0; icb = c * 8; }
    const int abase = (w + dy) * (66 * CH) + (m + dx) * CH + icb;
    bf16x8 a0 = *(const bf16x8*)(s_in + abase);
    bf16x8 a1 = *(const bf16x8*)(s_in + abase + 16 * CH);
    bf16x8 a2 = *(const bf16x8*)(s_in + abase + 32 * CH);
    bf16x8 a3 = *(const bf16x8*)(s_in + abase + 48 * CH);
    const u16* wrow = s_w + ((c >= 15) ? 45 * 320 : (dy * 15 + c) * 320);
    bf16x8 b0 = *(const bf16x8*)(wrow + m * 8);
    bf16x8 b1 = *(const bf16x8*)(wrow + (m + 16) * 8);
    bf16x8 b2 = *(const bf16x8*)(wrow + (m >= 8 ? 312 : (m + 32) * 8));
    accA[0][0] = __builtin_amdgcn_mfma_f32_16x16x32_bf16(b0, a0, accA[0][0], 0, 0, 0);
    accA[1][0] = __builtin_amdgcn_mfma_f32_16x16x32_bf16(b0, a1, accA[1][0], 0, 0, 0);
    accA[2][0] = __builtin_amdgcn_mfma_f32_16x16x32_bf16(b0, a2, accA[2][0], 0, 0, 0);
    accA[3][0] = __builtin_amdgcn_mfma_f32_16x16x32_bf16(b0, a3, accA[3][0], 0, 0, 0);
    accA[0][1] = __builtin_amdgcn_mfma_f32_16x16x32_bf16(b1, a0, accA[0][1], 0, 0, 0);
    accA[1][1] = __builtin_amdgcn_mfma_f32_16x16x32_bf16(b1, a1, accA[1][1], 0, 0, 0);
    accA[2][1] = __builtin_amdgcn_mfma_f32_16x16x32_bf16(b1, a2, accA[2][1], 0, 0, 0);
    accA[3][1] = __builtin_amdgcn_mfma_f32_16x16x32_bf16(b1, a3, accA[3][1], 0, 0, 0);
    accA[0][2] = __builtin_amdgcn_mfma_f32_16x16x32_bf16(b2, a0, accA[0][2], 0, 0, 0);
    accA[1][2] = __builtin_amdgcn_mfma_f32_16x16x32_bf16(b2, a1, accA[1][2], 0, 0, 0);
    accA[2][2] = __builtin_amdgcn_mfma_f32_16x16x32_bf16(b2, a2, accA[2][2], 0, 0, 0);
    accA[3][2] = __builtin_amdgcn_mfma_f32_16x16x32_bf16(b2, a3, accA[3][2], 0, 0, 0);
  }

  __syncthreads();                             // all waves done reading wA
  #pragma unroll
  for (int k = 0; k < 8; ++k) {                // wB into same region
    int i = tid + (k << 8);
    if (i < 1840) GLDS16(wscB + i * 8, s_w + i * 8);
  }
  __syncthreads();                             // wB ready (vmcnt drained)

  // ---- K-loop pass B -----------------------------------------------------
  #pragma unroll
  for (int s = 0; s < 12; ++s) {
    const int dy = s >> 2;
    const int c = ((s & 3) << 2) + g;
    int dx, icb;
    if (c >= 15)      { dx = 0; icb = 0; }
    else if (c >= 10) { dx = 2; icb = (c - 10) * 8; }
    else if (c >= 5)  { dx = 1; icb = (c - 5) * 8; }
    else              { dx = 0; icb = c * 8; }
    const int abase = (w + dy) * (66 * CH) + (m + dx) * CH + icb;
    bf16x8 a0 = *(const bf16x8*)(s_in + abase);
    bf16x8 a1 = *(const bf16x8*)(s_in + abase + 16 * CH);
    bf16x8 a2 = *(const bf16x8*)(s_in + abase + 32 * CH);
    bf16x8 a3 = *(const bf16x8*)(s_in + abase + 48 * CH);
    const u16* wrow = s_w + ((c >= 15) ? 45 * 320 : (dy * 15 + c) * 320);
    bf16x8 b0 = *(const bf16x8*)(wrow + m * 8);
    bf16x8 b1 = *(const bf16x8*)(wrow + (m + 16) * 8);
    bf16x8 b2 = *(const bf16x8*)(wrow + (m >= 8 ? 312 : (m + 32) * 8));
    accB[0][0] = __builtin_amdgcn_mfma_f32_16x16x32_bf16(b0, a0, accB[0][0], 0, 0, 0);
    accB[1][0] = __builtin_amdgcn_mfma_f32_16x16x32_bf16(b0, a1, accB[1][0], 0, 0, 0);
    accB[2][0] = __builtin_amdgcn_mfma_f32_16x16x32_bf16(b0, a2, accB[2][0], 0, 0, 0);
    accB[3][0] = __builtin_amdgcn_mfma_f32_16x16x32_bf16(b0, a3, accB[3][0], 0, 0, 0);
    accB[0][1] = __builtin_amdgcn_mfma_f32_16x16x32_bf16(b1, a0, accB[0][1], 0, 0, 0);
    accB[1][1] = __builtin_amdgcn_mfma_f32_16x16x32_bf16(b1, a1, accB[1][1], 0, 0, 0);
    accB[2][1] = __builtin_amdgcn_mfma_f32_16x16x32_bf16(b1, a2, accB[2][1], 0, 0, 0);
    accB[3][1] = __builtin_amdgcn_mfma_f32_16x16x32_bf16(b1, a3, accB[3][1], 0, 0, 0);
    accB[0][2] = __builtin_amdgcn_mfma_f32_16x16x32_bf16(b2, a0, accB[0][2], 0, 0, 0);
    accB[1][2] = __builtin_amdgcn_mfma_f32_16x16x32_bf16(b2, a1, accB[1][2], 0, 0, 0);
    accB[2][2] = __builtin_amdgcn_mfma_f32_16x16x32_bf16(b2, a2, accB[2][2], 0, 0, 0);
    accB[3][2] = __builtin_amdgcn_mfma_f32_16x16x32_bf16(b2, a3, accB[3][2], 0, 0, 0);
  }

  const int y = y0 + w;
  const size_t rowu = (size_t)n * IMG_CL + ((size_t)(y + 1) * IW + (x0 + 1)) * CH;
  __syncthreads();                             // all waves done reading s_w/s_in

  char* so = (char*)s_w + w * 5120;
  float4 bvA[3], bvB[3];
  bvA[0] = *(const float4*)(biasA + 4 * g);
  bvA[1] = *(const float4*)(biasA + 16 + 4 * g);
  bvA[2] = (g < 2) ? *(const float4*)(biasA + 32 + 4 * g) : make_float4(0.f, 0.f, 0.f, 0.f);
  bvB[0] = *(const float4*)(biasB + 4 * g);
  bvB[1] = *(const float4*)(biasB + 16 + 4 * g);
  bvB[2] = (g < 2) ? *(const float4*)(biasB + 32 + 4 * g) : make_float4(0.f, 0.f, 0.f, 0.f);

  #pragma unroll
  for (int tt = 0; tt < 3; ++tt) {
    if (tt == 2 && g >= 2) continue;
    #pragma unroll
    for (int xt = 0; xt < 4; ++xt) {
      const int pxl = xt * 16 + m;
      float v[4];
      #pragma unroll
      for (int i = 0; i < 4; ++i)
        v[i] = actf(accA[xt][tt][i] + ((const float*)&bvA[tt])[i], 1);
      uint2 pk;
      pk.x = pkbf(v[0], v[1]);
      pk.y = pkbf(v[2], v[3]);
      int byt = pxl * 80 + (16 * tt + 4 * g) * 2;
      byt ^= ((pxl >> 3) & 7) << 4;
      *(uint2*)(so + byt) = pk;
    }
  }
  #pragma unroll
  for (int q = 0; q < 5; ++q) {
    int byt = l * 80 + q * 16;
    byt ^= ((l >> 3) & 7) << 4;
    uint4 d = *(const uint4*)(so + byt);
    *(uint4*)(outA + rowu + (size_t)l * 40 + q * 8) = d;
  }

  #pragma unroll
  for (int tt = 0; tt < 3; ++tt) {
    if (tt == 2 && g >= 2) continue;
    #pragma unroll
    for (int xt = 0; xt < 4; ++xt) {
      const int pxl = xt * 16 + m;
      float v[4];
      #pragma unroll
      for (int i = 0; i < 4; ++i)
        v[i] = actf(accB[xt][tt][i] + ((const float*)&bvB[tt])[i], 2);
      uint2 pk;
      pk.x = pkbf(v[0], v[1]);
      pk.y = pkbf(v[2], v[3]);
      int byt = pxl * 80 + (16 * tt + 4 * g) * 2;
      byt ^= ((pxl >> 3) & 7) << 4;
      *(uint2*)(so + byt) = pk;
    }
  }
  #pragma unroll
  for (int q = 0; q < 5; ++q) {
    int byt = l * 80 + q * 16;
    byt ^= ((l >> 3) & 7) << 4;
    uint4 d = *(const uint4*)(so + byt);
    *(uint4*)(outB + rowu + (size_t)l * 40 + q * 8) = d;
  }
}

// ---- all-LDS-operand MFMA conv 3x3 (r12-verified; conv7 planar path) -----
template<int ACT, bool PLANAR>
__global__ __launch_bounds__(256, 2)
void convl_k(const u16* __restrict__ incl, const u16* __restrict__ wcm,
             const float* __restrict__ bias, void* __restrict__ outp)
{
  __shared__ __align__(16) u16 s_mem[31200];   // input 15840 + weights 15360
  u16* s_in = s_mem;
  u16* s_w  = s_mem + 15840;

  const int tid = threadIdx.x;
  const int bid = ((int)blockIdx.x & 7) * 256 + ((int)blockIdx.x >> 3);
  const int n = bid >> 8;
  const int tb = bid & 255;
  const int y0 = (tb >> 2) << 2;
  const int x0 = (tb & 3) << 6;

  const u16* src = incl + (size_t)n * IMG_CL + ((size_t)y0 * IW + x0) * CH;
  #pragma unroll
  for (int k = 0; k < 8; ++k) {
    int i = tid + (k << 8);
    if (i < 1980) {
      int r = i / 330, o = i - r * 330;
      GLDS16(src + (size_t)r * IWCH + o * 8, s_in + i * 8);
    }
  }
  #pragma unroll
  for (int k = 0; k < 8; ++k) {
    int i = tid + (k << 8);
    if (i < 1920) GLDS16(wcm + i * 8, s_w + i * 8);
  }
  __syncthreads();

  const int w = tid >> 6;
  const int l = tid & 63;
  const int g = l >> 4;
  const int m = l & 15;

  f32x4 acc[4][3];
  #pragma unroll
  for (int xt = 0; xt < 4; ++xt)
    #pragma unroll
    for (int tt = 0; tt < 3; ++tt) acc[xt][tt] = (f32x4){0.f, 0.f, 0.f, 0.f};

  #pragma unroll
  for (int s = 0; s < 12; ++s) {
    const int dy = s >> 2;
    const int c = ((s & 3) << 2) + g;
    int dx, icb;
    if (c >= 15)      { dx = 0; icb = 0; }
    else if (c >= 10) { dx = 2; icb = (c - 10) * 8; }
    else if (c >= 5)  { dx = 1; icb = (c - 5) * 8; }
    else              { dx = 0; icb = c * 8; }
    const int abase = (w + dy) * (66 * CH) + (m + dx) * CH + icb;
    bf16x8 a0 = *(const bf16x8*)(s_in + abase);
    bf16x8 a1 = *(const bf16x8*)(s_in + abase + 16 * CH);
    bf16x8 a2 = *(const bf16x8*)(s_in + abase + 32 * CH);
    bf16x8 a3 = *(const bf16x8*)(s_in + abase + 48 * CH);

    const int ch = (s << 2) + g;
    const u16* wrow = s_w + ch * 320;
    bf16x8 b0 = *(const bf16x8*)(wrow + m * 8);
    bf16x8 b1 = *(const bf16x8*)(wrow + (m + 16) * 8);
    bf16x8 b2 = *(const bf16x8*)(wrow + (m >= 8 ? 312 : (m + 32) * 8));

    #pragma unroll
    for (int xt = 0; xt < 4; ++xt) {
      bf16x8 aX = (xt == 0) ? a0 : (xt == 1) ? a1 : (xt == 2) ? a2 : a3;
      if (PLANAR) {
        acc[xt][0] = __builtin_amdgcn_mfma_f32_16x16x32_bf16(aX, b0, acc[xt][0], 0, 0, 0);
        acc[xt][1] = __builtin_amdgcn_mfma_f32_16x16x32_bf16(aX, b1, acc[xt][1], 0, 0, 0);
        acc[xt][2] = __builtin_amdgcn_mfma_f32_16x16x32_bf16(aX, b2, acc[xt][2], 0, 0, 0);
      } else {
        acc[xt][0] = __builtin_amdgcn_mfma_f32_16x16x32_bf16(b0, aX, acc[xt][0], 0, 0, 0);
        acc[xt][1] = __builtin_amdgcn_mfma_f32_16x16x32_bf16(b1, aX, acc[xt][1], 0, 0, 0);
        acc[xt][2] = __builtin_amdgcn_mfma_f32_16x16x32_bf16(b2, aX, acc[xt][2], 0, 0, 0);
      }
    }
  }

  const int y = y0 + w;

  if (PLANAR) {
    const float bv0 = bias[m];
    const float bv1 = bias[m + 16];
    const float bv2 = (m < 8) ? bias[m + 32] : 0.f;
    #pragma unroll
    for (int tt = 0; tt < 3; ++tt) {
      const int oc = m + 16 * tt;
      if (tt == 2 && m >= 8) continue;
      const float bv = (tt == 0) ? bv0 : (tt == 1) ? bv1 : bv2;
      #pragma unroll
      for (int xt = 0; xt < 4; ++xt) {
        const int xb = x0 + xt * 16 + 4 * g;
        float v[4];
        #pragma unroll
        for (int i = 0; i < 4; ++i) v[i] = actf(acc[xt][tt][i] + bv, ACT);
        *(float4*)((float*)outp + (((size_t)(n * CH + oc)) << 16) + ((size_t)y << 8) + xb)
            = make_float4(v[0], v[1], v[2], v[3]);
      }
    }
  } else {
    __syncthreads();
    char* so = (char*)s_mem + w * 5120;
    float4 bv[3];
    bv[0] = *(const float4*)(bias + 4 * g);
    bv[1] = *(const float4*)(bias + 16 + 4 * g);
    bv[2] = (g < 2) ? *(const float4*)(bias + 32 + 4 * g)
                    : make_float4(0.f, 0.f, 0.f, 0.f);
    #pragma unroll
    for (int tt = 0; tt < 3; ++tt) {
      if (tt == 2 && g >= 2) continue;
      #pragma unroll
      for (int xt = 0; xt < 4; ++xt) {
        const int pxl = xt * 16 + m;
        float v[4];
        #pragma unroll
        for (int i = 0; i < 4; ++i)
          v[i] = actf(acc[xt][tt][i] + ((const float*)&bv[tt])[i], ACT);
        uint2 pk;
        pk.x = pkbf(v[0], v[1]);
        pk.y = pkbf(v[2], v[3]);
        int byt = pxl * 80 + (16 * tt + 4 * g) * 2;
        byt ^= ((pxl >> 3) & 7) << 4;
        *(uint2*)(so + byt) = pk;
      }
    }
    const size_t rowu = (size_t)n * IMG_CL + ((size_t)(y + 1) * IW + (x0 + 1)) * CH;
    #pragma unroll
    for (int q = 0; q < 5; ++q) {
      int byt = l * 80 + q * 16;
      byt ^= ((l >> 3) & 7) << 4;
      uint4 d = *(const uint4*)(so + byt);
      *(uint4*)((u16*)outp + rowu + (size_t)l * 40 + q * 8) = d;
    }
  }
}

// ---- SPARSE conv2 (r13-verified): dd at dwconv sample points only --------
__global__ __launch_bounds__(256, 2)
void sconv_k(const u16* __restrict__ cla, const u16* __restrict__ wsc,
             const float* __restrict__ bias, u16* __restrict__ ddc)
{
  __shared__ __align__(16) u16 s_mem[32640];   // s_in 17920 + s_w 14720
  u16* s_in = s_mem;
  u16* s_w  = s_mem + 17920;

  const int tid = threadIdx.x;
  const int bid = ((int)blockIdx.x & 7) * 128 + ((int)blockIdx.x >> 3); // 1024
  const int n = bid >> 7;
  const int oy = (bid >> 2) & 31;
  const int xg = bid & 3;

  const u16* src = cla + (ptrdiff_t)((size_t)n * IMG_CL)
                       + (ptrdiff_t)(8 * oy - 2) * IWCH + (64 * xg - 2) * CH;
  #pragma unroll
  for (int k = 0; k < 9; ++k) {
    int i = tid + (k << 8);
    if (i < 2240) {
      int r = i / 320, o = i - r * 320;
      GLDS16(src + (ptrdiff_t)r * IWCH + o * 8, s_in + i * 8);
    }
  }
  #pragma unroll
  for (int k = 0; k < 8; ++k) {
    int i = tid + (k << 8);
    if (i < 1840) GLDS16(wsc + i * 8, s_w + i * 8);
  }
  __syncthreads();

  const int w = tid >> 6;
  const int l = tid & 63;
  const int g = l >> 4;
  const int m = l & 15;

  const int p0 = m;
  const int p1 = (m < 8) ? 16 + m : 23;
  const int rb0 = 8 * (p0 / 3) + 2 * (p0 % 3);
  const int rb1 = 8 * (p1 / 3) + 2 * (p1 % 3);

  f32x4 acc[2][3];
  #pragma unroll
  for (int mt = 0; mt < 2; ++mt)
    #pragma unroll
    for (int tt = 0; tt < 3; ++tt) acc[mt][tt] = (f32x4){0.f, 0.f, 0.f, 0.f};

  if (w < 3) {
    #pragma unroll
    for (int s = 0; s < 12; ++s) {
      const int dy = s >> 2;
      const int c = ((s & 3) << 2) + g;
      int dx, icb;
      if (c >= 15)      { dx = 0; icb = 0; }
      else if (c >= 10) { dx = 2; icb = (c - 10) * 8; }
      else if (c >= 5)  { dx = 1; icb = (c - 5) * 8; }
      else              { dx = 0; icb = c * 8; }
      const int rowb = (2 * w + dy) * 2560;
      bf16x8 a0 = *(const bf16x8*)(s_in + rowb + (rb0 + dx) * CH + icb);
      bf16x8 a1 = *(const bf16x8*)(s_in + rowb + (rb1 + dx) * CH + icb);

      const u16* wrow = s_w + ((c == 15) ? 45 * 320 : (dy * 15 + c) * 320);
      bf16x8 b0 = *(const bf16x8*)(wrow + m * 8);
      bf16x8 b1 = *(const bf16x8*)(wrow + (m + 16) * 8);
      bf16x8 b2 = *(const bf16x8*)(wrow + (m >= 8 ? 312 : (m + 32) * 8));

      acc[0][0] = __builtin_amdgcn_mfma_f32_16x16x32_bf16(b0, a0, acc[0][0], 0, 0, 0);
      acc[1][0] = __builtin_amdgcn_mfma_f32_16x16x32_bf16(b0, a1, acc[1][0], 0, 0, 0);
      acc[0][1] = __builtin_amdgcn_mfma_f32_16x16x32_bf16(b1, a0, acc[0][1], 0, 0, 0);
      acc[1][1] = __builtin_amdgcn_mfma_f32_16x16x32_bf16(b1, a1, acc[1][1], 0, 0, 0);
      acc[0][2] = __builtin_amdgcn_mfma_f32_16x16x32_bf16(b2, a0, acc[0][2], 0, 0, 0);
      acc[1][2] = __builtin_amdgcn_mfma_f32_16x16x32_bf16(b2, a1, acc[1][2], 0, 0, 0);
    }
  }

  __syncthreads();
  if (w == 3) return;

  char* so = (char*)s_w + w * 2048;
  float4 bv[3];
  bv[0] = *(const float4*)(bias + 4 * g);
  bv[1] = *(const float4*)(bias + 16 + 4 * g);
  bv[2] = (g < 2) ? *(const float4*)(bias + 32 + 4 * g)
                  : make_float4(0.f, 0.f, 0.f, 0.f);
  #pragma unroll
  for (int tt = 0; tt < 3; ++tt) {
    if (tt == 2 && g >= 2) continue;
    #pragma unroll
    for (int mt = 0; mt < 2; ++mt) {
      const int p = mt * 16 + m;
      if (p >= 24) continue;
      float v[4];
      #pragma unroll
      for (int i = 0; i < 4; ++i)
        v[i] = actf(acc[mt][tt][i] + ((const float*)&bv[tt])[i], 1);
      uint2 pk;
      pk.x = pkbf(v[0], v[1]);
      pk.y = pkbf(v[2], v[3]);
      int byt = p * 80 + (16 * tt + 4 * g) * 2;
      byt ^= ((p >> 3) & 7) << 4;
      *(uint2*)(so + byt) = pk;
    }
  }

  const int yi = oy * 3 + w;
  const int y = 8 * oy - 2 + 2 * w;
  const bool rowinv = (y < 0);
  #pragma unroll
  for (int pass = 0; pass < 2; ++pass) {
    int j = pass * 64 + l;
    if (j >= 120) continue;
    int p = j / 5, oct = j % 5;
    int byt = p * 80 + oct * 16;
    byt ^= ((p >> 3) & 7) << 4;
    uint4 d = *(const uint4*)(so + byt);
    int x = 64 * xg + 8 * (p / 3) + 2 * (p % 3) - 2;
    if (rowinv || x < 0) {
      d = (uint4){0u, 0u, 0u, 0u};
    } else {
      const u16* rp = cla + (size_t)n * IMG_CL
                    + ((size_t)(y + 1) * IW + (x + 1)) * CH + oct * 8;
      uint4 rv = *(const uint4*)rp;
      d.x = addbf2(d.x, rv.x); d.y = addbf2(d.y, rv.y);
      d.z = addbf2(d.z, rv.z); d.w = addbf2(d.w, rv.w);
    }
    *(uint4*)(ddc + (((size_t)(n * 96 + yi)) * 96 + 24 * xg + p) * CH + oct * 8) = d;
  }
}

// ---- depthwise conv on compact dd ----------------------------------------
__global__ __launch_bounds__(256)
void dwconv_c(const u16* __restrict__ ddc, const float* __restrict__ w,
              const float* __restrict__ b, float* __restrict__ out)
{
  int idx = blockIdx.x * 256 + threadIdx.x;
  if (idx >= 8 * 32 * 32 * CH) return;
  int c = idx % CH;
  int p = idx / CH;
  int ox = p & 31;
  int oy = (p >> 5) & 31;
  int n = p >> 10;
  float acc = b[c];
  const u16* base = ddc + (((size_t)(n * 96 + oy * 3)) * 96 + ox * 3) * CH + c;
  #pragma unroll
  for (int dyi = 0; dyi < 3; ++dyi)
    #pragma unroll
    for (int dxi = 0; dxi < 3; ++dxi)
      acc += w[c * 9 + dyi * 3 + dxi] * b2f(base[((size_t)dyi * 96 + dxi) * CH]);
  out[((size_t)(n * CH + c) << 10) + oy * 32 + ox] = acc;
}

// ---- per-8x8-block iDCT on planar f32 32x32 ------------------------------
__global__ __launch_bounds__(256)
void idct8_k(const float* __restrict__ in, float* __restrict__ out)
{
  __shared__ float ctab[8];
  if (threadIdx.x < 8) {
    const float c_[8] = {1.f, 0.70710678118654752f, 0.f, -0.70710678118654752f,
                         -1.f, -0.70710678118654752f, 0.f, 0.70710678118654752f};
    ctab[threadIdx.x] = c_[threadIdx.x];
  }
  __syncthreads();
  int idx = blockIdx.x * 256 + threadIdx.x;
  if (idx >= 8 * CH * 32 * 32) return;
  int ox = idx & 31, oy = (idx >> 5) & 31, bc = idx >> 10;
  int k = oy & 7, lq = ox & 7;
  const float* ip = in + bc * 1024 + (oy & ~7) * 32 + (ox & ~7);
  float acc = 0.f;
  #pragma unroll
  for (int mm = 0; mm < 8; ++mm) {
    float rk = ctab[(k * mm) & 7];
    float s = 0.f;
    #pragma unroll
    for (int nn = 0; nn < 8; ++nn)
      s += ctab[(lq * nn) & 7] * ip[mm * 32 + nn];
    acc += rk * s;
  }
  out[idx] = acc * 0.125f;
}

// ---- MFMA 1x1 conv + sigmoid + bilinear(32->256) multiply; cl bf16 -------
__global__ __launch_bounds__(256)
void wgtmul_k(const u16* __restrict__ t1cl, const u16* __restrict__ wt3,
              const float* __restrict__ b3, const float* __restrict__ dct,
              u16* __restrict__ outcl)
{
  __shared__ float s_yw[40 * 33];
  __shared__ u16 s_out[4 * 3072];

  const int q8 = (int)gridDim.x >> 3;
  const int bid = ((int)blockIdx.x & 7) * q8 + ((int)blockIdx.x >> 3);
  const int n = bid >> 8;
  const int y = bid & 255;
  const int tid = threadIdx.x;

  float sy = (y + 0.5f) * 0.125f - 0.5f;
  float yq = floorf(sy);
  float fy = sy - yq;
  int y0c = max((int)yq, 0), y1c = min((int)yq + 1, 31);

  for (int i = tid; i < 1280; i += 256) {
    int oc = i >> 5, c = i & 31;
    const float* sp = dct + ((size_t)(n * CH + oc) << 10);
    s_yw[oc * 33 + c] = (1.f - fy) * sp[y0c * 32 + c] + fy * sp[y1c * 32 + c];
  }
  __syncthreads();

  const int w = tid >> 6;
  const int l = tid & 63;
  const int g = l >> 4;
  const int m = l & 15;
  const int xb = w << 6;

  const u16* tp = t1cl + (size_t)n * IMG_CL + ((size_t)(y + 1) * IW + 1) * CH;

  f32x4 acc[4][3];
  #pragma unroll
  for (int xt = 0; xt < 4; ++xt)
    #pragma unroll
    for (int t = 0; t < 3; ++t) acc[xt][t] = (f32x4){0.f, 0.f, 0.f, 0.f};

  #pragma unroll
  for (int xt = 0; xt < 4; ++xt) {
    const u16* ap = tp + (size_t)(xb + xt * 16 + m) * CH;
    bf16x8 a0 = *(const bf16x8*)(ap + 8 * g);
    bf16x8 a1 = *(const bf16x8*)(ap + 32 + 8 * g);
    #pragma unroll
    for (int t = 0; t < 3; ++t) {
      bf16x8 b0 = *(const bf16x8*)(wt3 + (m + 16 * t) * 384 + 8 * g);
      bf16x8 b1 = *(const bf16x8*)(wt3 + (m + 16 * t) * 384 + 32 + 8 * g);
      acc[xt][t] = __builtin_amdgcn_mfma_f32_16x16x32_bf16(b0, a0, acc[xt][t], 0, 0, 0);
      acc[xt][t] = __builtin_amdgcn_mfma_f32_16x16x32_bf16(b1, a1, acc[xt][t], 0, 0, 0);
    }
  }

  u16* so = s_out + w * 3072;
  float4 bv[3];
  bv[0] = *(const float4*)(b3 + 4 * g);
  bv[1] = *(const float4*)(b3 + 16 + 4 * g);
  bv[2] = (g < 2) ? *(const float4*)(b3 + 32 + 4 * g) : make_float4(0.f, 0.f, 0.f, 0.f);
  #pragma unroll
  for (int t = 0; t < 3; ++t) {
    if (t == 2 && g >= 2) continue;
    #pragma unroll
    for (int xt = 0; xt < 4; ++xt) {
      const int pxl = xt * 16 + m;
      const int px = xb + pxl;
      float sx = (px + 0.5f) * 0.125f - 0.5f;
      float xq = floorf(sx);
      float fx = sx - xq;
      int x0c = max((int)xq, 0), x1c = min((int)xq + 1, 31);
      float r4[4];
      #pragma unroll
      for (int i = 0; i < 4; ++i) {
        int oc = 16 * t + 4 * g + i;
        float wgt = 1.f / (1.f + __expf(-(acc[xt][t][i] + ((const float*)&bv[t])[i])));
        float bil = (1.f - fx) * s_yw[oc * 33 + x0c] + fx * s_yw[oc * 33 + x1c];
        r4[i] = wgt * bil;
      }
      uint2 pk;
      pk.x = pkbf(r4[0], r4[1]);
      pk.y = pkbf(r4[2], r4[3]);
      int byt = pxl * 80 + (16 * t + 4 * g) * 2;
      byt ^= ((pxl >> 3) & 7) << 4;
      *(uint2*)((char*)so + byt) = pk;
    }
  }
  const size_t rowu = (size_t)n * IMG_CL + ((size_t)(y + 1) * IW + (xb + 1)) * CH;
  #pragma unroll
  for (int q = 0; q < 5; ++q) {
    int byt = l * 80 + q * 16;
    byt ^= ((l >> 3) & 7) << 4;
    uint4 d = *(const uint4*)((const char*)so + byt);
    *(uint4*)(outcl + rowu + (size_t)l * 40 + q * 8) = d;
  }
}

extern "C" void kernel_launch(void* const* d_in, const int* in_sizes, int n_in,
                              void* d_out, int out_size, void* d_ws, size_t ws_size,
                              hipStream_t stream)
{
  const float* x       = (const float*)d_in[0];
  const float* conv_w  = (const float*)d_in[1];
  const float* conv_b  = (const float*)d_in[2];
  const float* ddct_w  = (const float*)d_in[3];
  const float* ddct_b  = (const float*)d_in[4];
  const float* dctc_w  = (const float*)d_in[5];
  const float* dctc_b  = (const float*)d_in[6];
  const float* w1_w    = (const float*)d_in[7];
  const float* w1_b    = (const float*)d_in[8];
  const float* w3_w    = (const float*)d_in[9];
  const float* w3_b    = (const float*)d_in[10];
  const float* after_w = (const float*)d_in[11];
  const float* after_b = (const float*)d_in[12];

  char* ws = (char*)d_ws;
  const size_t CLB = (size_t)8 * IMG_CL * 2;          // 42,600,960 B
  float* small0 = (float*)ws;                         // 1,310,720
  float* small1 = (float*)(ws + 1310720);             // 1,310,720
  u16*   wt4    = (u16*)(ws + 2621440);               // 36,864 (w3 rm)
  u16*   wcma   = (u16*)(ws + 2658304);               // 30,720 (after cm)
  u16*   wsc    = (u16*)(ws + 2689024);               // 88,320 (3 compressed)
  u16*   ddc    = (u16*)(ws + 2777344);               // 5,898,240 compact dd
  u16*   cl_a   = (u16*)(ws + 8675584);               // dct_feat, later prod
  u16*   cl_c   = (u16*)(ws + 8675584 + CLB);         // t1

  // 0. weight transforms + cl_a ring zeroing
  prep_w_k<<<305, 256, 0, stream>>>(conv_w, ddct_w, w1_w, after_w, w3_w,
                                    wt4, wcma, wsc);
  ringz_k<<<8 * IW, 256, 0, stream>>>(cl_a);
  // 1+5. dct_feat = gelu(conv1(x)) -> cl_a ; t1 = relu(conv5(x)) -> cl_c
  fconv2p_k<<<2048, 256, 0, stream>>>(x, wsc, wsc + WSC_SET,
                                      conv_b, w1_b, cl_a, cl_c);
  // 2. SPARSE dd at dwconv sample points           -> ddc (compact)
  sconv_k<<<1024, 256, 0, stream>>>(cl_a, wsc + 2 * WSC_SET, ddct_b, ddc);
  // 3. depthwise strided conv on compact dd        -> small0
  dwconv_c<<<1280, 256, 0, stream>>>(ddc, dctc_w, dctc_b, small0);
  // 4. per-block 8x8 iDCT                          -> small1
  idct8_k<<<1280, 256, 0, stream>>>(small0, small1);
  // 6. prod = sigmoid(1x1(t1)) * bilinear(idct)    -> cl_a (dct_feat dead)
  wgtmul_k<<<2048, 256, 0, stream>>>(cl_c, wt4, w3_b, small1, cl_a);
  // 7. out = conv(prod, after)                     -> d_out fp32 planar
  convl_k<0, true><<<2048, 256, 0, stream>>>(cl_a, wcma, after_b, (void*)d_out);
}

// Round 17
// 157.057 us; speedup vs baseline: 2.4989x; 1.0777x over previous
//
#include <hip/hip_runtime.h>

typedef unsigned short u16;
typedef unsigned int u32;
typedef __attribute__((ext_vector_type(8))) short bf16x8;
typedef __attribute__((ext_vector_type(4))) float f32x4;

#define CH 40
#define IW 258                   // ring-padded width (256 + 2)
#define IWCH (IW * CH)           // 10320
#define IMG_CL (IW * IW * CH)    // u16 elements per image, channel-last padded
#define WT_SET (48 * 384)        // u16: w3 row-major set (wgtmul)
#define WCM_SET (48 * 40 * 8)    // u16: after_w chunk-major set (conv7) = 15360
#define WSC_SET (46 * 40 * 8)    // u16 compressed set: 45 real + 1 zero = 14720

#define GLDS16(g, l) __builtin_amdgcn_global_load_lds( \
    (const __attribute__((address_space(1))) void*)(g), \
    (__attribute__((address_space(3))) void*)(l), 16, 0, 0)

__device__ __forceinline__ float b2f(u16 u) {
  union { u32 i; float f; } v; v.i = ((u32)u) << 16; return v.f;
}
// HW packed f32->bf16 (RNE)
__device__ __forceinline__ u32 pkbf(float lo, float hi) {
  u32 r;
  asm("v_cvt_pk_bf16_f32 %0, %1, %2" : "=v"(r) : "v"(lo), "v"(hi));
  return r;
}
__device__ __forceinline__ u16 f2b(float f) {
  union { float f; u32 i; } v; v.f = f;
  u32 r = v.i + 0x7fffu + ((v.i >> 16) & 1u);
  return (u16)(r >> 16);
}
__device__ __forceinline__ u32 addbf2(u32 a, u32 b) {
  union { u32 i; float f; } lo_a, lo_b, hi_a, hi_b;
  lo_a.i = a << 16; lo_b.i = b << 16;
  hi_a.i = a & 0xffff0000u; hi_b.i = b & 0xffff0000u;
  return pkbf(lo_a.f + lo_b.f, hi_a.f + hi_b.f);
}
// tanh-approx gelu (validated r10)
__device__ __forceinline__ float actf(float t, int ACT) {
  if (ACT == 1) {
    float u2 = t * (1.5957691216057308f + 0.07135481627000862f * t * t);
    float e = __expf(u2);
    return t - t / (e + 1.f);
  }
  if (ACT == 2) return fmaxf(t, 0.f);
  return t;
}

// ---- weights: w3 rm + after cm + compressed 46-chunk x3 ------------------
__global__ __launch_bounds__(256)
void prep_w_k(const float* __restrict__ w0, const float* __restrict__ w1,
              const float* __restrict__ w2, const float* __restrict__ w3,
              const float* __restrict__ w4, u16* __restrict__ wt4,
              u16* __restrict__ wcma, u16* __restrict__ wsc)
{
  int i = blockIdx.x * 256 + threadIdx.x;
  if (i >= WT_SET + WCM_SET + 3 * WSC_SET) return;
  if (i < WT_SET) {
    int k = i % 384;
    int oc = i / 384;
    u16 v = 0;
    if (oc < 40 && k < 40) v = f2b(w4[oc * 40 + k]);
    wt4[i] = v;
  } else if (i < WT_SET + WCM_SET) {
    int j = i - WT_SET;
    int c = j / 320;
    int rem = j - c * 320;
    int oc = rem >> 3;
    int e = rem & 7;
    int k = c * 8 + e;
    int dy = k >> 7;
    int r = k & 127;
    u16 v = 0;
    if (r < 120) {
      int dx = r / 40;
      int ic = r - dx * 40;
      v = f2b(w3[((oc * 40 + ic) * 3 + dy) * 3 + dx]);
    }
    wcma[j] = v;
  } else {
    int j2 = i - WT_SET - WCM_SET;
    int set3 = j2 / WSC_SET;
    int r3 = j2 - set3 * WSC_SET;
    int c2 = r3 / 320;
    int rem = r3 - c2 * 320;
    int oc = rem >> 3;
    int e = rem & 7;
    u16 v = 0;
    if (c2 < 45) {
      int dy = c2 / 15, cc = c2 % 15;
      int dx = cc / 5, icq = cc % 5;
      int ic = icq * 8 + e;
      const float* w = (set3 == 0) ? w0 : (set3 == 1) ? w2 : w1;
      v = f2b(w[((oc * 40 + ic) * 3 + dy) * 3 + dx]);
    }
    wsc[j2] = v;
  }
}

// ---- zero the halo rings of cl_a -----------------------------------------
__global__ __launch_bounds__(256)
void ringz_k(u16* __restrict__ cla)
{
  const int n = blockIdx.x / IW;
  const int yr = blockIdx.x % IW;
  const int t = threadIdx.x;
  const size_t base = (size_t)n * IMG_CL + (size_t)yr * IWCH;
  const uint4 z = {0u, 0u, 0u, 0u};
  if (yr == 0 || yr == IW - 1) {
    for (int i = t; i < IWCH / 8; i += 256) ((uint4*)(cla + base))[i] = z;
    return;
  }
  if (t < 5) {
    ((uint4*)(cla + base))[t] = z;
  } else if (t < 10) {
    ((uint4*)(cla + base + (size_t)(IW - 1) * CH))[t - 5] = z;
  }
}

// ---- fused conv1+conv5, 512 thr / 8 waves: wave (ry=w>>1, h=w&1) covers
// 2 x-subtiles of row y0+ry. In-kernel x->bf16 conversion, 2 weight passes.
__global__ __launch_bounds__(512, 2)
void fconv2p_k(const float* __restrict__ xg, const u16* __restrict__ wscA,
               const u16* __restrict__ wscB, const float* __restrict__ biasA,
               const float* __restrict__ biasB, u16* __restrict__ outA,
               u16* __restrict__ outB)
{
  __shared__ __align__(16) u16 s_mem[30560];   // x 15840 + w 14720 = 61120 B
  u16* s_in = s_mem;
  u16* s_w  = s_mem + 15840;                   // weights; reused as restage

  const int tid = threadIdx.x;
  const int bid = ((int)blockIdx.x & 7) * 256 + ((int)blockIdx.x >> 3);
  const int n = bid >> 8;
  const int tb = bid & 255;
  const int y0 = (tb >> 2) << 2;
  const int x0 = (tb & 3) << 6;

  #pragma unroll
  for (int k = 0; k < 4; ++k) {                // wA: 1840 16B chunks
    int i = tid + (k << 9);
    if (i < 1840) GLDS16(wscA + i * 8, s_w + i * 8);
  }
  // stage x tile (6 rows x 66 px x 40 ic), packed-converting
  const float* xsrc = xg + (size_t)n * CH * 65536;
  if (tid < 396) {
    int slot = tid;
    int r = slot / 66, p = slot - r * 66;
    int gy = y0 + r - 1, gx = x0 + p - 1;
    __attribute__((aligned(16))) u32 buf[20];
    if ((unsigned)gy < 256u && (unsigned)gx < 256u) {
      const float* xp = xsrc + (size_t)gy * 256 + gx;
      #pragma unroll
      for (int icp = 0; icp < 20; ++icp)
        buf[icp] = pkbf(xp[(size_t)(2 * icp) * 65536],
                        xp[(size_t)(2 * icp + 1) * 65536]);
    } else {
      #pragma unroll
      for (int icp = 0; icp < 20; ++icp) buf[icp] = 0u;
    }
    u16* dst = s_in + slot * 40;
    #pragma unroll
    for (int q = 0; q < 5; ++q) ((uint4*)dst)[q] = ((const uint4*)buf)[q];
  }
  __syncthreads();

  const int w = tid >> 6;
  const int ry = w >> 1;                       // output row y0+ry
  const int h = w & 1;                         // x half: px (2h..2h+1)*16
  const int l = tid & 63;
  const int g = l >> 4;
  const int m = l & 15;

  f32x4 accA[2][3], accB[2][3];
  #pragma unroll
  for (int xt = 0; xt < 2; ++xt)
    #pragma unroll
    for (int tt = 0; tt < 3; ++tt) {
      accA[xt][tt] = (f32x4){0.f, 0.f, 0.f, 0.f};
      accB[xt][tt] = (f32x4){0.f, 0.f, 0.f, 0.f};
    }

  // ---- K-loop pass A -----------------------------------------------------
  #pragma unroll
  for (int s = 0; s < 12; ++s) {
    const int dy = s >> 2;
    const int c = ((s & 3) << 2) + g;
    int dx, icb;
    if (c >= 15)      { dx = 0; icb = 0; }
    else if (c >= 10) { dx = 2; icb = (c - 10) * 8; }
    else if (c >= 5)  { dx = 1; icb = (c - 5) * 8; }
    else              { dx = 0; icb = c * 8; }
    const int abase = (ry + dy) * (66 * CH) + ((h * 2) * 16 + m + dx) * CH + icb;
    bf16x8 a0 = *(const bf16x8*)(s_in + abase);
    bf16x8 a1 = *(const bf16x8*)(s_in + abase + 16 * CH);
    const u16* wrow = s_w + ((c >= 15) ? 45 * 320 : (dy * 15 + c) * 320);
    bf16x8 b0 = *(const bf16x8*)(wrow + m * 8);
    bf16x8 b1 = *(const bf16x8*)(wrow + (m + 16) * 8);
    bf16x8 b2 = *(const bf16x8*)(wrow + (m >= 8 ? 312 : (m + 32) * 8));
    accA[0][0] = __builtin_amdgcn_mfma_f32_16x16x32_bf16(b0, a0, accA[0][0], 0, 0, 0);
    accA[1][0] = __builtin_amdgcn_mfma_f32_16x16x32_bf16(b0, a1, accA[1][0], 0, 0, 0);
    accA[0][1] = __builtin_amdgcn_mfma_f32_16x16x32_bf16(b1, a0, accA[0][1], 0, 0, 0);
    accA[1][1] = __builtin_amdgcn_mfma_f32_16x16x32_bf16(b1, a1, accA[1][1], 0, 0, 0);
    accA[0][2] = __builtin_amdgcn_mfma_f32_16x16x32_bf16(b2, a0, accA[0][2], 0, 0, 0);
    accA[1][2] = __builtin_amdgcn_mfma_f32_16x16x32_bf16(b2, a1, accA[1][2], 0, 0, 0);
  }

  __syncthreads();                             // all waves done reading wA
  #pragma unroll
  for (int k = 0; k < 4; ++k) {                // wB into same region
    int i = tid + (k << 9);
    if (i < 1840) GLDS16(wscB + i * 8, s_w + i * 8);
  }
  __syncthreads();                             // wB ready (vmcnt drained)

  // ---- K-loop pass B -----------------------------------------------------
  #pragma unroll
  for (int s = 0; s < 12; ++s) {
    const int dy = s >> 2;
    const int c = ((s & 3) << 2) + g;
    int dx, icb;
    if (c >= 15)      { dx = 0; icb = 0; }
    else if (c >= 10) { dx = 2; icb = (c - 10) * 8; }
    else if (c >= 5)  { dx = 1; icb = (c - 5) * 8; }
    else              { dx = 0; icb = c * 8; }
    const int abase = (ry + dy) * (66 * CH) + ((h * 2) * 16 + m + dx) * CH + icb;
    bf16x8 a0 = *(const bf16x8*)(s_in + abase);
    bf16x8 a1 = *(const bf16x8*)(s_in + abase + 16 * CH);
    const u16* wrow = s_w + ((c >= 15) ? 45 * 320 : (dy * 15 + c) * 320);
    bf16x8 b0 = *(const bf16x8*)(wrow + m * 8);
    bf16x8 b1 = *(const bf16x8*)(wrow + (m + 16) * 8);
    bf16x8 b2 = *(const bf16x8*)(wrow + (m >= 8 ? 312 : (m + 32) * 8));
    accB[0][0] = __builtin_amdgcn_mfma_f32_16x16x32_bf16(b0, a0, accB[0][0], 0, 0, 0);
    accB[1][0] = __builtin_amdgcn_mfma_f32_16x16x32_bf16(b0, a1, accB[1][0], 0, 0, 0);
    accB[0][1] = __builtin_amdgcn_mfma_f32_16x16x32_bf16(b1, a0, accB[0][1], 0, 0, 0);
    accB[1][1] = __builtin_amdgcn_mfma_f32_16x16x32_bf16(b1, a1, accB[1][1], 0, 0, 0);
    accB[0][2] = __builtin_amdgcn_mfma_f32_16x16x32_bf16(b2, a0, accB[0][2], 0, 0, 0);
    accB[1][2] = __builtin_amdgcn_mfma_f32_16x16x32_bf16(b2, a1, accB[1][2], 0, 0, 0);
  }

  __syncthreads();                             // all reads of s_w/s_in done

  float4 bvA[3], bvB[3];
  bvA[0] = *(const float4*)(biasA + 4 * g);
  bvA[1] = *(const float4*)(biasA + 16 + 4 * g);
  bvA[2] = (g < 2) ? *(const float4*)(biasA + 32 + 4 * g) : make_float4(0.f, 0.f, 0.f, 0.f);
  bvB[0] = *(const float4*)(biasB + 4 * g);
  bvB[1] = *(const float4*)(biasB + 16 + 4 * g);
  bvB[2] = (g < 2) ? *(const float4*)(biasB + 32 + 4 * g) : make_float4(0.f, 0.f, 0.f, 0.f);

  // row-shared restage regions: row ry -> s_w + ry*5120 bytes
  char* so = (char*)s_w + ry * 5120;
  const int rdrow = tid >> 7;                  // readback: 128 threads per row
  const int l2 = tid & 127;
  const size_t rowu_rd = (size_t)n * IMG_CL
                       + ((size_t)(y0 + rdrow + 1) * IW + (x0 + 1)) * CH;

  // ---- pass A: restage (waves write own px) -> barrier -> readback -------
  #pragma unroll
  for (int tt = 0; tt < 3; ++tt) {
    if (tt == 2 && g >= 2) continue;
    #pragma unroll
    for (int xt = 0; xt < 2; ++xt) {
      const int pxl = (2 * h + xt) * 16 + m;
      float v[4];
      #pragma unroll
      for (int i = 0; i < 4; ++i)
        v[i] = actf(accA[xt][tt][i] + ((const float*)&bvA[tt])[i], 1);
      uint2 pk;
      pk.x = pkbf(v[0], v[1]);
      pk.y = pkbf(v[2], v[3]);
      int byt = pxl * 80 + (16 * tt + 4 * g) * 2;
      byt ^= ((pxl >> 3) & 7) << 4;
      *(uint2*)(so + byt) = pk;
    }
  }
  __syncthreads();
  {
    const char* ro = (const char*)s_w + rdrow * 5120;
    #pragma unroll
    for (int pass = 0; pass < 3; ++pass) {
      int j = l2 + (pass << 7);
      if (j < 320) {
        int px = j / 5, oct = j % 5;
        int byt = px * 80 + oct * 16;
        byt ^= ((px >> 3) & 7) << 4;
        uint4 d = *(const uint4*)(ro + byt);
        *(uint4*)(outA + rowu_rd + (size_t)px * 40 + oct * 8) = d;
      }
    }
  }
  __syncthreads();

  // ---- pass B ------------------------------------------------------------
  #pragma unroll
  for (int tt = 0; tt < 3; ++tt) {
    if (tt == 2 && g >= 2) continue;
    #pragma unroll
    for (int xt = 0; xt < 2; ++xt) {
      const int pxl = (2 * h + xt) * 16 + m;
      float v[4];
      #pragma unroll
      for (int i = 0; i < 4; ++i)
        v[i] = actf(accB[xt][tt][i] + ((const float*)&bvB[tt])[i], 2);
      uint2 pk;
      pk.x = pkbf(v[0], v[1]);
      pk.y = pkbf(v[2], v[3]);
      int byt = pxl * 80 + (16 * tt + 4 * g) * 2;
      byt ^= ((pxl >> 3) & 7) << 4;
      *(uint2*)(so + byt) = pk;
    }
  }
  __syncthreads();
  {
    const char* ro = (const char*)s_w + rdrow * 5120;
    #pragma unroll
    for (int pass = 0; pass < 3; ++pass) {
      int j = l2 + (pass << 7);
      if (j < 320) {
        int px = j / 5, oct = j % 5;
        int byt = px * 80 + oct * 16;
        byt ^= ((px >> 3) & 7) << 4;
        uint4 d = *(const uint4*)(ro + byt);
        *(uint4*)(outB + rowu_rd + (size_t)px * 40 + oct * 8) = d;
      }
    }
  }
}

// ---- conv7: all-LDS MFMA conv 3x3, planar f32 out, 512 thr / 8 waves -----
__global__ __launch_bounds__(512, 2)
void convl_k(const u16* __restrict__ incl, const u16* __restrict__ wcm,
             const float* __restrict__ bias, float* __restrict__ outp)
{
  __shared__ __align__(16) u16 s_mem[31200];   // input 15840 + weights 15360
  u16* s_in = s_mem;
  u16* s_w  = s_mem + 15840;

  const int tid = threadIdx.x;
  const int bid = ((int)blockIdx.x & 7) * 256 + ((int)blockIdx.x >> 3);
  const int n = bid >> 8;
  const int tb = bid & 255;
  const int y0 = (tb >> 2) << 2;
  const int x0 = (tb & 3) << 6;

  const u16* src = incl + (size_t)n * IMG_CL + ((size_t)y0 * IW + x0) * CH;
  #pragma unroll
  for (int k = 0; k < 4; ++k) {
    int i = tid + (k << 9);
    if (i < 1980) {
      int r = i / 330, o = i - r * 330;
      GLDS16(src + (size_t)r * IWCH + o * 8, s_in + i * 8);
    }
  }
  #pragma unroll
  for (int k = 0; k < 4; ++k) {
    int i = tid + (k << 9);
    if (i < 1920) GLDS16(wcm + i * 8, s_w + i * 8);
  }
  __syncthreads();

  const int w = tid >> 6;
  const int ry = w >> 1;
  const int h = w & 1;
  const int l = tid & 63;
  const int g = l >> 4;
  const int m = l & 15;

  f32x4 acc[2][3];
  #pragma unroll
  for (int xt = 0; xt < 2; ++xt)
    #pragma unroll
    for (int tt = 0; tt < 3; ++tt) acc[xt][tt] = (f32x4){0.f, 0.f, 0.f, 0.f};

  #pragma unroll
  for (int s = 0; s < 12; ++s) {
    const int dy = s >> 2;
    const int c = ((s & 3) << 2) + g;
    int dx, icb;
    if (c >= 15)      { dx = 0; icb = 0; }
    else if (c >= 10) { dx = 2; icb = (c - 10) * 8; }
    else if (c >= 5)  { dx = 1; icb = (c - 5) * 8; }
    else              { dx = 0; icb = c * 8; }
    const int abase = (ry + dy) * (66 * CH) + ((h * 2) * 16 + m + dx) * CH + icb;
    bf16x8 a0 = *(const bf16x8*)(s_in + abase);
    bf16x8 a1 = *(const bf16x8*)(s_in + abase + 16 * CH);

    const int ch = (s << 2) + g;
    const u16* wrow = s_w + ch * 320;
    bf16x8 b0 = *(const bf16x8*)(wrow + m * 8);
    bf16x8 b1 = *(const bf16x8*)(wrow + (m + 16) * 8);
    bf16x8 b2 = *(const bf16x8*)(wrow + (m >= 8 ? 312 : (m + 32) * 8));

    acc[0][0] = __builtin_amdgcn_mfma_f32_16x16x32_bf16(a0, b0, acc[0][0], 0, 0, 0);
    acc[1][0] = __builtin_amdgcn_mfma_f32_16x16x32_bf16(a1, b0, acc[1][0], 0, 0, 0);
    acc[0][1] = __builtin_amdgcn_mfma_f32_16x16x32_bf16(a0, b1, acc[0][1], 0, 0, 0);
    acc[1][1] = __builtin_amdgcn_mfma_f32_16x16x32_bf16(a1, b1, acc[1][1], 0, 0, 0);
    acc[0][2] = __builtin_amdgcn_mfma_f32_16x16x32_bf16(a0, b2, acc[0][2], 0, 0, 0);
    acc[1][2] = __builtin_amdgcn_mfma_f32_16x16x32_bf16(a1, b2, acc[1][2], 0, 0, 0);
  }

  const int y = y0 + ry;
  const float bv0 = bias[m];
  const float bv1 = bias[m + 16];
  const float bv2 = (m < 8) ? bias[m + 32] : 0.f;
  #pragma unroll
  for (int tt = 0; tt < 3; ++tt) {
    const int oc = m + 16 * tt;
    if (tt == 2 && m >= 8) continue;
    const float bv = (tt == 0) ? bv0 : (tt == 1) ? bv1 : bv2;
    #pragma unroll
    for (int xt = 0; xt < 2; ++xt) {
      const int xb = x0 + (2 * h + xt) * 16 + 4 * g;
      float v[4];
      #pragma unroll
      for (int i = 0; i < 4; ++i) v[i] = acc[xt][tt][i] + bv;
      *(float4*)(outp + (((size_t)(n * CH + oc)) << 16) + ((size_t)y << 8) + xb)
          = make_float4(v[0], v[1], v[2], v[3]);
    }
  }
}

// ---- SPARSE conv2 (r13-verified) -----------------------------------------
__global__ __launch_bounds__(256, 2)
void sconv_k(const u16* __restrict__ cla, const u16* __restrict__ wsc,
             const float* __restrict__ bias, u16* __restrict__ ddc)
{
  __shared__ __align__(16) u16 s_mem[32640];   // s_in 17920 + s_w 14720
  u16* s_in = s_mem;
  u16* s_w  = s_mem + 17920;

  const int tid = threadIdx.x;
  const int bid = ((int)blockIdx.x & 7) * 128 + ((int)blockIdx.x >> 3); // 1024
  const int n = bid >> 7;
  const int oy = (bid >> 2) & 31;
  const int xg = bid & 3;

  const u16* src = cla + (ptrdiff_t)((size_t)n * IMG_CL)
                       + (ptrdiff_t)(8 * oy - 2) * IWCH + (64 * xg - 2) * CH;
  #pragma unroll
  for (int k = 0; k < 9; ++k) {
    int i = tid + (k << 8);
    if (i < 2240) {
      int r = i / 320, o = i - r * 320;
      GLDS16(src + (ptrdiff_t)r * IWCH + o * 8, s_in + i * 8);
    }
  }
  #pragma unroll
  for (int k = 0; k < 8; ++k) {
    int i = tid + (k << 8);
    if (i < 1840) GLDS16(wsc + i * 8, s_w + i * 8);
  }
  __syncthreads();

  const int w = tid >> 6;
  const int l = tid & 63;
  const int g = l >> 4;
  const int m = l & 15;

  const int p0 = m;
  const int p1 = (m < 8) ? 16 + m : 23;
  const int rb0 = 8 * (p0 / 3) + 2 * (p0 % 3);
  const int rb1 = 8 * (p1 / 3) + 2 * (p1 % 3);

  f32x4 acc[2][3];
  #pragma unroll
  for (int mt = 0; mt < 2; ++mt)
    #pragma unroll
    for (int tt = 0; tt < 3; ++tt) acc[mt][tt] = (f32x4){0.f, 0.f, 0.f, 0.f};

  if (w < 3) {
    #pragma unroll
    for (int s = 0; s < 12; ++s) {
      const int dy = s >> 2;
      const int c = ((s & 3) << 2) + g;
      int dx, icb;
      if (c >= 15)      { dx = 0; icb = 0; }
      else if (c >= 10) { dx = 2; icb = (c - 10) * 8; }
      else if (c >= 5)  { dx = 1; icb = (c - 5) * 8; }
      else              { dx = 0; icb = c * 8; }
      const int rowb = (2 * w + dy) * 2560;
      bf16x8 a0 = *(const bf16x8*)(s_in + rowb + (rb0 + dx) * CH + icb);
      bf16x8 a1 = *(const bf16x8*)(s_in + rowb + (rb1 + dx) * CH + icb);

      const u16* wrow = s_w + ((c == 15) ? 45 * 320 : (dy * 15 + c) * 320);
      bf16x8 b0 = *(const bf16x8*)(wrow + m * 8);
      bf16x8 b1 = *(const bf16x8*)(wrow + (m + 16) * 8);
      bf16x8 b2 = *(const bf16x8*)(wrow + (m >= 8 ? 312 : (m + 32) * 8));

      acc[0][0] = __builtin_amdgcn_mfma_f32_16x16x32_bf16(b0, a0, acc[0][0], 0, 0, 0);
      acc[1][0] = __builtin_amdgcn_mfma_f32_16x16x32_bf16(b0, a1, acc[1][0], 0, 0, 0);
      acc[0][1] = __builtin_amdgcn_mfma_f32_16x16x32_bf16(b1, a0, acc[0][1], 0, 0, 0);
      acc[1][1] = __builtin_amdgcn_mfma_f32_16x16x32_bf16(b1, a1, acc[1][1], 0, 0, 0);
      acc[0][2] = __builtin_amdgcn_mfma_f32_16x16x32_bf16(b2, a0, acc[0][2], 0, 0, 0);
      acc[1][2] = __builtin_amdgcn_mfma_f32_16x16x32_bf16(b2, a1, acc[1][2], 0, 0, 0);
    }
  }

  __syncthreads();
  if (w == 3) return;

  char* so = (char*)s_w + w * 2048;
  float4 bv[3];
  bv[0] = *(const float4*)(bias + 4 * g);
  bv[1] = *(const float4*)(bias + 16 + 4 * g);
  bv[2] = (g < 2) ? *(const float4*)(bias + 32 + 4 * g)
                  : make_float4(0.f, 0.f, 0.f, 0.f);
  #pragma unroll
  for (int tt = 0; tt < 3; ++tt) {
    if (tt == 2 && g >= 2) continue;
    #pragma unroll
    for (int mt = 0; mt < 2; ++mt) {
      const int p = mt * 16 + m;
      if (p >= 24) continue;
      float v[4];
      #pragma unroll
      for (int i = 0; i < 4; ++i)
        v[i] = actf(acc[mt][tt][i] + ((const float*)&bv[tt])[i], 1);
      uint2 pk;
      pk.x = pkbf(v[0], v[1]);
      pk.y = pkbf(v[2], v[3]);
      int byt = p * 80 + (16 * tt + 4 * g) * 2;
      byt ^= ((p >> 3) & 7) << 4;
      *(uint2*)(so + byt) = pk;
    }
  }

  const int yi = oy * 3 + w;
  const int y = 8 * oy - 2 + 2 * w;
  const bool rowinv = (y < 0);
  #pragma unroll
  for (int pass = 0; pass < 2; ++pass) {
    int j = pass * 64 + l;
    if (j >= 120) continue;
    int p = j / 5, oct = j % 5;
    int byt = p * 80 + oct * 16;
    byt ^= ((p >> 3) & 7) << 4;
    uint4 d = *(const uint4*)(so + byt);
    int x = 64 * xg + 8 * (p / 3) + 2 * (p % 3) - 2;
    if (rowinv || x < 0) {
      d = (uint4){0u, 0u, 0u, 0u};
    } else {
      const u16* rp = cla + (size_t)n * IMG_CL
                    + ((size_t)(y + 1) * IW + (x + 1)) * CH + oct * 8;
      uint4 rv = *(const uint4*)rp;
      d.x = addbf2(d.x, rv.x); d.y = addbf2(d.y, rv.y);
      d.z = addbf2(d.z, rv.z); d.w = addbf2(d.w, rv.w);
    }
    *(uint4*)(ddc + (((size_t)(n * 96 + yi)) * 96 + 24 * xg + p) * CH + oct * 8) = d;
  }
}

// ---- depthwise conv on compact dd ----------------------------------------
__global__ __launch_bounds__(256)
void dwconv_c(const u16* __restrict__ ddc, const float* __restrict__ w,
              const float* __restrict__ b, float* __restrict__ out)
{
  int idx = blockIdx.x * 256 + threadIdx.x;
  if (idx >= 8 * 32 * 32 * CH) return;
  int c = idx % CH;
  int p = idx / CH;
  int ox = p & 31;
  int oy = (p >> 5) & 31;
  int n = p >> 10;
  float acc = b[c];
  const u16* base = ddc + (((size_t)(n * 96 + oy * 3)) * 96 + ox * 3) * CH + c;
  #pragma unroll
  for (int dyi = 0; dyi < 3; ++dyi)
    #pragma unroll
    for (int dxi = 0; dxi < 3; ++dxi)
      acc += w[c * 9 + dyi * 3 + dxi] * b2f(base[((size_t)dyi * 96 + dxi) * CH]);
  out[((size_t)(n * CH + c) << 10) + oy * 32 + ox] = acc;
}

// ---- per-8x8-block iDCT on planar f32 32x32 ------------------------------
__global__ __launch_bounds__(256)
void idct8_k(const float* __restrict__ in, float* __restrict__ out)
{
  __shared__ float ctab[8];
  if (threadIdx.x < 8) {
    const float c_[8] = {1.f, 0.70710678118654752f, 0.f, -0.70710678118654752f,
                         -1.f, -0.70710678118654752f, 0.f, 0.70710678118654752f};
    ctab[threadIdx.x] = c_[threadIdx.x];
  }
  __syncthreads();
  int idx = blockIdx.x * 256 + threadIdx.x;
  if (idx >= 8 * CH * 32 * 32) return;
  int ox = idx & 31, oy = (idx >> 5) & 31, bc = idx >> 10;
  int k = oy & 7, lq = ox & 7;
  const float* ip = in + bc * 1024 + (oy & ~7) * 32 + (ox & ~7);
  float acc = 0.f;
  #pragma unroll
  for (int mm = 0; mm < 8; ++mm) {
    float rk = ctab[(k * mm) & 7];
    float s = 0.f;
    #pragma unroll
    for (int nn = 0; nn < 8; ++nn)
      s += ctab[(lq * nn) & 7] * ip[mm * 32 + nn];
    acc += rk * s;
  }
  out[idx] = acc * 0.125f;
}

// ---- MFMA 1x1 conv + sigmoid + bilinear(32->256) multiply; cl bf16 -------
__global__ __launch_bounds__(256)
void wgtmul_k(const u16* __restrict__ t1cl, const u16* __restrict__ wt3,
              const float* __restrict__ b3, const float* __restrict__ dct,
              u16* __restrict__ outcl)
{
  __shared__ float s_yw[40 * 33];
  __shared__ u16 s_out[4 * 3072];

  const int q8 = (int)gridDim.x >> 3;
  const int bid = ((int)blockIdx.x & 7) * q8 + ((int)blockIdx.x >> 3);
  const int n = bid >> 8;
  const int y = bid & 255;
  const int tid = threadIdx.x;

  float sy = (y + 0.5f) * 0.125f - 0.5f;
  float yq = floorf(sy);
  float fy = sy - yq;
  int y0c = max((int)yq, 0), y1c = min((int)yq + 1, 31);

  for (int i = tid; i < 1280; i += 256) {
    int oc = i >> 5, c = i & 31;
    const float* sp = dct + ((size_t)(n * CH + oc) << 10);
    s_yw[oc * 33 + c] = (1.f - fy) * sp[y0c * 32 + c] + fy * sp[y1c * 32 + c];
  }
  __syncthreads();

  const int w = tid >> 6;
  const int l = tid & 63;
  const int g = l >> 4;
  const int m = l & 15;
  const int xb = w << 6;

  const u16* tp = t1cl + (size_t)n * IMG_CL + ((size_t)(y + 1) * IW + 1) * CH;

  f32x4 acc[4][3];
  #pragma unroll
  for (int xt = 0; xt < 4; ++xt)
    #pragma unroll
    for (int t = 0; t < 3; ++t) acc[xt][t] = (f32x4){0.f, 0.f, 0.f, 0.f};

  #pragma unroll
  for (int xt = 0; xt < 4; ++xt) {
    const u16* ap = tp + (size_t)(xb + xt * 16 + m) * CH;
    bf16x8 a0 = *(const bf16x8*)(ap + 8 * g);
    bf16x8 a1 = *(const bf16x8*)(ap + 32 + 8 * g);
    #pragma unroll
    for (int t = 0; t < 3; ++t) {
      bf16x8 b0 = *(const bf16x8*)(wt3 + (m + 16 * t) * 384 + 8 * g);
      bf16x8 b1 = *(const bf16x8*)(wt3 + (m + 16 * t) * 384 + 32 + 8 * g);
      acc[xt][t] = __builtin_amdgcn_mfma_f32_16x16x32_bf16(b0, a0, acc[xt][t], 0, 0, 0);
      acc[xt][t] = __builtin_amdgcn_mfma_f32_16x16x32_bf16(b1, a1, acc[xt][t], 0, 0, 0);
    }
  }

  u16* so = s_out + w * 3072;
  float4 bv[3];
  bv[0] = *(const float4*)(b3 + 4 * g);
  bv[1] = *(const float4*)(b3 + 16 + 4 * g);
  bv[2] = (g < 2) ? *(const float4*)(b3 + 32 + 4 * g) : make_float4(0.f, 0.f, 0.f, 0.f);
  #pragma unroll
  for (int t = 0; t < 3; ++t) {
    if (t == 2 && g >= 2) continue;
    #pragma unroll
    for (int xt = 0; xt < 4; ++xt) {
      const int pxl = xt * 16 + m;
      const int px = xb + pxl;
      float sx = (px + 0.5f) * 0.125f - 0.5f;
      float xq = floorf(sx);
      float fx = sx - xq;
      int x0c = max((int)xq, 0), x1c = min((int)xq + 1, 31);
      float r4[4];
      #pragma unroll
      for (int i = 0; i < 4; ++i) {
        int oc = 16 * t + 4 * g + i;
        float wgt = 1.f / (1.f + __expf(-(acc[xt][t][i] + ((const float*)&bv[t])[i])));
        float bil = (1.f - fx) * s_yw[oc * 33 + x0c] + fx * s_yw[oc * 33 + x1c];
        r4[i] = wgt * bil;
      }
      uint2 pk;
      pk.x = pkbf(r4[0], r4[1]);
      pk.y = pkbf(r4[2], r4[3]);
      int byt = pxl * 80 + (16 * t + 4 * g) * 2;
      byt ^= ((pxl >> 3) & 7) << 4;
      *(uint2*)((char*)so + byt) = pk;
    }
  }
  const size_t rowu = (size_t)n * IMG_CL + ((size_t)(y + 1) * IW + (xb + 1)) * CH;
  #pragma unroll
  for (int q = 0; q < 5; ++q) {
    int byt = l * 80 + q * 16;
    byt ^= ((l >> 3) & 7) << 4;
    uint4 d = *(const uint4*)((const char*)so + byt);
    *(uint4*)(outcl + rowu + (size_t)l * 40 + q * 8) = d;
  }
}

extern "C" void kernel_launch(void* const* d_in, const int* in_sizes, int n_in,
                              void* d_out, int out_size, void* d_ws, size_t ws_size,
                              hipStream_t stream)
{
  const float* x       = (const float*)d_in[0];
  const float* conv_w  = (const float*)d_in[1];
  const float* conv_b  = (const float*)d_in[2];
  const float* ddct_w  = (const float*)d_in[3];
  const float* ddct_b  = (const float*)d_in[4];
  const float* dctc_w  = (const float*)d_in[5];
  const float* dctc_b  = (const float*)d_in[6];
  const float* w1_w    = (const float*)d_in[7];
  const float* w1_b    = (const float*)d_in[8];
  const float* w3_w    = (const float*)d_in[9];
  const float* w3_b    = (const float*)d_in[10];
  const float* after_w = (const float*)d_in[11];
  const float* after_b = (const float*)d_in[12];

  char* ws = (char*)d_ws;
  const size_t CLB = (size_t)8 * IMG_CL * 2;          // 42,600,960 B
  float* small0 = (float*)ws;                         // 1,310,720
  float* small1 = (float*)(ws + 1310720);             // 1,310,720
  u16*   wt4    = (u16*)(ws + 2621440);               // 36,864 (w3 rm)
  u16*   wcma   = (u16*)(ws + 2658304);               // 30,720 (after cm)
  u16*   wsc    = (u16*)(ws + 2689024);               // 88,320 (3 compressed)
  u16*   ddc    = (u16*)(ws + 2777344);               // 5,898,240 compact dd
  u16*   cl_a   = (u16*)(ws + 8675584);               // dct_feat, later prod
  u16*   cl_c   = (u16*)(ws + 8675584 + CLB);         // t1

  // 0. weight transforms + cl_a ring zeroing
  prep_w_k<<<305, 256, 0, stream>>>(conv_w, ddct_w, w1_w, after_w, w3_w,
                                    wt4, wcma, wsc);
  ringz_k<<<8 * IW, 256, 0, stream>>>(cl_a);
  // 1+5. dct_feat = gelu(conv1(x)) -> cl_a ; t1 = relu(conv5(x)) -> cl_c
  fconv2p_k<<<2048, 512, 0, stream>>>(x, wsc, wsc + WSC_SET,
                                      conv_b, w1_b, cl_a, cl_c);
  // 2. SPARSE dd at dwconv sample points           -> ddc (compact)
  sconv_k<<<1024, 256, 0, stream>>>(cl_a, wsc + 2 * WSC_SET, ddct_b, ddc);
  // 3. depthwise strided conv on compact dd        -> small0
  dwconv_c<<<1280, 256, 0, stream>>>(ddc, dctc_w, dctc_b, small0);
  // 4. per-block 8x8 iDCT                          -> small1
  idct8_k<<<1280, 256, 0, stream>>>(small0, small1);
  // 6. prod = sigmoid(1x1(t1)) * bilinear(idct)    -> cl_a (dct_feat dead)
  wgtmul_k<<<2048, 256, 0, stream>>>(cl_c, wt4, w3_b, small1, cl_a);
  // 7. out = conv(prod, after)                     -> d_out fp32 planar
  convl_k<<<2048, 512, 0, stream>>>(cl_a, wcma, after_b, (float*)d_out);
}